// Round 7
// baseline (357.764 us; speedup 1.0000x reference)
//
#include <hip/hip_runtime.h>
#include <math.h>

#define B_SZ 8
#define SEQ  4096
#define DM   64
#define DI   128
#define NH   2
#define HD   64
#define DS   128
#define DIP  514
#define XW   384           // zxb width: xBC only (z computed in k_fused, dt in DT)
#define CD   384
#define QC   64
#define NC   64
#define NR   (B_SZ*SEQ)
#define WPAD 576

typedef __attribute__((ext_vector_type(8))) short bf16x8;
typedef __attribute__((ext_vector_type(4))) float f32x4;
typedef __attribute__((ext_vector_type(2))) __bf16 bf16x2;
typedef __attribute__((ext_vector_type(2))) unsigned int u32x2;
typedef __attribute__((ext_vector_type(4))) unsigned int u32x4;

__device__ __forceinline__ unsigned short f2bf(float f) {
    union { __bf16 h; unsigned short u; } x;
    x.h = (__bf16)f;
    return x.u;
}
__device__ __forceinline__ unsigned int pk2(float lo, float hi) {
    union { bf16x2 v; unsigned int u; } x;
    x.v[0] = (__bf16)lo;
    x.v[1] = (__bf16)hi;
    return x.u;
}
__device__ __forceinline__ float bf2f(unsigned short h) {
    union { unsigned int u; float f; } x; x.u = ((unsigned int)h) << 16;
    return x.f;
}
// fast SiLU: x * rcp(1+e^-x). v_rcp_f32 is 1ulp — invisible after bf16 rounding.
__device__ __forceinline__ float fsilu(float x) {
    return x * __builtin_amdgcn_rcpf(1.f + __expf(-x));
}
// A/B-operand frag: lane holds M[r0+(lane&15)][k0 + (lane>>4)*8 + j], row-major [m][k]
__device__ __forceinline__ bf16x8 fragld(const unsigned short* base, int r0, int k0, int ld) {
    int l = threadIdx.x & 63;
    return *(const bf16x8*)(base + (ptrdiff_t)(r0 + (l & 15)) * ld + k0 + (l >> 4) * 8);
}

// ---------------- setup: weight bf16 conversion + residual x conversion (merged) ----------------
__global__ __launch_bounds__(256) void k_pre(const float* __restrict__ in_w,
                                             const float* __restrict__ out_w,
                                             const float* __restrict__ X,
                                             unsigned short* __restrict__ Wb,
                                             unsigned short* __restrict__ OWb,
                                             unsigned short* __restrict__ Xb) {
    int bid = blockIdx.x;
    if (bid < 576) {
        int idx = bid * 256 + threadIdx.x;
        if (idx < 4 * WPAD * 64) {
            int l = idx / (WPAD * 64), r = idx % (WPAD * 64);
            int n = r >> 6, k = r & 63;
            float v = (n < DIP) ? in_w[(size_t)l * DIP * 64 + (size_t)n * 64 + k] : 0.f;
            Wb[idx] = f2bf(v);
        }
        if (idx < 4 * 64 * 128) OWb[idx] = f2bf(out_w[idx]);
    } else {
        int idx = ((bid - 576) * 256 + threadIdx.x) * 4;
        float4 v = *(const float4*)(X + idx);
        uint2 p;
        p.x = pk2(v.x, v.y);
        p.y = pk2(v.z, v.w);
        *(uint2*)(Xb + idx) = p;
    }
}

// ---------------- in_proj (layer 0 only): LDS-free MFMA ----------------
__global__ __launch_bounds__(256) void k_inproj(const unsigned short* __restrict__ Xb,
                                                const unsigned short* __restrict__ Wb,
                                                unsigned short* __restrict__ ZXb,
                                                float* __restrict__ DT) {
    int m0 = blockIdx.x * 256;
    int ny = blockIdx.y;               // 0..5: xBC cols; 6: dt
    int tid = threadIdx.x;
    int wid = tid >> 6, lane = tid & 63;
    int q4 = lane >> 4, c16 = lane & 15;
    int mb = m0 + wid * 64;
    bf16x8 af[4][2];
#pragma unroll
    for (int mt = 0; mt < 4; mt++)
#pragma unroll
        for (int ks = 0; ks < 2; ks++)
            af[mt][ks] = *(const bf16x8*)(Xb + (size_t)(mb + mt * 16 + c16) * 64 + ks * 32 + q4 * 8);
    if (ny < 6) {
#pragma unroll
        for (int nt = 0; nt < 4; nt++) {
            bf16x8 bf[2];
#pragma unroll
            for (int ks = 0; ks < 2; ks++)
                bf[ks] = *(const bf16x8*)(Wb + (size_t)(128 + ny * 64 + nt * 16 + c16) * 64 + ks * 32 + q4 * 8);
#pragma unroll
            for (int mt = 0; mt < 4; mt++) {
                f32x4 acc = {0.f, 0.f, 0.f, 0.f};
                acc = __builtin_amdgcn_mfma_f32_16x16x32_bf16(af[mt][0], bf[0], acc, 0, 0, 0);
                acc = __builtin_amdgcn_mfma_f32_16x16x32_bf16(af[mt][1], bf[1], acc, 0, 0, 0);
#pragma unroll
                for (int rr = 0; rr < 4; rr++) {
                    float v = acc[rr];
                    float vn = __shfl_xor(v, 1);
                    if (!(lane & 1)) {
                        unsigned int pk = pk2(v, vn);
                        *(unsigned int*)(ZXb + (size_t)(mb + mt * 16 + q4 * 4 + rr) * XW + ny * 64 + nt * 16 + c16) = pk;
                    }
                }
            }
        }
    } else {
        bf16x8 bf[2];
#pragma unroll
        for (int ks = 0; ks < 2; ks++)
            bf[ks] = *(const bf16x8*)(Wb + (size_t)(512 + c16) * 64 + ks * 32 + q4 * 8);
#pragma unroll
        for (int mt = 0; mt < 4; mt++) {
            f32x4 acc = {0.f, 0.f, 0.f, 0.f};
            acc = __builtin_amdgcn_mfma_f32_16x16x32_bf16(af[mt][0], bf[0], acc, 0, 0, 0);
            acc = __builtin_amdgcn_mfma_f32_16x16x32_bf16(af[mt][1], bf[1], acc, 0, 0, 0);
            if (c16 < 2)
#pragma unroll
                for (int rr = 0; rr < 4; rr++)
                    DT[(size_t)(mb + mt * 16 + q4 * 4 + rr) * 2 + c16] = acc[rr];
        }
    }
}

// ---------------- chunk1 (1024 thr): dt/cum, conv+SiLU, G, M, Y_intra(tile-major), SL^T ----------------
__global__ __launch_bounds__(1024, 8) void k_chunk1(
        const unsigned short* __restrict__ ZXb, const float* __restrict__ DT,
        const float* __restrict__ CW, const float* __restrict__ CB,
        const float* __restrict__ dtb, const float* __restrict__ Alog,
        const float* __restrict__ Dv,
        unsigned short* __restrict__ SL, unsigned short* __restrict__ CBuf,
        float* __restrict__ EB,
        float* __restrict__ TB, unsigned short* __restrict__ YBb) {
    __shared__ unsigned short sBt[128][72];
    __shared__ unsigned short sXt[128][72];
    __shared__ unsigned short uBC[2][64][136];
    __shared__ float s_cum[2][64], s_dt[2][64], s_w[2][64];
    unsigned short (*sM)[64][72] = (unsigned short (*)[64][72])&uBC[0][0][0];

    int c = blockIdx.x, b = blockIdx.y;
    size_t rbase = (size_t)b * SEQ + c * QC;
    int tid = threadIdx.x;
    int wid = tid >> 6, lane = tid & 63;
    int q4 = lane >> 4, c16 = lane & 15;

    // Phase A: dt/cumsum (waves 0,1) — ordered vs Phase C by the conv barrier
    if (wid < 2) {
        int h = wid, j = lane;
        float raw = DT[(rbase + j) * 2 + h] + dtb[h];
        float dt = (raw > 20.f) ? raw : log1pf(__expf(raw));
        float A = -__expf(Alog[h]);
        float x = dt * A;
        for (int off = 1; off < 64; off <<= 1) {
            float o = __shfl_up(x, off);
            if (lane >= off) x += o;
        }
        float T = __shfl(x, 63);
        s_dt[h][j] = dt;
        s_cum[h][j] = x;
        s_w[h][j] = __expf(T - x) * dt;
        EB[((size_t)(b * NC + c)) * 128 + h * 64 + j] = __expf(x);
        if (j == 0) TB[(b * 2 + h) * NC + c] = __expf(T);
    }

    // Phase B: conv(4)+bias+SiLU from global ZXb (width 384); scatter to MFMA layouts
    size_t cbbase = ((size_t)(b * NC + c)) * 8192;
    for (int e = tid; e < 64 * 96; e += 1024) {
        int j = e / 96;
        int q = e - j * 96;
        int cc = q * 4;
        const unsigned short* zp = ZXb + (rbase + j) * XW + cc;
        uint2 a0 = *(const uint2*)zp;
        uint2 a1, a2, a3;
        if (c != 0) {            // uniform: interior chunk, halo always valid
            a1 = *(const uint2*)(zp - XW);
            a2 = *(const uint2*)(zp - 2 * XW);
            a3 = *(const uint2*)(zp - 3 * XW);
        } else {
            a1 = make_uint2(0, 0); a2 = make_uint2(0, 0); a3 = make_uint2(0, 0);
            if (j >= 1) a1 = *(const uint2*)(zp - XW);
            if (j >= 2) a2 = *(const uint2*)(zp - 2 * XW);
            if (j >= 3) a3 = *(const uint2*)(zp - 3 * XW);
        }
        float v[4];
#pragma unroll
        for (int u = 0; u < 4; u++) {
            unsigned int w0 = (u < 2) ? a0.x : a0.y;
            unsigned int w1 = (u < 2) ? a1.x : a1.y;
            unsigned int w2 = (u < 2) ? a2.x : a2.y;
            unsigned int w3 = (u < 2) ? a3.x : a3.y;
            int sh = (u & 1) * 16;
            float r0 = bf2f((unsigned short)(w0 >> sh));
            float r1 = bf2f((unsigned short)(w1 >> sh));
            float r2 = bf2f((unsigned short)(w2 >> sh));
            float r3 = bf2f((unsigned short)(w3 >> sh));
            float4 wv = *(const float4*)(CW + (cc + u) * 4);
            float tt = CB[cc + u] + wv.w * r0 + wv.z * r1 + wv.y * r2 + wv.x * r3;
            v[u] = fsilu(tt);
        }
        if (cc < 128) {
#pragma unroll
            for (int u = 0; u < 4; u++) sXt[cc + u][j] = f2bf(v[u]);
        } else if (cc < 256) {
            int s = cc - 128;
            unsigned int p0 = pk2(v[0], v[1]);
            unsigned int p1 = pk2(v[2], v[3]);
            *(uint2*)&uBC[0][j][s] = make_uint2(p0, p1);
#pragma unroll
            for (int u = 0; u < 4; u++) sBt[s + u][j] = f2bf(v[u]);
        } else {
            int s = cc - 256;
            unsigned int p0 = pk2(v[0], v[1]);
            unsigned int p1 = pk2(v[2], v[3]);
            *(uint2*)&uBC[1][j][s] = make_uint2(p0, p1);
            *(uint2*)(CBuf + cbbase + (size_t)j * 128 + s) = make_uint2(p0, p1);
        }
    }
    __syncthreads();

    // Phase C: G = C.B^T (16 tiles / 16 waves), stage in regs, overlay sM
    f32x4 gacc;
    {
        int it = wid >> 2, jt = wid & 3;
        f32x4 acc = {0.f, 0.f, 0.f, 0.f};
        __builtin_amdgcn_s_setprio(1);
        for (int ks = 0; ks < 4; ks++) {
            bf16x8 a = fragld(&uBC[1][0][0], it * 16, ks * 32, 136);
            bf16x8 bb = fragld(&uBC[0][0][0], jt * 16, ks * 32, 136);
            acc = __builtin_amdgcn_mfma_f32_16x16x32_bf16(a, bb, acc, 0, 0, 0);
        }
        __builtin_amdgcn_s_setprio(0);
        gacc = acc;
    }
    __syncthreads();
    {
        int it = wid >> 2, jt = wid & 3;
        int j = jt * 16 + c16;
        for (int rr = 0; rr < 4; rr++) {
            int i = it * 16 + q4 * 4 + rr;
            float gv = gacc[rr];
            for (int h = 0; h < 2; h++) {
                float m = 0.f;
                if (j <= i) m = gv * __expf(s_cum[h][i] - s_cum[h][j]) * s_dt[h][j];
                sM[h][i][j] = f2bf(m);
            }
        }
    }
    __syncthreads();

    // Phase D1: Y_intra = M_h @ X_h + D*x (32 tiles / 16 waves) — tile-major store
    size_t ybase = ((size_t)(b * NC + c)) * 8192;   // 32 tiles * 256 elems per chunk
#pragma unroll
    for (int u = 0; u < 2; u++) {
        int idx = wid * 2 + u;
        int h = idx >> 4, tt = idx & 15;
        int it = tt >> 2, pt = tt & 3;
        float dco = Dv[h];
        int pg = h * 64 + pt * 16 + c16;
        f32x4 acc;
        for (int rr = 0; rr < 4; rr++) {
            int i = it * 16 + q4 * 4 + rr;
            acc[rr] = dco * bf2f(sXt[pg][i]);
        }
        __builtin_amdgcn_s_setprio(1);
        for (int ks = 0; ks < 2; ks++) {
            bf16x8 a = fragld(&sM[h][0][0], it * 16, ks * 32, 72);
            bf16x8 bb = fragld(&sXt[0][0], h * 64 + pt * 16, ks * 32, 72);
            acc = __builtin_amdgcn_mfma_f32_16x16x32_bf16(a, bb, acc, 0, 0, 0);
        }
        __builtin_amdgcn_s_setprio(0);
        uint2 pk;
        pk.x = pk2(acc[0], acc[1]);
        pk.y = pk2(acc[2], acc[3]);
        *(uint2*)(YBb + ybase + (size_t)idx * 256 + lane * 4) = pk;
    }
    // Pre-scale sXt in place by s_w so D2 needs no per-fragment rescale
    __syncthreads();
    {
        int row = tid >> 3, c0 = (tid & 7) * 8;
        uint4 xv = *(uint4*)&sXt[row][c0];
        const float* wp = s_w[row >> 6];
        unsigned int* px = &xv.x;
        uint4 ov;
        unsigned int* po = &ov.x;
#pragma unroll
        for (int t = 0; t < 4; t++) {
            float lo = bf2f((unsigned short)(px[t] & 0xffff)) * wp[c0 + 2 * t];
            float hi = bf2f((unsigned short)(px[t] >> 16)) * wp[c0 + 2 * t + 1];
            po[t] = pk2(lo, hi);
        }
        *(uint4*)&sXt[row][c0] = ov;
    }
    __syncthreads();
    // Phase D2: SL^T[p][s] (64 tiles / 16 waves) — nontemporal stores (SL is stream-once)
    size_t slbase = ((size_t)(b * NC + c)) * 16384;
#pragma unroll
    for (int u = 0; u < 4; u++) {
        int idx = wid * 4 + u;
        int ptl = idx >> 3, st = idx & 7;
        f32x4 acc = {0.f, 0.f, 0.f, 0.f};
        __builtin_amdgcn_s_setprio(1);
        for (int ks = 0; ks < 2; ks++) {
            bf16x8 a = fragld(&sXt[0][0], ptl * 16, ks * 32, 72);
            bf16x8 bb = fragld(&sBt[0][0], st * 16, ks * 32, 72);
            acc = __builtin_amdgcn_mfma_f32_16x16x32_bf16(a, bb, acc, 0, 0, 0);
        }
        __builtin_amdgcn_s_setprio(0);
        int s = st * 16 + c16;
        for (int rr = 0; rr < 4; rr++) {
            int p = ptl * 16 + q4 * 4 + rr;
            float vv = acc[rr];
            float vn = __shfl_xor(vv, 1);
            if (!(lane & 1)) {
                unsigned int pk = pk2(vv, vn);
                __builtin_nontemporal_store(pk, (unsigned int*)(SL + slbase + (size_t)p * 128 + s));
            }
        }
    }
}

// ---------------- cross-chunk state scan: segmented 8-deep (512 blk x 1024 thr), nontemporal ----------------
__global__ __launch_bounds__(1024) void k_scan(unsigned short* __restrict__ SL,
                                               const float* __restrict__ TB) {
    __shared__ float sT0[8][128], sT1[8][128], sP[8];
    int tid = threadIdx.x;
    int col = tid & 127, seg = tid >> 7;
    int colg = blockIdx.x * 128 + col;         // 65536 col-pairs total
    int b2 = colg >> 13;
    int pu = colg & 8191;
    int h2 = pu >> 12;
    const float* dAp = TB + (b2 * 2 + h2) * NC;
    size_t cbase = (size_t)(b2 * NC) * 16384 + (size_t)pu * 2;
    int cc0 = seg * 8;
    unsigned int sv[8];
    float dA[8];
    float hP = 1.f, t0 = 0.f, t1 = 0.f;
#pragma unroll
    for (int k = 0; k < 8; k++) {
        sv[k] = __builtin_nontemporal_load((const unsigned int*)(SL + cbase + (size_t)(cc0 + k) * 16384));
        dA[k] = dAp[cc0 + k];
        float sx0 = bf2f((unsigned short)(sv[k] & 0xffff));
        float sx1 = bf2f((unsigned short)(sv[k] >> 16));
        t0 = t0 * dA[k] + sx0;
        t1 = t1 * dA[k] + sx1;
        hP *= dA[k];
    }
    sT0[seg][col] = t0;
    sT1[seg][col] = t1;
    if (col == 0) sP[seg] = hP;
    __syncthreads();
    float h0 = 0.f, h1 = 0.f;
    for (int s2 = 0; s2 < seg; s2++) {
        float Ps = sP[s2];
        h0 = h0 * Ps + sT0[s2][col];
        h1 = h1 * Ps + sT1[s2][col];
    }
#pragma unroll
    for (int k = 0; k < 8; k++) {
        __builtin_nontemporal_store(pk2(h0, h1), (unsigned int*)(SL + cbase + (size_t)(cc0 + k) * 16384));
        float sx0 = bf2f((unsigned short)(sv[k] & 0xffff));
        float sx1 = bf2f((unsigned short)(sv[k] >> 16));
        h0 = h0 * dA[k] + sx0;
        h1 = h1 * dA[k] + sx1;
    }
}

// ---------------- fused (1024 thr): z-GEMM + Y_inter + gate + RMSNorm + out_proj + residual
//                  + next-layer in_proj (row-local, from LDS) ----------------
__global__ __launch_bounds__(1024, 8) void k_fused(
        const unsigned short* __restrict__ SL, const unsigned short* __restrict__ CBuf,
        const float* __restrict__ EB,
        const unsigned short* __restrict__ YBb, const unsigned short* __restrict__ Wzb,
        const float* __restrict__ NW, const unsigned short* __restrict__ OWb,
        unsigned short* __restrict__ Xb, float* __restrict__ OutF,
        const unsigned short* __restrict__ WbN,      // next layer's in_proj weights (bf16)
        unsigned short* __restrict__ ZXbO,           // next layer's xBC buffer
        float* __restrict__ DTO,                     // next layer's dt buffer
        int last) {
    __shared__ __attribute__((aligned(16))) unsigned short sH[128][136];
    __shared__ __attribute__((aligned(16))) unsigned short sE[128][136];
    float* sGf = (float*)&sH[0][0];                                   // [64][132] overlay (dead after RMS)
    unsigned short (*sG)[136] = (unsigned short (*)[136])&sE[0][0];   // [64][136] overlay
    unsigned short (*sX2)[72] = (unsigned short (*)[72])&sH[0][0];    // [64][72] overlay (written in out_proj)

    int c = blockIdx.x, b = blockIdx.y;
    size_t rbase = (size_t)b * SEQ + c * QC;
    int tid = threadIdx.x;
    int wid = tid >> 6, lane = tid & 63;
    int q4 = lane >> 4, c16 = lane & 15;
    size_t base = ((size_t)(b * NC + c)) * 16384;
    size_t ybase = ((size_t)(b * NC + c)) * 8192;

    // ---- prefetch (issues before the first barrier; latency hides under sE fill) ----
    u32x2 yi[2];
    bf16x8 xa[2][2];
#pragma unroll
    for (int u = 0; u < 2; u++) {
        int idx = wid * 2 + u;
        int it = (idx & 15) >> 2;
        yi[u] = __builtin_nontemporal_load((const u32x2*)(YBb + ybase + (size_t)idx * 256 + lane * 4));
#pragma unroll
        for (int ks = 0; ks < 2; ks++)
            xa[u][ks] = fragld(Xb, (int)rbase + it * 16, ks * 32, 64);
    }

    for (int u = 0; u < 2; u++) {
        int e = u * 1024 + tid;
        int row = e >> 4, cb8 = (e & 15) * 8;
        u32x4 hv = __builtin_nontemporal_load((const u32x4*)(SL + base + (size_t)row * 128 + cb8));
        *(u32x4*)&sH[row][cb8] = hv;
    }
    size_t cbbase = ((size_t)(b * NC + c)) * 8192;
    size_t ebase  = ((size_t)(b * NC + c)) * 128;
    {
        int i = tid >> 4, sc = (tid & 15) * 8;
        u32x4 cv = __builtin_nontemporal_load((const u32x4*)(CBuf + cbbase + (size_t)i * 128 + sc));
        float e0 = EB[ebase + i], e1 = EB[ebase + 64 + i];
        unsigned int w[4] = {cv[0], cv[1], cv[2], cv[3]};
        uint4 o0, o1;
        unsigned int* po0 = &o0.x;
        unsigned int* po1 = &o1.x;
#pragma unroll
        for (int t = 0; t < 4; t++) {
            float lo = bf2f((unsigned short)(w[t] & 0xffff));
            float hi = bf2f((unsigned short)(w[t] >> 16));
            po0[t] = pk2(lo * e0, hi * e0);
            po1[t] = pk2(lo * e1, hi * e1);
        }
        *(uint4*)&sE[i][sc] = o0;
        *(uint4*)&sE[64 + i][sc] = o1;
    }
    __syncthreads();

    float yv[2][4];
    int tit[2], tpg[2];
#pragma unroll
    for (int u = 0; u < 2; u++) {
        int idx = wid * 2 + u;                 // 32 tiles / 16 waves
        int h = idx >> 4, tt = idx & 15;
        int it = tt >> 2, pt = tt & 3;
        int pg = h * 64 + pt * 16 + c16;
        f32x4 zacc = {0.f, 0.f, 0.f, 0.f};
        f32x4 acc = {0.f, 0.f, 0.f, 0.f};
        __builtin_amdgcn_s_setprio(1);
#pragma unroll
        for (int ks = 0; ks < 2; ks++) {
            bf16x8 wz = fragld(Wzb, h * 64 + pt * 16, ks * 32, 64);
            zacc = __builtin_amdgcn_mfma_f32_16x16x32_bf16(xa[u][ks], wz, zacc, 0, 0, 0);
        }
        for (int ks = 0; ks < 4; ks++) {
            bf16x8 a = fragld(&sE[0][0], h * 64 + it * 16, ks * 32, 136);
            bf16x8 bb = fragld(&sH[0][0], h * 64 + pt * 16, ks * 32, 136);
            acc = __builtin_amdgcn_mfma_f32_16x16x32_bf16(a, bb, acc, 0, 0, 0);
        }
        __builtin_amdgcn_s_setprio(0);
        tit[u] = it; tpg[u] = pg;
        float yin[4] = {bf2f((unsigned short)(yi[u][0] & 0xffff)), bf2f((unsigned short)(yi[u][0] >> 16)),
                        bf2f((unsigned short)(yi[u][1] & 0xffff)), bf2f((unsigned short)(yi[u][1] >> 16))};
        for (int rr = 0; rr < 4; rr++) {
            float y = acc[rr] + yin[rr];
            yv[u][rr] = y * fsilu(zacc[rr]);
        }
    }
    __syncthreads();
#pragma unroll
    for (int u = 0; u < 2; u++)
        for (int rr = 0; rr < 4; rr++) {
            int i = tit[u] * 16 + q4 * 4 + rr;
            sGf[i * 132 + tpg[u]] = yv[u][rr];
        }
    __syncthreads();
    // prefetch residual (hides under RMS reduction)
    unsigned short xres[4];
    {
        int mt = wid >> 2, nt2 = wid & 3;
        int n = nt2 * 16 + c16;
#pragma unroll
        for (int rr = 0; rr < 4; rr++) {
            int m = mt * 16 + q4 * 4 + rr;
            xres[rr] = Xb[(rbase + m) * DM + n];
        }
    }
    {
        int row = tid >> 4, part = tid & 15;
        int d0 = part * 8;
        float g[8];
        float ss = 0.f;
        for (int t2 = 0; t2 < 8; t2++) { g[t2] = sGf[row * 132 + d0 + t2]; ss += g[t2] * g[t2]; }
        ss += __shfl_xor(ss, 1);
        ss += __shfl_xor(ss, 2);
        ss += __shfl_xor(ss, 4);
        ss += __shfl_xor(ss, 8);
        float rms = rsqrtf(ss * (1.f / 128.f) + 1e-5f);
        for (int t2 = 0; t2 < 8; t2 += 2) {
            unsigned int pk = pk2(g[t2] * rms * NW[d0 + t2], g[t2 + 1] * rms * NW[d0 + t2 + 1]);
            *(unsigned int*)&sG[row][d0 + t2] = pk;
        }
    }
    __syncthreads();
    {
        // out_proj: 16 tiles over 16 waves (mt 0..3 × nt 0..3); also stage new-x into sX2
        int mt = wid >> 2, nt = wid & 3;
        f32x4 acc = {0.f, 0.f, 0.f, 0.f};
        __builtin_amdgcn_s_setprio(1);
        for (int ks = 0; ks < 4; ks++) {
            bf16x8 a = fragld(&sG[0][0], mt * 16, ks * 32, 136);
            bf16x8 bb = *(const bf16x8*)(OWb + (size_t)(nt * 16 + c16) * 128 + ks * 32 + q4 * 8);
            acc = __builtin_amdgcn_mfma_f32_16x16x32_bf16(a, bb, acc, 0, 0, 0);
        }
        __builtin_amdgcn_s_setprio(0);
        for (int rr = 0; rr < 4; rr++) {
            int m = mt * 16 + q4 * 4 + rr;
            int n = nt * 16 + c16;
            size_t o = (rbase + m) * DM + n;
            float v = bf2f(xres[rr]) + acc[rr];
            if (last) {
                __builtin_nontemporal_store(v, &OutF[o]);
            } else {
                unsigned short vb = f2bf(v);
                sX2[m][n] = vb;
                float vn = __shfl_xor(v, 1);
                if (!(lane & 1)) {
                    unsigned int pk = (unsigned int)vb | ((unsigned int)f2bf(vn) << 16);
                    *(unsigned int*)(Xb + o) = pk;
                }
            }
        }
    }
    if (!last) {
        __syncthreads();
        // next-layer in_proj for rows rbase..rbase+63: 100 tile jobs over 16 waves
        for (int t = wid; t < 100; t += 16) {
            int mt2, n0;
            int isdt = (t >= 96);
            if (!isdt) { mt2 = t & 3; n0 = (t >> 2) * 16; }
            else       { mt2 = t - 96; n0 = 0; }
            bf16x8 a0 = fragld(&sX2[0][0], mt2 * 16, 0, 72);
            bf16x8 a1 = fragld(&sX2[0][0], mt2 * 16, 32, 72);
            const unsigned short* wrow = isdt ? (WbN + (size_t)(512 + c16) * 64)
                                              : (WbN + (size_t)(128 + n0 + c16) * 64);
            bf16x8 b0 = *(const bf16x8*)(wrow + q4 * 8);
            bf16x8 b1 = *(const bf16x8*)(wrow + 32 + q4 * 8);
            f32x4 acc = {0.f, 0.f, 0.f, 0.f};
            __builtin_amdgcn_s_setprio(1);
            acc = __builtin_amdgcn_mfma_f32_16x16x32_bf16(a0, b0, acc, 0, 0, 0);
            acc = __builtin_amdgcn_mfma_f32_16x16x32_bf16(a1, b1, acc, 0, 0, 0);
            __builtin_amdgcn_s_setprio(0);
            if (!isdt) {
#pragma unroll
                for (int rr = 0; rr < 4; rr++) {
                    float v = acc[rr];
                    float vn = __shfl_xor(v, 1);
                    if (!(lane & 1)) {
                        unsigned int pk = pk2(v, vn);
                        *(unsigned int*)(ZXbO + (rbase + mt2 * 16 + q4 * 4 + rr) * XW + n0 + c16) = pk;
                    }
                }
            } else {
                if (c16 < 2)
#pragma unroll
                    for (int rr = 0; rr < 4; rr++)
                        DTO[(rbase + mt2 * 16 + q4 * 4 + rr) * 2 + c16] = acc[rr];
            }
        }
    }
}

extern "C" void kernel_launch(void* const* d_in, const int* in_sizes, int n_in,
                              void* d_out, int out_size, void* d_ws, size_t ws_size,
                              hipStream_t stream) {
    const float* x       = (const float*)d_in[0];
    const float* in_w    = (const float*)d_in[1];
    const float* conv_w  = (const float*)d_in[2];
    const float* conv_b  = (const float*)d_in[3];
    const float* dt_bias = (const float*)d_in[4];
    const float* A_log   = (const float*)d_in[5];
    const float* Dp      = (const float*)d_in[6];
    const float* norm_w  = (const float*)d_in[7];
    const float* out_w   = (const float*)d_in[8];
    float* out = (float*)d_out;
    float* ws  = (float*)d_ws;

    float* dt = ws;                                        // NR*2 f32
    float* tb = dt + (size_t)NR * 2;                       // 1024 f32
    float* eb = tb + 1024;                                 // 8*64*128 f32
    unsigned short* zxb  = (unsigned short*)(eb + (size_t)B_SZ * NC * 128); // NR*384
    unsigned short* ybb  = zxb + (size_t)NR * XW;          // 8*64*8192 (tile-major)
    unsigned short* sl   = ybb + (size_t)B_SZ * NC * 8192; // 8*64*16384
    unsigned short* cbuf = sl + (size_t)B_SZ * NC * 16384; // 8*64*8192
    unsigned short* xb   = cbuf + (size_t)B_SZ * NC * 8192;// NR*64
    unsigned short* wb   = xb + (size_t)NR * DM;           // 4*576*64
    unsigned short* owb  = wb + (size_t)4 * WPAD * 64;     // 4*64*128

    k_pre<<<576 + NR * DM / 1024, 256, 0, stream>>>(in_w, out_w, x, wb, owb, xb);
    k_inproj<<<dim3(NR / 256, 7), 256, 0, stream>>>(xb, wb, zxb, dt);   // layer 0 only

    for (int layer = 0; layer < 4; layer++) {
        int nl = (layer < 3) ? layer + 1 : 3;
        k_chunk1<<<dim3(NC, B_SZ), 1024, 0, stream>>>(zxb, dt,
                conv_w + (size_t)layer * CD * 4, conv_b + (size_t)layer * CD,
                dt_bias + layer * NH, A_log + layer * NH, Dp + layer * NH,
                sl, cbuf, eb, tb, ybb);
        k_scan<<<512, 1024, 0, stream>>>(sl, tb);
        k_fused<<<dim3(NC, B_SZ), 1024, 0, stream>>>(sl, cbuf, eb, ybb,
                wb + (size_t)layer * WPAD * 64, norm_w + layer * DI,
                owb + (size_t)layer * 64 * 128, xb, out,
                wb + (size_t)nl * WPAD * 64, zxb, dt,
                (layer == 3) ? 1 : 0);
    }
}

// Round 8
// 355.400 us; speedup vs baseline: 1.0066x; 1.0066x over previous
//
#include <hip/hip_runtime.h>
#include <math.h>

#define B_SZ 8
#define SEQ  4096
#define DM   64
#define DI   128
#define NH   2
#define HD   64
#define DS   128
#define DIP  514
#define XW   384           // zxb width: xBC only (z computed in k_fused, dt in DT)
#define CD   384
#define QC   64
#define NC   64
#define NR   (B_SZ*SEQ)
#define WPAD 576

typedef __attribute__((ext_vector_type(8))) short bf16x8;
typedef __attribute__((ext_vector_type(4))) float f32x4;
typedef __attribute__((ext_vector_type(2))) __bf16 bf16x2;

__device__ __forceinline__ unsigned short f2bf(float f) {
    union { __bf16 h; unsigned short u; } x;
    x.h = (__bf16)f;
    return x.u;
}
__device__ __forceinline__ unsigned int pk2(float lo, float hi) {
    union { bf16x2 v; unsigned int u; } x;
    x.v[0] = (__bf16)lo;
    x.v[1] = (__bf16)hi;
    return x.u;
}
__device__ __forceinline__ float bf2f(unsigned short h) {
    union { unsigned int u; float f; } x; x.u = ((unsigned int)h) << 16;
    return x.f;
}
// fast SiLU: x * rcp(1+e^-x). v_rcp_f32 is 1ulp — invisible after bf16 rounding.
__device__ __forceinline__ float fsilu(float x) {
    return x * __builtin_amdgcn_rcpf(1.f + __expf(-x));
}
// A/B-operand frag: lane holds M[r0+(lane&15)][k0 + (lane>>4)*8 + j], row-major [m][k]
__device__ __forceinline__ bf16x8 fragld(const unsigned short* base, int r0, int k0, int ld) {
    int l = threadIdx.x & 63;
    return *(const bf16x8*)(base + (ptrdiff_t)(r0 + (l & 15)) * ld + k0 + (l >> 4) * 8);
}

// ---------------- setup: weight bf16 conversion + residual x conversion (merged) ----------------
__global__ __launch_bounds__(256) void k_pre(const float* __restrict__ in_w,
                                             const float* __restrict__ out_w,
                                             const float* __restrict__ X,
                                             unsigned short* __restrict__ Wb,
                                             unsigned short* __restrict__ OWb,
                                             unsigned short* __restrict__ Xb) {
    int bid = blockIdx.x;
    if (bid < 576) {
        int idx = bid * 256 + threadIdx.x;
        if (idx < 4 * WPAD * 64) {
            int l = idx / (WPAD * 64), r = idx % (WPAD * 64);
            int n = r >> 6, k = r & 63;
            float v = (n < DIP) ? in_w[(size_t)l * DIP * 64 + (size_t)n * 64 + k] : 0.f;
            Wb[idx] = f2bf(v);
        }
        if (idx < 4 * 64 * 128) OWb[idx] = f2bf(out_w[idx]);
    } else {
        int idx = ((bid - 576) * 256 + threadIdx.x) * 4;
        float4 v = *(const float4*)(X + idx);
        uint2 p;
        p.x = pk2(v.x, v.y);
        p.y = pk2(v.z, v.w);
        *(uint2*)(Xb + idx) = p;
    }
}

// ---------------- in_proj (layer 0 only): LDS-free MFMA ----------------
__global__ __launch_bounds__(256) void k_inproj(const unsigned short* __restrict__ Xb,
                                                const unsigned short* __restrict__ Wb,
                                                unsigned short* __restrict__ ZXb,
                                                float* __restrict__ DT) {
    int m0 = blockIdx.x * 256;
    int ny = blockIdx.y;               // 0..5: xBC cols; 6: dt
    int tid = threadIdx.x;
    int wid = tid >> 6, lane = tid & 63;
    int q4 = lane >> 4, c16 = lane & 15;
    int mb = m0 + wid * 64;
    bf16x8 af[4][2];
#pragma unroll
    for (int mt = 0; mt < 4; mt++)
#pragma unroll
        for (int ks = 0; ks < 2; ks++)
            af[mt][ks] = *(const bf16x8*)(Xb + (size_t)(mb + mt * 16 + c16) * 64 + ks * 32 + q4 * 8);
    if (ny < 6) {
#pragma unroll
        for (int nt = 0; nt < 4; nt++) {
            bf16x8 bf[2];
#pragma unroll
            for (int ks = 0; ks < 2; ks++)
                bf[ks] = *(const bf16x8*)(Wb + (size_t)(128 + ny * 64 + nt * 16 + c16) * 64 + ks * 32 + q4 * 8);
#pragma unroll
            for (int mt = 0; mt < 4; mt++) {
                f32x4 acc = {0.f, 0.f, 0.f, 0.f};
                acc = __builtin_amdgcn_mfma_f32_16x16x32_bf16(af[mt][0], bf[0], acc, 0, 0, 0);
                acc = __builtin_amdgcn_mfma_f32_16x16x32_bf16(af[mt][1], bf[1], acc, 0, 0, 0);
#pragma unroll
                for (int rr = 0; rr < 4; rr++) {
                    float v = acc[rr];
                    float vn = __shfl_xor(v, 1);
                    if (!(lane & 1)) {
                        unsigned int pk = pk2(v, vn);
                        *(unsigned int*)(ZXb + (size_t)(mb + mt * 16 + q4 * 4 + rr) * XW + ny * 64 + nt * 16 + c16) = pk;
                    }
                }
            }
        }
    } else {
        bf16x8 bf[2];
#pragma unroll
        for (int ks = 0; ks < 2; ks++)
            bf[ks] = *(const bf16x8*)(Wb + (size_t)(512 + c16) * 64 + ks * 32 + q4 * 8);
#pragma unroll
        for (int mt = 0; mt < 4; mt++) {
            f32x4 acc = {0.f, 0.f, 0.f, 0.f};
            acc = __builtin_amdgcn_mfma_f32_16x16x32_bf16(af[mt][0], bf[0], acc, 0, 0, 0);
            acc = __builtin_amdgcn_mfma_f32_16x16x32_bf16(af[mt][1], bf[1], acc, 0, 0, 0);
            if (c16 < 2)
#pragma unroll
                for (int rr = 0; rr < 4; rr++)
                    DT[(size_t)(mb + mt * 16 + q4 * 4 + rr) * 2 + c16] = acc[rr];
        }
    }
}

// ---------------- chunk1 (1024 thr): dt/cum, conv+SiLU, G, M, Y_intra(tile-major), SL^T ----------------
__global__ __launch_bounds__(1024, 8) void k_chunk1(
        const unsigned short* __restrict__ ZXb, const float* __restrict__ DT,
        const float* __restrict__ CW, const float* __restrict__ CB,
        const float* __restrict__ dtb, const float* __restrict__ Alog,
        const float* __restrict__ Dv,
        unsigned short* __restrict__ SL, unsigned short* __restrict__ CBuf,
        float* __restrict__ EB,
        float* __restrict__ TB, unsigned short* __restrict__ YBb) {
    __shared__ unsigned short sBt[128][72];
    __shared__ unsigned short sXt[128][72];
    __shared__ unsigned short uBC[2][64][136];
    __shared__ float s_cum[2][64], s_dt[2][64], s_w[2][64];
    unsigned short (*sM)[64][72] = (unsigned short (*)[64][72])&uBC[0][0][0];

    int c = blockIdx.x, b = blockIdx.y;
    size_t rbase = (size_t)b * SEQ + c * QC;
    int tid = threadIdx.x;
    int wid = tid >> 6, lane = tid & 63;
    int q4 = lane >> 4, c16 = lane & 15;

    // Phase A: dt/cumsum (waves 0,1) — ordered vs Phase C by the conv barrier
    if (wid < 2) {
        int h = wid, j = lane;
        float raw = DT[(rbase + j) * 2 + h] + dtb[h];
        float dt = (raw > 20.f) ? raw : log1pf(__expf(raw));
        float A = -__expf(Alog[h]);
        float x = dt * A;
        for (int off = 1; off < 64; off <<= 1) {
            float o = __shfl_up(x, off);
            if (lane >= off) x += o;
        }
        float T = __shfl(x, 63);
        s_dt[h][j] = dt;
        s_cum[h][j] = x;
        s_w[h][j] = __expf(T - x) * dt;
        EB[((size_t)(b * NC + c)) * 128 + h * 64 + j] = __expf(x);
        if (j == 0) TB[(b * 2 + h) * NC + c] = __expf(T);
    }

    // Phase B: conv(4)+bias+SiLU from global ZXb (width 384); scatter to MFMA layouts
    size_t cbbase = ((size_t)(b * NC + c)) * 8192;
    for (int e = tid; e < 64 * 96; e += 1024) {
        int j = e / 96;
        int q = e - j * 96;
        int cc = q * 4;
        const unsigned short* zp = ZXb + (rbase + j) * XW + cc;
        uint2 a0 = *(const uint2*)zp;
        uint2 a1, a2, a3;
        if (c != 0) {            // uniform: interior chunk, halo always valid
            a1 = *(const uint2*)(zp - XW);
            a2 = *(const uint2*)(zp - 2 * XW);
            a3 = *(const uint2*)(zp - 3 * XW);
        } else {
            a1 = make_uint2(0, 0); a2 = make_uint2(0, 0); a3 = make_uint2(0, 0);
            if (j >= 1) a1 = *(const uint2*)(zp - XW);
            if (j >= 2) a2 = *(const uint2*)(zp - 2 * XW);
            if (j >= 3) a3 = *(const uint2*)(zp - 3 * XW);
        }
        float v[4];
#pragma unroll
        for (int u = 0; u < 4; u++) {
            unsigned int w0 = (u < 2) ? a0.x : a0.y;
            unsigned int w1 = (u < 2) ? a1.x : a1.y;
            unsigned int w2 = (u < 2) ? a2.x : a2.y;
            unsigned int w3 = (u < 2) ? a3.x : a3.y;
            int sh = (u & 1) * 16;
            float r0 = bf2f((unsigned short)(w0 >> sh));
            float r1 = bf2f((unsigned short)(w1 >> sh));
            float r2 = bf2f((unsigned short)(w2 >> sh));
            float r3 = bf2f((unsigned short)(w3 >> sh));
            float4 wv = *(const float4*)(CW + (cc + u) * 4);
            float tt = CB[cc + u] + wv.w * r0 + wv.z * r1 + wv.y * r2 + wv.x * r3;
            v[u] = fsilu(tt);
        }
        if (cc < 128) {
#pragma unroll
            for (int u = 0; u < 4; u++) sXt[cc + u][j] = f2bf(v[u]);
        } else if (cc < 256) {
            int s = cc - 128;
            unsigned int p0 = pk2(v[0], v[1]);
            unsigned int p1 = pk2(v[2], v[3]);
            *(uint2*)&uBC[0][j][s] = make_uint2(p0, p1);
#pragma unroll
            for (int u = 0; u < 4; u++) sBt[s + u][j] = f2bf(v[u]);
        } else {
            int s = cc - 256;
            unsigned int p0 = pk2(v[0], v[1]);
            unsigned int p1 = pk2(v[2], v[3]);
            *(uint2*)&uBC[1][j][s] = make_uint2(p0, p1);
            *(uint2*)(CBuf + cbbase + (size_t)j * 128 + s) = make_uint2(p0, p1);
        }
    }
    __syncthreads();

    // Phase C: G = C.B^T (16 tiles / 16 waves), stage in regs, overlay sM
    f32x4 gacc;
    {
        int it = wid >> 2, jt = wid & 3;
        f32x4 acc = {0.f, 0.f, 0.f, 0.f};
        __builtin_amdgcn_s_setprio(1);
        for (int ks = 0; ks < 4; ks++) {
            bf16x8 a = fragld(&uBC[1][0][0], it * 16, ks * 32, 136);
            bf16x8 bb = fragld(&uBC[0][0][0], jt * 16, ks * 32, 136);
            acc = __builtin_amdgcn_mfma_f32_16x16x32_bf16(a, bb, acc, 0, 0, 0);
        }
        __builtin_amdgcn_s_setprio(0);
        gacc = acc;
    }
    __syncthreads();
    {
        int it = wid >> 2, jt = wid & 3;
        int j = jt * 16 + c16;
        for (int rr = 0; rr < 4; rr++) {
            int i = it * 16 + q4 * 4 + rr;
            float gv = gacc[rr];
            for (int h = 0; h < 2; h++) {
                float m = 0.f;
                if (j <= i) m = gv * __expf(s_cum[h][i] - s_cum[h][j]) * s_dt[h][j];
                sM[h][i][j] = f2bf(m);
            }
        }
    }
    __syncthreads();

    // Phase D1: Y_intra = M_h @ X_h + D*x (32 tiles / 16 waves) — tile-major store
    size_t ybase = ((size_t)(b * NC + c)) * 8192;   // 32 tiles * 256 elems per chunk
#pragma unroll
    for (int u = 0; u < 2; u++) {
        int idx = wid * 2 + u;
        int h = idx >> 4, tt = idx & 15;
        int it = tt >> 2, pt = tt & 3;
        float dco = Dv[h];
        int pg = h * 64 + pt * 16 + c16;
        f32x4 acc;
        for (int rr = 0; rr < 4; rr++) {
            int i = it * 16 + q4 * 4 + rr;
            acc[rr] = dco * bf2f(sXt[pg][i]);
        }
        __builtin_amdgcn_s_setprio(1);
        for (int ks = 0; ks < 2; ks++) {
            bf16x8 a = fragld(&sM[h][0][0], it * 16, ks * 32, 72);
            bf16x8 bb = fragld(&sXt[0][0], h * 64 + pt * 16, ks * 32, 72);
            acc = __builtin_amdgcn_mfma_f32_16x16x32_bf16(a, bb, acc, 0, 0, 0);
        }
        __builtin_amdgcn_s_setprio(0);
        uint2 pk;
        pk.x = pk2(acc[0], acc[1]);
        pk.y = pk2(acc[2], acc[3]);
        *(uint2*)(YBb + ybase + (size_t)idx * 256 + lane * 4) = pk;
    }
    // Pre-scale sXt in place by s_w so D2 needs no per-fragment rescale
    __syncthreads();
    {
        int row = tid >> 3, c0 = (tid & 7) * 8;
        uint4 xv = *(uint4*)&sXt[row][c0];
        const float* wp = s_w[row >> 6];
        unsigned int* px = &xv.x;
        uint4 ov;
        unsigned int* po = &ov.x;
#pragma unroll
        for (int t = 0; t < 4; t++) {
            float lo = bf2f((unsigned short)(px[t] & 0xffff)) * wp[c0 + 2 * t];
            float hi = bf2f((unsigned short)(px[t] >> 16)) * wp[c0 + 2 * t + 1];
            po[t] = pk2(lo, hi);
        }
        *(uint4*)&sXt[row][c0] = ov;
    }
    __syncthreads();
    // Phase D2: SL^T[p][s] (64 tiles / 16 waves)
    size_t slbase = ((size_t)(b * NC + c)) * 16384;
#pragma unroll
    for (int u = 0; u < 4; u++) {
        int idx = wid * 4 + u;
        int ptl = idx >> 3, st = idx & 7;
        f32x4 acc = {0.f, 0.f, 0.f, 0.f};
        __builtin_amdgcn_s_setprio(1);
        for (int ks = 0; ks < 2; ks++) {
            bf16x8 a = fragld(&sXt[0][0], ptl * 16, ks * 32, 72);
            bf16x8 bb = fragld(&sBt[0][0], st * 16, ks * 32, 72);
            acc = __builtin_amdgcn_mfma_f32_16x16x32_bf16(a, bb, acc, 0, 0, 0);
        }
        __builtin_amdgcn_s_setprio(0);
        int s = st * 16 + c16;
        for (int rr = 0; rr < 4; rr++) {
            int p = ptl * 16 + q4 * 4 + rr;
            float vv = acc[rr];
            float vn = __shfl_xor(vv, 1);
            if (!(lane & 1)) {
                unsigned int pk = pk2(vv, vn);
                *(unsigned int*)(SL + slbase + (size_t)p * 128 + s) = pk;
            }
        }
    }
}

// ---------------- cross-chunk state scan: segmented, 8-deep chain (512 blk x 1024 thr) ----------------
__global__ __launch_bounds__(1024) void k_scan(unsigned short* __restrict__ SL,
                                               const float* __restrict__ TB) {
    __shared__ float sT0[8][128], sT1[8][128], sP[8];
    int tid = threadIdx.x;
    int col = tid & 127, seg = tid >> 7;
    int colg = blockIdx.x * 128 + col;         // 65536 col-pairs total
    int b2 = colg >> 13;
    int pu = colg & 8191;
    int h2 = pu >> 12;
    const float* dAp = TB + (b2 * 2 + h2) * NC;
    size_t cbase = (size_t)(b2 * NC) * 16384 + (size_t)pu * 2;
    int cc0 = seg * 8;
    unsigned int sv[8];
    float dA[8];
    float hP = 1.f, t0 = 0.f, t1 = 0.f;
#pragma unroll
    for (int k = 0; k < 8; k++) {
        sv[k] = *(unsigned int*)(SL + cbase + (size_t)(cc0 + k) * 16384);
        dA[k] = dAp[cc0 + k];
        float sx0 = bf2f((unsigned short)(sv[k] & 0xffff));
        float sx1 = bf2f((unsigned short)(sv[k] >> 16));
        t0 = t0 * dA[k] + sx0;
        t1 = t1 * dA[k] + sx1;
        hP *= dA[k];
    }
    sT0[seg][col] = t0;
    sT1[seg][col] = t1;
    if (col == 0) sP[seg] = hP;
    __syncthreads();
    float h0 = 0.f, h1 = 0.f;
    for (int s2 = 0; s2 < seg; s2++) {
        float Ps = sP[s2];
        h0 = h0 * Ps + sT0[s2][col];
        h1 = h1 * Ps + sT1[s2][col];
    }
#pragma unroll
    for (int k = 0; k < 8; k++) {
        *(unsigned int*)(SL + cbase + (size_t)(cc0 + k) * 16384) = pk2(h0, h1);
        float sx0 = bf2f((unsigned short)(sv[k] & 0xffff));
        float sx1 = bf2f((unsigned short)(sv[k] >> 16));
        h0 = h0 * dA[k] + sx0;
        h1 = h1 * dA[k] + sx1;
    }
}

// ---------------- fused (1024 thr): z-GEMM + Y_inter + gate + RMSNorm + out_proj + residual
//                  + next-layer in_proj (row-local, from LDS) ----------------
__global__ __launch_bounds__(1024, 8) void k_fused(
        const unsigned short* __restrict__ SL, const unsigned short* __restrict__ CBuf,
        const float* __restrict__ EB,
        const unsigned short* __restrict__ YBb, const unsigned short* __restrict__ Wzb,
        const float* __restrict__ NW, const unsigned short* __restrict__ OWb,
        unsigned short* __restrict__ Xb, float* __restrict__ OutF,
        const unsigned short* __restrict__ WbN,      // next layer's in_proj weights (bf16)
        unsigned short* __restrict__ ZXbO,           // next layer's xBC buffer
        float* __restrict__ DTO,                     // next layer's dt buffer
        int last) {
    __shared__ __attribute__((aligned(16))) unsigned short sH[128][136];  // overlay space only
    __shared__ __attribute__((aligned(16))) unsigned short sE[128][136];
    float* sGf = (float*)&sH[0][0];                                   // [64][132] overlay
    unsigned short (*sG)[136] = (unsigned short (*)[136])&sE[0][0];   // [64][136] overlay
    unsigned short (*sX2)[72] = (unsigned short (*)[72])&sH[0][0];    // [64][72] overlay (out_proj)

    int c = blockIdx.x, b = blockIdx.y;
    size_t rbase = (size_t)b * SEQ + c * QC;
    int tid = threadIdx.x;
    int wid = tid >> 6, lane = tid & 63;
    int q4 = lane >> 4, c16 = lane & 15;
    size_t base = ((size_t)(b * NC + c)) * 16384;
    size_t ybase = ((size_t)(b * NC + c)) * 8192;

    // ---- prefetch (issues before the first barrier; latency hides under sE fill) ----
    uint2 yi[2];
    bf16x8 xa[2][2];
#pragma unroll
    for (int u = 0; u < 2; u++) {
        int idx = wid * 2 + u;
        int it = (idx & 15) >> 2;
        yi[u] = *(const uint2*)(YBb + ybase + (size_t)idx * 256 + lane * 4);
#pragma unroll
        for (int ks = 0; ks < 2; ks++)
            xa[u][ks] = fragld(Xb, (int)rbase + it * 16, ks * 32, 64);
    }

    // sE fill: C * e^cumsum (H-state is read directly from global SL — L2-hot, no staging)
    size_t cbbase = ((size_t)(b * NC + c)) * 8192;
    size_t ebase  = ((size_t)(b * NC + c)) * 128;
    {
        int i = tid >> 4, sc = (tid & 15) * 8;
        uint4 cv = *(const uint4*)(CBuf + cbbase + (size_t)i * 128 + sc);
        float e0 = EB[ebase + i], e1 = EB[ebase + 64 + i];
        unsigned int w[4] = {cv.x, cv.y, cv.z, cv.w};
        uint4 o0, o1;
        unsigned int* po0 = &o0.x;
        unsigned int* po1 = &o1.x;
#pragma unroll
        for (int t = 0; t < 4; t++) {
            float lo = bf2f((unsigned short)(w[t] & 0xffff));
            float hi = bf2f((unsigned short)(w[t] >> 16));
            po0[t] = pk2(lo * e0, hi * e0);
            po1[t] = pk2(lo * e1, hi * e1);
        }
        *(uint4*)&sE[i][sc] = o0;
        *(uint4*)&sE[64 + i][sc] = o1;
    }
    __syncthreads();

    float yv[2][4];
    int tit[2], tpg[2];
#pragma unroll
    for (int u = 0; u < 2; u++) {
        int idx = wid * 2 + u;                 // 32 tiles / 16 waves
        int h = idx >> 4, tt = idx & 15;
        int it = tt >> 2, pt = tt & 3;
        int pg = h * 64 + pt * 16 + c16;
        f32x4 zacc = {0.f, 0.f, 0.f, 0.f};
        f32x4 acc = {0.f, 0.f, 0.f, 0.f};
        __builtin_amdgcn_s_setprio(1);
#pragma unroll
        for (int ks = 0; ks < 2; ks++) {
            bf16x8 wz = fragld(Wzb, h * 64 + pt * 16, ks * 32, 64);
            zacc = __builtin_amdgcn_mfma_f32_16x16x32_bf16(xa[u][ks], wz, zacc, 0, 0, 0);
        }
        for (int ks = 0; ks < 4; ks++) {
            bf16x8 a = fragld(&sE[0][0], h * 64 + it * 16, ks * 32, 136);
            bf16x8 bb = fragld(SL + base, h * 64 + pt * 16, ks * 32, 128);   // direct L2 read
            acc = __builtin_amdgcn_mfma_f32_16x16x32_bf16(a, bb, acc, 0, 0, 0);
        }
        __builtin_amdgcn_s_setprio(0);
        tit[u] = it; tpg[u] = pg;
        float yin[4] = {bf2f((unsigned short)(yi[u].x & 0xffff)), bf2f((unsigned short)(yi[u].x >> 16)),
                        bf2f((unsigned short)(yi[u].y & 0xffff)), bf2f((unsigned short)(yi[u].y >> 16))};
        for (int rr = 0; rr < 4; rr++) {
            float y = acc[rr] + yin[rr];
            yv[u][rr] = y * fsilu(zacc[rr]);
        }
    }
    __syncthreads();
#pragma unroll
    for (int u = 0; u < 2; u++)
        for (int rr = 0; rr < 4; rr++) {
            int i = tit[u] * 16 + q4 * 4 + rr;
            sGf[i * 132 + tpg[u]] = yv[u][rr];
        }
    __syncthreads();
    // prefetch residual (hides under RMS reduction)
    unsigned short xres[4];
    {
        int mt = wid >> 2, nt2 = wid & 3;
        int n = nt2 * 16 + c16;
#pragma unroll
        for (int rr = 0; rr < 4; rr++) {
            int m = mt * 16 + q4 * 4 + rr;
            xres[rr] = Xb[(rbase + m) * DM + n];
        }
    }
    {
        int row = tid >> 4, part = tid & 15;
        int d0 = part * 8;
        float g[8];
        float ss = 0.f;
        for (int t2 = 0; t2 < 8; t2++) { g[t2] = sGf[row * 132 + d0 + t2]; ss += g[t2] * g[t2]; }
        ss += __shfl_xor(ss, 1);
        ss += __shfl_xor(ss, 2);
        ss += __shfl_xor(ss, 4);
        ss += __shfl_xor(ss, 8);
        float rms = rsqrtf(ss * (1.f / 128.f) + 1e-5f);
        for (int t2 = 0; t2 < 8; t2 += 2) {
            unsigned int pk = pk2(g[t2] * rms * NW[d0 + t2], g[t2 + 1] * rms * NW[d0 + t2 + 1]);
            *(unsigned int*)&sG[row][d0 + t2] = pk;
        }
    }
    __syncthreads();
    {
        // out_proj: 16 tiles over 16 waves (mt 0..3 × nt 0..3); also stage new-x into sX2
        int mt = wid >> 2, nt = wid & 3;
        f32x4 acc = {0.f, 0.f, 0.f, 0.f};
        __builtin_amdgcn_s_setprio(1);
        for (int ks = 0; ks < 4; ks++) {
            bf16x8 a = fragld(&sG[0][0], mt * 16, ks * 32, 136);
            bf16x8 bb = *(const bf16x8*)(OWb + (size_t)(nt * 16 + c16) * 128 + ks * 32 + q4 * 8);
            acc = __builtin_amdgcn_mfma_f32_16x16x32_bf16(a, bb, acc, 0, 0, 0);
        }
        __builtin_amdgcn_s_setprio(0);
        for (int rr = 0; rr < 4; rr++) {
            int m = mt * 16 + q4 * 4 + rr;
            int n = nt * 16 + c16;
            size_t o = (rbase + m) * DM + n;
            float v = bf2f(xres[rr]) + acc[rr];
            if (last) {
                OutF[o] = v;
            } else {
                unsigned short vb = f2bf(v);
                sX2[m][n] = vb;
                float vn = __shfl_xor(v, 1);
                if (!(lane & 1)) {
                    unsigned int pk = (unsigned int)vb | ((unsigned int)f2bf(vn) << 16);
                    *(unsigned int*)(Xb + o) = pk;
                }
            }
        }
    }
    if (!last) {
        __syncthreads();
        // next-layer in_proj for rows rbase..rbase+63: 100 tile jobs over 16 waves
        for (int t = wid; t < 100; t += 16) {
            int mt2, n0;
            int isdt = (t >= 96);
            if (!isdt) { mt2 = t & 3; n0 = (t >> 2) * 16; }
            else       { mt2 = t - 96; n0 = 0; }
            bf16x8 a0 = fragld(&sX2[0][0], mt2 * 16, 0, 72);
            bf16x8 a1 = fragld(&sX2[0][0], mt2 * 16, 32, 72);
            const unsigned short* wrow = isdt ? (WbN + (size_t)(512 + c16) * 64)
                                              : (WbN + (size_t)(128 + n0 + c16) * 64);
            bf16x8 b0 = *(const bf16x8*)(wrow + q4 * 8);
            bf16x8 b1 = *(const bf16x8*)(wrow + 32 + q4 * 8);
            f32x4 acc = {0.f, 0.f, 0.f, 0.f};
            __builtin_amdgcn_s_setprio(1);
            acc = __builtin_amdgcn_mfma_f32_16x16x32_bf16(a0, b0, acc, 0, 0, 0);
            acc = __builtin_amdgcn_mfma_f32_16x16x32_bf16(a1, b1, acc, 0, 0, 0);
            __builtin_amdgcn_s_setprio(0);
            if (!isdt) {
#pragma unroll
                for (int rr = 0; rr < 4; rr++) {
                    float v = acc[rr];
                    float vn = __shfl_xor(v, 1);
                    if (!(lane & 1)) {
                        unsigned int pk = pk2(v, vn);
                        *(unsigned int*)(ZXbO + (rbase + mt2 * 16 + q4 * 4 + rr) * XW + n0 + c16) = pk;
                    }
                }
            } else {
                if (c16 < 2)
#pragma unroll
                    for (int rr = 0; rr < 4; rr++)
                        DTO[(rbase + mt2 * 16 + q4 * 4 + rr) * 2 + c16] = acc[rr];
            }
        }
    }
}

extern "C" void kernel_launch(void* const* d_in, const int* in_sizes, int n_in,
                              void* d_out, int out_size, void* d_ws, size_t ws_size,
                              hipStream_t stream) {
    const float* x       = (const float*)d_in[0];
    const float* in_w    = (const float*)d_in[1];
    const float* conv_w  = (const float*)d_in[2];
    const float* conv_b  = (const float*)d_in[3];
    const float* dt_bias = (const float*)d_in[4];
    const float* A_log   = (const float*)d_in[5];
    const float* Dp      = (const float*)d_in[6];
    const float* norm_w  = (const float*)d_in[7];
    const float* out_w   = (const float*)d_in[8];
    float* out = (float*)d_out;
    float* ws  = (float*)d_ws;

    float* dt = ws;                                        // NR*2 f32
    float* tb = dt + (size_t)NR * 2;                       // 1024 f32
    float* eb = tb + 1024;                                 // 8*64*128 f32
    unsigned short* zxb  = (unsigned short*)(eb + (size_t)B_SZ * NC * 128); // NR*384
    unsigned short* ybb  = zxb + (size_t)NR * XW;          // 8*64*8192 (tile-major)
    unsigned short* sl   = ybb + (size_t)B_SZ * NC * 8192; // 8*64*16384
    unsigned short* cbuf = sl + (size_t)B_SZ * NC * 16384; // 8*64*8192
    unsigned short* xb   = cbuf + (size_t)B_SZ * NC * 8192;// NR*64
    unsigned short* wb   = xb + (size_t)NR * DM;           // 4*576*64
    unsigned short* owb  = wb + (size_t)4 * WPAD * 64;     // 4*64*128

    k_pre<<<576 + NR * DM / 1024, 256, 0, stream>>>(in_w, out_w, x, wb, owb, xb);
    k_inproj<<<dim3(NR / 256, 7), 256, 0, stream>>>(xb, wb, zxb, dt);   // layer 0 only

    for (int layer = 0; layer < 4; layer++) {
        int nl = (layer < 3) ? layer + 1 : 3;
        k_chunk1<<<dim3(NC, B_SZ), 1024, 0, stream>>>(zxb, dt,
                conv_w + (size_t)layer * CD * 4, conv_b + (size_t)layer * CD,
                dt_bias + layer * NH, A_log + layer * NH, Dp + layer * NH,
                sl, cbuf, eb, tb, ybb);
        k_scan<<<512, 1024, 0, stream>>>(sl, tb);
        k_fused<<<dim3(NC, B_SZ), 1024, 0, stream>>>(sl, cbuf, eb, ybb,
                wb + (size_t)layer * WPAD * 64, norm_w + layer * DI,
                owb + (size_t)layer * 64 * 128, xb, out,
                wb + (size_t)nl * WPAD * 64, zxb, dt,
                (layer == 3) ? 1 : 0);
    }
}

// Round 10
// 336.907 us; speedup vs baseline: 1.0619x; 1.0549x over previous
//
#include <hip/hip_runtime.h>
#include <math.h>

#define B_SZ 8
#define SEQ  4096
#define DM   64
#define DI   128
#define NH   2
#define HD   64
#define DS   128
#define DIP  514
#define XW   384           // zxb width: xBC only (z computed in k_fused, dt in DT)
#define CD   384
#define QC   64
#define NC   64
#define NR   (B_SZ*SEQ)
#define WPAD 576

typedef __attribute__((ext_vector_type(8))) short bf16x8;
typedef __attribute__((ext_vector_type(4))) float f32x4;
typedef __attribute__((ext_vector_type(2))) __bf16 bf16x2;

__device__ __forceinline__ unsigned short f2bf(float f) {
    union { __bf16 h; unsigned short u; } x;
    x.h = (__bf16)f;
    return x.u;
}
__device__ __forceinline__ unsigned int pk2(float lo, float hi) {
    union { bf16x2 v; unsigned int u; } x;
    x.v[0] = (__bf16)lo;
    x.v[1] = (__bf16)hi;
    return x.u;
}
__device__ __forceinline__ float bf2f(unsigned short h) {
    union { unsigned int u; float f; } x; x.u = ((unsigned int)h) << 16;
    return x.f;
}
// fast SiLU: x * rcp(1+e^-x). v_rcp_f32 is 1ulp — invisible after bf16 rounding.
__device__ __forceinline__ float fsilu(float x) {
    return x * __builtin_amdgcn_rcpf(1.f + __expf(-x));
}
// A/B-operand frag: lane holds M[r0+(lane&15)][k0 + (lane>>4)*8 + j], row-major [m][k]
__device__ __forceinline__ bf16x8 fragld(const unsigned short* base, int r0, int k0, int ld) {
    int l = threadIdx.x & 63;
    return *(const bf16x8*)(base + (ptrdiff_t)(r0 + (l & 15)) * ld + k0 + (l >> 4) * 8);
}

// ---------------- setup: weight bf16 conversion + residual x conversion (merged) ----------------
__global__ __launch_bounds__(256) void k_pre(const float* __restrict__ in_w,
                                             const float* __restrict__ out_w,
                                             const float* __restrict__ X,
                                             unsigned short* __restrict__ Wb,
                                             unsigned short* __restrict__ OWb,
                                             unsigned short* __restrict__ Xb) {
    int bid = blockIdx.x;
    if (bid < 576) {
        int idx = bid * 256 + threadIdx.x;
        if (idx < 4 * WPAD * 64) {
            int l = idx / (WPAD * 64), r = idx % (WPAD * 64);
            int n = r >> 6, k = r & 63;
            float v = (n < DIP) ? in_w[(size_t)l * DIP * 64 + (size_t)n * 64 + k] : 0.f;
            Wb[idx] = f2bf(v);
        }
        if (idx < 4 * 64 * 128) OWb[idx] = f2bf(out_w[idx]);
    } else {
        int idx = ((bid - 576) * 256 + threadIdx.x) * 4;
        float4 v = *(const float4*)(X + idx);
        uint2 p;
        p.x = pk2(v.x, v.y);
        p.y = pk2(v.z, v.w);
        *(uint2*)(Xb + idx) = p;
    }
}

// ---------------- in_proj (layer 0 only): LDS-free MFMA ----------------
__global__ __launch_bounds__(256) void k_inproj(const unsigned short* __restrict__ Xb,
                                                const unsigned short* __restrict__ Wb,
                                                unsigned short* __restrict__ ZXb,
                                                float* __restrict__ DT) {
    int m0 = blockIdx.x * 256;
    int ny = blockIdx.y;               // 0..5: xBC cols; 6: dt
    int tid = threadIdx.x;
    int wid = tid >> 6, lane = tid & 63;
    int q4 = lane >> 4, c16 = lane & 15;
    int mb = m0 + wid * 64;
    bf16x8 af[4][2];
#pragma unroll
    for (int mt = 0; mt < 4; mt++)
#pragma unroll
        for (int ks = 0; ks < 2; ks++)
            af[mt][ks] = *(const bf16x8*)(Xb + (size_t)(mb + mt * 16 + c16) * 64 + ks * 32 + q4 * 8);
    if (ny < 6) {
#pragma unroll
        for (int nt = 0; nt < 4; nt++) {
            bf16x8 bf[2];
#pragma unroll
            for (int ks = 0; ks < 2; ks++)
                bf[ks] = *(const bf16x8*)(Wb + (size_t)(128 + ny * 64 + nt * 16 + c16) * 64 + ks * 32 + q4 * 8);
#pragma unroll
            for (int mt = 0; mt < 4; mt++) {
                f32x4 acc = {0.f, 0.f, 0.f, 0.f};
                acc = __builtin_amdgcn_mfma_f32_16x16x32_bf16(af[mt][0], bf[0], acc, 0, 0, 0);
                acc = __builtin_amdgcn_mfma_f32_16x16x32_bf16(af[mt][1], bf[1], acc, 0, 0, 0);
#pragma unroll
                for (int rr = 0; rr < 4; rr++) {
                    float v = acc[rr];
                    float vn = __shfl_xor(v, 1);
                    if (!(lane & 1)) {
                        unsigned int pk = pk2(v, vn);
                        *(unsigned int*)(ZXb + (size_t)(mb + mt * 16 + q4 * 4 + rr) * XW + ny * 64 + nt * 16 + c16) = pk;
                    }
                }
            }
        }
    } else {
        bf16x8 bf[2];
#pragma unroll
        for (int ks = 0; ks < 2; ks++)
            bf[ks] = *(const bf16x8*)(Wb + (size_t)(512 + c16) * 64 + ks * 32 + q4 * 8);
#pragma unroll
        for (int mt = 0; mt < 4; mt++) {
            f32x4 acc = {0.f, 0.f, 0.f, 0.f};
            acc = __builtin_amdgcn_mfma_f32_16x16x32_bf16(af[mt][0], bf[0], acc, 0, 0, 0);
            acc = __builtin_amdgcn_mfma_f32_16x16x32_bf16(af[mt][1], bf[1], acc, 0, 0, 0);
            if (c16 < 2)
#pragma unroll
                for (int rr = 0; rr < 4; rr++)
                    DT[(size_t)(mb + mt * 16 + q4 * 4 + rr) * 2 + c16] = acc[rr];
        }
    }
}

// ---------------- chunk1 (1024 thr): dt/cum, conv+SiLU, G, M, Y_intra(tile-major), SL^T ----------------
__global__ __launch_bounds__(1024, 8) void k_chunk1(
        const unsigned short* __restrict__ ZXb, const float* __restrict__ DT,
        const float* __restrict__ CW, const float* __restrict__ CB,
        const float* __restrict__ dtb, const float* __restrict__ Alog,
        const float* __restrict__ Dv,
        unsigned short* __restrict__ SL, unsigned short* __restrict__ CBuf,
        float* __restrict__ EB,
        float* __restrict__ TB, unsigned short* __restrict__ YBb) {
    __shared__ unsigned short sBt[128][72];
    __shared__ unsigned short sXt[128][72];
    __shared__ unsigned short uBC[2][64][136];
    __shared__ float s_cum[2][64], s_dt[2][64], s_w[2][64];
    unsigned short (*sM)[64][72] = (unsigned short (*)[64][72])&uBC[0][0][0];

    int c = blockIdx.x, b = blockIdx.y;
    size_t rbase = (size_t)b * SEQ + c * QC;
    int tid = threadIdx.x;
    int wid = tid >> 6, lane = tid & 63;
    int q4 = lane >> 4, c16 = lane & 15;

    // Phase A: dt/cumsum (waves 0,1) — ordered vs Phase C by the conv barrier
    if (wid < 2) {
        int h = wid, j = lane;
        float raw = DT[(rbase + j) * 2 + h] + dtb[h];
        float dt = (raw > 20.f) ? raw : log1pf(__expf(raw));
        float A = -__expf(Alog[h]);
        float x = dt * A;
        for (int off = 1; off < 64; off <<= 1) {
            float o = __shfl_up(x, off);
            if (lane >= off) x += o;
        }
        float T = __shfl(x, 63);
        s_dt[h][j] = dt;
        s_cum[h][j] = x;
        s_w[h][j] = __expf(T - x) * dt;
        EB[((size_t)(b * NC + c)) * 128 + h * 64 + j] = __expf(x);
        if (j == 0) TB[(b * 2 + h) * NC + c] = __expf(T);
    }

    // Phase B: conv(4)+bias+SiLU from global ZXb (width 384); scatter to MFMA layouts
    size_t cbbase = ((size_t)(b * NC + c)) * 8192;
    for (int e = tid; e < 64 * 96; e += 1024) {
        int j = e / 96;
        int q = e - j * 96;
        int cc = q * 4;
        int l = c * QC + j;
        const unsigned short* zp = ZXb + (rbase + j) * XW + cc;
        uint2 a0 = *(const uint2*)zp;
        uint2 a1 = make_uint2(0, 0), a2 = make_uint2(0, 0), a3 = make_uint2(0, 0);
        if (l >= 1) a1 = *(const uint2*)(zp - XW);
        if (l >= 2) a2 = *(const uint2*)(zp - 2 * XW);
        if (l >= 3) a3 = *(const uint2*)(zp - 3 * XW);
        float v[4];
#pragma unroll
        for (int u = 0; u < 4; u++) {
            unsigned int w0 = (u < 2) ? a0.x : a0.y;
            unsigned int w1 = (u < 2) ? a1.x : a1.y;
            unsigned int w2 = (u < 2) ? a2.x : a2.y;
            unsigned int w3 = (u < 2) ? a3.x : a3.y;
            int sh = (u & 1) * 16;
            float r0 = bf2f((unsigned short)(w0 >> sh));
            float r1 = bf2f((unsigned short)(w1 >> sh));
            float r2 = bf2f((unsigned short)(w2 >> sh));
            float r3 = bf2f((unsigned short)(w3 >> sh));
            float4 wv = *(const float4*)(CW + (cc + u) * 4);
            float tt = CB[cc + u] + wv.w * r0 + wv.z * r1 + wv.y * r2 + wv.x * r3;
            v[u] = fsilu(tt);
        }
        if (cc < 128) {
#pragma unroll
            for (int u = 0; u < 4; u++) sXt[cc + u][j] = f2bf(v[u]);
        } else if (cc < 256) {
            int s = cc - 128;
            unsigned int p0 = pk2(v[0], v[1]);
            unsigned int p1 = pk2(v[2], v[3]);
            *(uint2*)&uBC[0][j][s] = make_uint2(p0, p1);
#pragma unroll
            for (int u = 0; u < 4; u++) sBt[s + u][j] = f2bf(v[u]);
        } else {
            int s = cc - 256;
            unsigned int p0 = pk2(v[0], v[1]);
            unsigned int p1 = pk2(v[2], v[3]);
            *(uint2*)&uBC[1][j][s] = make_uint2(p0, p1);
            *(uint2*)(CBuf + cbbase + (size_t)j * 128 + s) = make_uint2(p0, p1);
        }
    }
    __syncthreads();

    // Phase C: G = C.B^T (16 tiles / 16 waves), stage in regs, overlay sM
    f32x4 gacc;
    {
        int it = wid >> 2, jt = wid & 3;
        f32x4 acc = {0.f, 0.f, 0.f, 0.f};
        __builtin_amdgcn_s_setprio(1);
        for (int ks = 0; ks < 4; ks++) {
            bf16x8 a = fragld(&uBC[1][0][0], it * 16, ks * 32, 136);
            bf16x8 bb = fragld(&uBC[0][0][0], jt * 16, ks * 32, 136);
            acc = __builtin_amdgcn_mfma_f32_16x16x32_bf16(a, bb, acc, 0, 0, 0);
        }
        __builtin_amdgcn_s_setprio(0);
        gacc = acc;
    }
    __syncthreads();
    {
        int it = wid >> 2, jt = wid & 3;
        int j = jt * 16 + c16;
        for (int rr = 0; rr < 4; rr++) {
            int i = it * 16 + q4 * 4 + rr;
            float gv = gacc[rr];
            for (int h = 0; h < 2; h++) {
                float m = 0.f;
                if (j <= i) m = gv * __expf(s_cum[h][i] - s_cum[h][j]) * s_dt[h][j];
                sM[h][i][j] = f2bf(m);
            }
        }
    }
    __syncthreads();

    // Phase D1: Y_intra = M_h @ X_h + D*x (32 tiles / 16 waves) — tile-major store
    size_t ybase = ((size_t)(b * NC + c)) * 8192;   // 32 tiles * 256 elems per chunk
#pragma unroll
    for (int u = 0; u < 2; u++) {
        int idx = wid * 2 + u;
        int h = idx >> 4, tt = idx & 15;
        int it = tt >> 2, pt = tt & 3;
        float dco = Dv[h];
        int pg = h * 64 + pt * 16 + c16;
        f32x4 acc;
        for (int rr = 0; rr < 4; rr++) {
            int i = it * 16 + q4 * 4 + rr;
            acc[rr] = dco * bf2f(sXt[pg][i]);
        }
        __builtin_amdgcn_s_setprio(1);
        for (int ks = 0; ks < 2; ks++) {
            bf16x8 a = fragld(&sM[h][0][0], it * 16, ks * 32, 72);
            bf16x8 bb = fragld(&sXt[0][0], h * 64 + pt * 16, ks * 32, 72);
            acc = __builtin_amdgcn_mfma_f32_16x16x32_bf16(a, bb, acc, 0, 0, 0);
        }
        __builtin_amdgcn_s_setprio(0);
        uint2 pk;
        pk.x = pk2(acc[0], acc[1]);
        pk.y = pk2(acc[2], acc[3]);
        *(uint2*)(YBb + ybase + (size_t)idx * 256 + lane * 4) = pk;
    }
    // Pre-scale sXt in place by s_w so D2 needs no per-fragment rescale
    __syncthreads();
    {
        int row = tid >> 3, c0 = (tid & 7) * 8;
        uint4 xv = *(uint4*)&sXt[row][c0];
        const float* wp = s_w[row >> 6];
        unsigned int* px = &xv.x;
        uint4 ov;
        unsigned int* po = &ov.x;
#pragma unroll
        for (int t = 0; t < 4; t++) {
            float lo = bf2f((unsigned short)(px[t] & 0xffff)) * wp[c0 + 2 * t];
            float hi = bf2f((unsigned short)(px[t] >> 16)) * wp[c0 + 2 * t + 1];
            po[t] = pk2(lo, hi);
        }
        *(uint4*)&sXt[row][c0] = ov;
    }
    __syncthreads();
    // Phase D2: SL^T[p][s] (64 tiles / 16 waves)
    size_t slbase = ((size_t)(b * NC + c)) * 16384;
#pragma unroll
    for (int u = 0; u < 4; u++) {
        int idx = wid * 4 + u;
        int ptl = idx >> 3, st = idx & 7;
        f32x4 acc = {0.f, 0.f, 0.f, 0.f};
        __builtin_amdgcn_s_setprio(1);
        for (int ks = 0; ks < 2; ks++) {
            bf16x8 a = fragld(&sXt[0][0], ptl * 16, ks * 32, 72);
            bf16x8 bb = fragld(&sBt[0][0], st * 16, ks * 32, 72);
            acc = __builtin_amdgcn_mfma_f32_16x16x32_bf16(a, bb, acc, 0, 0, 0);
        }
        __builtin_amdgcn_s_setprio(0);
        int s = st * 16 + c16;
        for (int rr = 0; rr < 4; rr++) {
            int p = ptl * 16 + q4 * 4 + rr;
            float vv = acc[rr];
            float vn = __shfl_xor(vv, 1);
            if (!(lane & 1)) {
                unsigned int pk = pk2(vv, vn);
                *(unsigned int*)(SL + slbase + (size_t)p * 128 + s) = pk;
            }
        }
    }
}

// ---------------- cross-chunk state scan: segmented, 8-deep chain (512 blk x 1024 thr) ----------------
__global__ __launch_bounds__(1024) void k_scan(unsigned short* __restrict__ SL,
                                               const float* __restrict__ TB) {
    __shared__ float sT0[8][128], sT1[8][128], sP[8];
    int tid = threadIdx.x;
    int col = tid & 127, seg = tid >> 7;
    int colg = blockIdx.x * 128 + col;         // 65536 col-pairs total
    int b2 = colg >> 13;
    int pu = colg & 8191;
    int h2 = pu >> 12;
    const float* dAp = TB + (b2 * 2 + h2) * NC;
    size_t cbase = (size_t)(b2 * NC) * 16384 + (size_t)pu * 2;
    int cc0 = seg * 8;
    unsigned int sv[8];
    float dA[8];
    float hP = 1.f, t0 = 0.f, t1 = 0.f;
#pragma unroll
    for (int k = 0; k < 8; k++) {
        sv[k] = *(unsigned int*)(SL + cbase + (size_t)(cc0 + k) * 16384);
        dA[k] = dAp[cc0 + k];
        float sx0 = bf2f((unsigned short)(sv[k] & 0xffff));
        float sx1 = bf2f((unsigned short)(sv[k] >> 16));
        t0 = t0 * dA[k] + sx0;
        t1 = t1 * dA[k] + sx1;
        hP *= dA[k];
    }
    sT0[seg][col] = t0;
    sT1[seg][col] = t1;
    if (col == 0) sP[seg] = hP;
    __syncthreads();
    float h0 = 0.f, h1 = 0.f;
    for (int s2 = 0; s2 < seg; s2++) {
        float Ps = sP[s2];
        h0 = h0 * Ps + sT0[s2][col];
        h1 = h1 * Ps + sT1[s2][col];
    }
#pragma unroll
    for (int k = 0; k < 8; k++) {
        *(unsigned int*)(SL + cbase + (size_t)(cc0 + k) * 16384) = pk2(h0, h1);
        float sx0 = bf2f((unsigned short)(sv[k] & 0xffff));
        float sx1 = bf2f((unsigned short)(sv[k] >> 16));
        h0 = h0 * dA[k] + sx0;
        h1 = h1 * dA[k] + sx1;
    }
}

// ---------------- fused (1024 thr): z-GEMM + Y_inter + gate + RMSNorm + out_proj + residual
//                  + next-layer in_proj (row-local, from LDS) ----------------
__global__ __launch_bounds__(1024, 8) void k_fused(
        const unsigned short* __restrict__ SL, const unsigned short* __restrict__ CBuf,
        const float* __restrict__ EB,
        const unsigned short* __restrict__ YBb, const unsigned short* __restrict__ Wzb,
        const float* __restrict__ NW, const unsigned short* __restrict__ OWb,
        unsigned short* __restrict__ Xb, float* __restrict__ OutF,
        const unsigned short* __restrict__ WbN,      // next layer's in_proj weights (bf16)
        unsigned short* __restrict__ ZXbO,           // next layer's xBC buffer
        float* __restrict__ DTO,                     // next layer's dt buffer
        int last) {
    __shared__ __attribute__((aligned(16))) unsigned short sH[128][136];
    __shared__ __attribute__((aligned(16))) unsigned short sE[128][136];
    float* sGf = (float*)&sH[0][0];                                   // [64][132] overlay (dead after RMS)
    unsigned short (*sG)[136] = (unsigned short (*)[136])&sE[0][0];   // [64][136] overlay
    unsigned short (*sX2)[72] = (unsigned short (*)[72])&sH[0][0];    // [64][72] overlay (written in out_proj)

    int c = blockIdx.x, b = blockIdx.y;
    size_t rbase = (size_t)b * SEQ + c * QC;
    int tid = threadIdx.x;
    int wid = tid >> 6, lane = tid & 63;
    int q4 = lane >> 4, c16 = lane & 15;
    size_t base = ((size_t)(b * NC + c)) * 16384;
    size_t ybase = ((size_t)(b * NC + c)) * 8192;

    // ---- prefetch (issues before the first barrier; latency hides under sE fill) ----
    uint2 yi[2];
    bf16x8 xa[2][2];
#pragma unroll
    for (int u = 0; u < 2; u++) {
        int idx = wid * 2 + u;
        int it = (idx & 15) >> 2;
        yi[u] = *(const uint2*)(YBb + ybase + (size_t)idx * 256 + lane * 4);
#pragma unroll
        for (int ks = 0; ks < 2; ks++)
            xa[u][ks] = fragld(Xb, (int)rbase + it * 16, ks * 32, 64);
    }

    for (int u = 0; u < 2; u++) {
        int e = u * 1024 + tid;
        int row = e >> 4, cb8 = (e & 15) * 8;
        *(uint4*)&sH[row][cb8] = *(const uint4*)(SL + base + (size_t)row * 128 + cb8);
    }
    size_t cbbase = ((size_t)(b * NC + c)) * 8192;
    size_t ebase  = ((size_t)(b * NC + c)) * 128;
    {
        int i = tid >> 4, sc = (tid & 15) * 8;
        uint4 cv = *(const uint4*)(CBuf + cbbase + (size_t)i * 128 + sc);
        float e0 = EB[ebase + i], e1 = EB[ebase + 64 + i];
        unsigned int w[4] = {cv.x, cv.y, cv.z, cv.w};
        uint4 o0, o1;
        unsigned int* po0 = &o0.x;
        unsigned int* po1 = &o1.x;
#pragma unroll
        for (int t = 0; t < 4; t++) {
            float lo = bf2f((unsigned short)(w[t] & 0xffff));
            float hi = bf2f((unsigned short)(w[t] >> 16));
            po0[t] = pk2(lo * e0, hi * e0);
            po1[t] = pk2(lo * e1, hi * e1);
        }
        *(uint4*)&sE[i][sc] = o0;
        *(uint4*)&sE[64 + i][sc] = o1;
    }
    __syncthreads();

    float yv[2][4];
    int tit[2], tpg[2];
#pragma unroll
    for (int u = 0; u < 2; u++) {
        int idx = wid * 2 + u;                 // 32 tiles / 16 waves
        int h = idx >> 4, tt = idx & 15;
        int it = tt >> 2, pt = tt & 3;
        int pg = h * 64 + pt * 16 + c16;
        f32x4 zacc = {0.f, 0.f, 0.f, 0.f};
        f32x4 acc = {0.f, 0.f, 0.f, 0.f};
        __builtin_amdgcn_s_setprio(1);
#pragma unroll
        for (int ks = 0; ks < 2; ks++) {
            bf16x8 wz = fragld(Wzb, h * 64 + pt * 16, ks * 32, 64);
            zacc = __builtin_amdgcn_mfma_f32_16x16x32_bf16(xa[u][ks], wz, zacc, 0, 0, 0);
        }
        for (int ks = 0; ks < 4; ks++) {
            bf16x8 a = fragld(&sE[0][0], h * 64 + it * 16, ks * 32, 136);
            bf16x8 bb = fragld(&sH[0][0], h * 64 + pt * 16, ks * 32, 136);
            acc = __builtin_amdgcn_mfma_f32_16x16x32_bf16(a, bb, acc, 0, 0, 0);
        }
        __builtin_amdgcn_s_setprio(0);
        tit[u] = it; tpg[u] = pg;
        float yin[4] = {bf2f((unsigned short)(yi[u].x & 0xffff)), bf2f((unsigned short)(yi[u].x >> 16)),
                        bf2f((unsigned short)(yi[u].y & 0xffff)), bf2f((unsigned short)(yi[u].y >> 16))};
        for (int rr = 0; rr < 4; rr++) {
            float y = acc[rr] + yin[rr];
            yv[u][rr] = y * fsilu(zacc[rr]);
        }
    }
    __syncthreads();
#pragma unroll
    for (int u = 0; u < 2; u++)
        for (int rr = 0; rr < 4; rr++) {
            int i = tit[u] * 16 + q4 * 4 + rr;
            sGf[i * 132 + tpg[u]] = yv[u][rr];
        }
    __syncthreads();
    {
        int row = tid >> 4, part = tid & 15;
        int d0 = part * 8;
        float g[8];
        float ss = 0.f;
        for (int t2 = 0; t2 < 8; t2++) { g[t2] = sGf[row * 132 + d0 + t2]; ss += g[t2] * g[t2]; }
        ss += __shfl_xor(ss, 1);
        ss += __shfl_xor(ss, 2);
        ss += __shfl_xor(ss, 4);
        ss += __shfl_xor(ss, 8);
        float rms = rsqrtf(ss * (1.f / 128.f) + 1e-5f);
        for (int t2 = 0; t2 < 8; t2 += 2) {
            unsigned int pk = pk2(g[t2] * rms * NW[d0 + t2], g[t2 + 1] * rms * NW[d0 + t2 + 1]);
            *(unsigned int*)&sG[row][d0 + t2] = pk;
        }
    }
    __syncthreads();
    {
        // out_proj: 16 tiles over 16 waves (mt 0..3 × nt 0..3); also stage new-x into sX2
        int mt = wid >> 2, nt = wid & 3;
        f32x4 acc = {0.f, 0.f, 0.f, 0.f};
        __builtin_amdgcn_s_setprio(1);
        for (int ks = 0; ks < 4; ks++) {
            bf16x8 a = fragld(&sG[0][0], mt * 16, ks * 32, 136);
            bf16x8 bb = *(const bf16x8*)(OWb + (size_t)(nt * 16 + c16) * 128 + ks * 32 + q4 * 8);
            acc = __builtin_amdgcn_mfma_f32_16x16x32_bf16(a, bb, acc, 0, 0, 0);
        }
        __builtin_amdgcn_s_setprio(0);
        for (int rr = 0; rr < 4; rr++) {
            int m = mt * 16 + q4 * 4 + rr;
            int n = nt * 16 + c16;
            size_t o = (rbase + m) * DM + n;
            float v = bf2f(Xb[o]) + acc[rr];
            if (last) {
                OutF[o] = v;
            } else {
                unsigned short vb = f2bf(v);
                sX2[m][n] = vb;
                float vn = __shfl_xor(v, 1);
                if (!(lane & 1)) {
                    unsigned int pk = (unsigned int)vb | ((unsigned int)f2bf(vn) << 16);
                    *(unsigned int*)(Xb + o) = pk;
                }
            }
        }
    }
    if (!last) {
        __syncthreads();
        // next-layer in_proj for rows rbase..rbase+63: 100 tile jobs over 16 waves
        for (int t = wid; t < 100; t += 16) {
            int mt2, n0;
            int isdt = (t >= 96);
            if (!isdt) { mt2 = t & 3; n0 = (t >> 2) * 16; }
            else       { mt2 = t - 96; n0 = 0; }
            bf16x8 a0 = fragld(&sX2[0][0], mt2 * 16, 0, 72);
            bf16x8 a1 = fragld(&sX2[0][0], mt2 * 16, 32, 72);
            const unsigned short* wrow = isdt ? (WbN + (size_t)(512 + c16) * 64)
                                              : (WbN + (size_t)(128 + n0 + c16) * 64);
            bf16x8 b0 = *(const bf16x8*)(wrow + q4 * 8);
            bf16x8 b1 = *(const bf16x8*)(wrow + 32 + q4 * 8);
            f32x4 acc = {0.f, 0.f, 0.f, 0.f};
            __builtin_amdgcn_s_setprio(1);
            acc = __builtin_amdgcn_mfma_f32_16x16x32_bf16(a0, b0, acc, 0, 0, 0);
            acc = __builtin_amdgcn_mfma_f32_16x16x32_bf16(a1, b1, acc, 0, 0, 0);
            __builtin_amdgcn_s_setprio(0);
            if (!isdt) {
#pragma unroll
                for (int rr = 0; rr < 4; rr++) {
                    float v = acc[rr];
                    float vn = __shfl_xor(v, 1);
                    if (!(lane & 1)) {
                        unsigned int pk = pk2(v, vn);
                        *(unsigned int*)(ZXbO + (rbase + mt2 * 16 + q4 * 4 + rr) * XW + n0 + c16) = pk;
                    }
                }
            } else {
                if (c16 < 2)
#pragma unroll
                    for (int rr = 0; rr < 4; rr++)
                        DTO[(rbase + mt2 * 16 + q4 * 4 + rr) * 2 + c16] = acc[rr];
            }
        }
    }
}

extern "C" void kernel_launch(void* const* d_in, const int* in_sizes, int n_in,
                              void* d_out, int out_size, void* d_ws, size_t ws_size,
                              hipStream_t stream) {
    const float* x       = (const float*)d_in[0];
    const float* in_w    = (const float*)d_in[1];
    const float* conv_w  = (const float*)d_in[2];
    const float* conv_b  = (const float*)d_in[3];
    const float* dt_bias = (const float*)d_in[4];
    const float* A_log   = (const float*)d_in[5];
    const float* Dp      = (const float*)d_in[6];
    const float* norm_w  = (const float*)d_in[7];
    const float* out_w   = (const float*)d_in[8];
    float* out = (float*)d_out;
    float* ws  = (float*)d_ws;

    float* dt = ws;                                        // NR*2 f32
    float* tb = dt + (size_t)NR * 2;                       // 1024 f32
    float* eb = tb + 1024;                                 // 8*64*128 f32
    unsigned short* zxb  = (unsigned short*)(eb + (size_t)B_SZ * NC * 128); // NR*384
    unsigned short* ybb  = zxb + (size_t)NR * XW;          // 8*64*8192 (tile-major)
    unsigned short* sl   = ybb + (size_t)B_SZ * NC * 8192; // 8*64*16384
    unsigned short* cbuf = sl + (size_t)B_SZ * NC * 16384; // 8*64*8192
    unsigned short* xb   = cbuf + (size_t)B_SZ * NC * 8192;// NR*64
    unsigned short* wb   = xb + (size_t)NR * DM;           // 4*576*64
    unsigned short* owb  = wb + (size_t)4 * WPAD * 64;     // 4*64*128

    k_pre<<<576 + NR * DM / 1024, 256, 0, stream>>>(in_w, out_w, x, wb, owb, xb);
    k_inproj<<<dim3(NR / 256, 7), 256, 0, stream>>>(xb, wb, zxb, dt);   // layer 0 only

    for (int layer = 0; layer < 4; layer++) {
        int nl = (layer < 3) ? layer + 1 : 3;
        k_chunk1<<<dim3(NC, B_SZ), 1024, 0, stream>>>(zxb, dt,
                conv_w + (size_t)layer * CD * 4, conv_b + (size_t)layer * CD,
                dt_bias + layer * NH, A_log + layer * NH, Dp + layer * NH,
                sl, cbuf, eb, tb, ybb);
        k_scan<<<512, 1024, 0, stream>>>(sl, tb);
        k_fused<<<dim3(NC, B_SZ), 1024, 0, stream>>>(sl, cbuf, eb, ybb,
                wb + (size_t)layer * WPAD * 64, norm_w + layer * DI,
                owb + (size_t)layer * 64 * 128, xb, out,
                wb + (size_t)nl * WPAD * 64, zxb, dt,
                (layer == 3) ? 1 : 0);
    }
}

// Round 11
// 335.792 us; speedup vs baseline: 1.0654x; 1.0033x over previous
//
#include <hip/hip_runtime.h>
#include <math.h>

#define B_SZ 8
#define SEQ  4096
#define DM   64
#define DI   128
#define NH   2
#define HD   64
#define DS   128
#define DIP  514
#define XW   384           // zxb width: xBC only (z computed in k_fused, dt in DT)
#define CD   384
#define QC   64
#define NC   64
#define NR   (B_SZ*SEQ)
#define WPAD 576

typedef __attribute__((ext_vector_type(8))) short bf16x8;
typedef __attribute__((ext_vector_type(4))) float f32x4;
typedef __attribute__((ext_vector_type(2))) __bf16 bf16x2;

__device__ __forceinline__ unsigned short f2bf(float f) {
    union { __bf16 h; unsigned short u; } x;
    x.h = (__bf16)f;
    return x.u;
}
__device__ __forceinline__ unsigned int pk2(float lo, float hi) {
    union { bf16x2 v; unsigned int u; } x;
    x.v[0] = (__bf16)lo;
    x.v[1] = (__bf16)hi;
    return x.u;
}
__device__ __forceinline__ float bf2f(unsigned short h) {
    union { unsigned int u; float f; } x; x.u = ((unsigned int)h) << 16;
    return x.f;
}
// fast SiLU: x * rcp(1+e^-x). v_rcp_f32 is 1ulp — invisible after bf16 rounding.
__device__ __forceinline__ float fsilu(float x) {
    return x * __builtin_amdgcn_rcpf(1.f + __expf(-x));
}
// A/B-operand frag: lane holds M[r0+(lane&15)][k0 + (lane>>4)*8 + j], row-major [m][k]
__device__ __forceinline__ bf16x8 fragld(const unsigned short* base, int r0, int k0, int ld) {
    int l = threadIdx.x & 63;
    return *(const bf16x8*)(base + (ptrdiff_t)(r0 + (l & 15)) * ld + k0 + (l >> 4) * 8);
}

// ---------------- setup: weight bf16 conversion + residual x conversion (merged) ----------------
__global__ __launch_bounds__(256) void k_pre(const float* __restrict__ in_w,
                                             const float* __restrict__ out_w,
                                             const float* __restrict__ X,
                                             unsigned short* __restrict__ Wb,
                                             unsigned short* __restrict__ OWb,
                                             unsigned short* __restrict__ Xb) {
    int bid = blockIdx.x;
    if (bid < 576) {
        int idx = bid * 256 + threadIdx.x;
        if (idx < 4 * WPAD * 64) {
            int l = idx / (WPAD * 64), r = idx % (WPAD * 64);
            int n = r >> 6, k = r & 63;
            float v = (n < DIP) ? in_w[(size_t)l * DIP * 64 + (size_t)n * 64 + k] : 0.f;
            Wb[idx] = f2bf(v);
        }
        if (idx < 4 * 64 * 128) OWb[idx] = f2bf(out_w[idx]);
    } else {
        int idx = ((bid - 576) * 256 + threadIdx.x) * 4;
        float4 v = *(const float4*)(X + idx);
        uint2 p;
        p.x = pk2(v.x, v.y);
        p.y = pk2(v.z, v.w);
        *(uint2*)(Xb + idx) = p;
    }
}

// ---------------- in_proj (layer 0 only): LDS-free MFMA ----------------
__global__ __launch_bounds__(256) void k_inproj(const unsigned short* __restrict__ Xb,
                                                const unsigned short* __restrict__ Wb,
                                                unsigned short* __restrict__ ZXb,
                                                float* __restrict__ DT) {
    int m0 = blockIdx.x * 256;
    int ny = blockIdx.y;               // 0..5: xBC cols; 6: dt
    int tid = threadIdx.x;
    int wid = tid >> 6, lane = tid & 63;
    int q4 = lane >> 4, c16 = lane & 15;
    int mb = m0 + wid * 64;
    bf16x8 af[4][2];
#pragma unroll
    for (int mt = 0; mt < 4; mt++)
#pragma unroll
        for (int ks = 0; ks < 2; ks++)
            af[mt][ks] = *(const bf16x8*)(Xb + (size_t)(mb + mt * 16 + c16) * 64 + ks * 32 + q4 * 8);
    if (ny < 6) {
#pragma unroll
        for (int nt = 0; nt < 4; nt++) {
            bf16x8 bf[2];
#pragma unroll
            for (int ks = 0; ks < 2; ks++)
                bf[ks] = *(const bf16x8*)(Wb + (size_t)(128 + ny * 64 + nt * 16 + c16) * 64 + ks * 32 + q4 * 8);
#pragma unroll
            for (int mt = 0; mt < 4; mt++) {
                f32x4 acc = {0.f, 0.f, 0.f, 0.f};
                acc = __builtin_amdgcn_mfma_f32_16x16x32_bf16(af[mt][0], bf[0], acc, 0, 0, 0);
                acc = __builtin_amdgcn_mfma_f32_16x16x32_bf16(af[mt][1], bf[1], acc, 0, 0, 0);
#pragma unroll
                for (int rr = 0; rr < 4; rr++) {
                    float v = acc[rr];
                    float vn = __shfl_xor(v, 1);
                    if (!(lane & 1)) {
                        unsigned int pk = pk2(v, vn);
                        *(unsigned int*)(ZXb + (size_t)(mb + mt * 16 + q4 * 4 + rr) * XW + ny * 64 + nt * 16 + c16) = pk;
                    }
                }
            }
        }
    } else {
        bf16x8 bf[2];
#pragma unroll
        for (int ks = 0; ks < 2; ks++)
            bf[ks] = *(const bf16x8*)(Wb + (size_t)(512 + c16) * 64 + ks * 32 + q4 * 8);
#pragma unroll
        for (int mt = 0; mt < 4; mt++) {
            f32x4 acc = {0.f, 0.f, 0.f, 0.f};
            acc = __builtin_amdgcn_mfma_f32_16x16x32_bf16(af[mt][0], bf[0], acc, 0, 0, 0);
            acc = __builtin_amdgcn_mfma_f32_16x16x32_bf16(af[mt][1], bf[1], acc, 0, 0, 0);
            if (c16 < 2)
#pragma unroll
                for (int rr = 0; rr < 4; rr++)
                    DT[(size_t)(mb + mt * 16 + q4 * 4 + rr) * 2 + c16] = acc[rr];
        }
    }
}

// ---------------- chunk1 (1024 thr): dt/cum, conv+SiLU, G, M, Y_intra(tile-major), SL^T ----------------
__global__ __launch_bounds__(1024, 8) void k_chunk1(
        const unsigned short* __restrict__ ZXb, const float* __restrict__ DT,
        const float* __restrict__ CW, const float* __restrict__ CB,
        const float* __restrict__ dtb, const float* __restrict__ Alog,
        const float* __restrict__ Dv,
        unsigned short* __restrict__ SL, unsigned short* __restrict__ CBuf,
        float* __restrict__ EB,
        float* __restrict__ TB, unsigned short* __restrict__ YBb) {
    __shared__ unsigned short sBt[128][72];
    __shared__ unsigned short sXt[128][72];
    __shared__ unsigned short uBC[2][64][136];
    __shared__ float s_cum[2][64], s_dt[2][64], s_w[2][64];
    unsigned short (*sM)[64][72] = (unsigned short (*)[64][72])&uBC[0][0][0];

    int c = blockIdx.x, b = blockIdx.y;
    size_t rbase = (size_t)b * SEQ + c * QC;
    int tid = threadIdx.x;
    int wid = tid >> 6, lane = tid & 63;
    int q4 = lane >> 4, c16 = lane & 15;

    // Phase A: dt/cumsum (waves 0,1) — ordered vs Phase C by the conv barrier
    if (wid < 2) {
        int h = wid, j = lane;
        float raw = DT[(rbase + j) * 2 + h] + dtb[h];
        float dt = (raw > 20.f) ? raw : log1pf(__expf(raw));
        float A = -__expf(Alog[h]);
        float x = dt * A;
        for (int off = 1; off < 64; off <<= 1) {
            float o = __shfl_up(x, off);
            if (lane >= off) x += o;
        }
        float T = __shfl(x, 63);
        s_dt[h][j] = dt;
        s_cum[h][j] = x;
        s_w[h][j] = __expf(T - x) * dt;
        EB[((size_t)(b * NC + c)) * 128 + h * 64 + j] = __expf(x);
        if (j == 0) TB[(b * 2 + h) * NC + c] = __expf(T);
    }

    // Phase B: conv(4)+bias+SiLU from global ZXb (width 384); scatter to MFMA layouts
    size_t cbbase = ((size_t)(b * NC + c)) * 8192;
    for (int e = tid; e < 64 * 96; e += 1024) {
        int j = e / 96;
        int q = e - j * 96;
        int cc = q * 4;
        const unsigned short* zp = ZXb + (rbase + j) * XW + cc;
        uint2 a0 = *(const uint2*)zp;
        uint2 a1, a2, a3;
        if (c != 0) {            // uniform (SGPR) branch: interior chunk, halo always valid
            a1 = *(const uint2*)(zp - XW);
            a2 = *(const uint2*)(zp - 2 * XW);
            a3 = *(const uint2*)(zp - 3 * XW);
        } else {
            a1 = make_uint2(0, 0); a2 = make_uint2(0, 0); a3 = make_uint2(0, 0);
            if (j >= 1) a1 = *(const uint2*)(zp - XW);
            if (j >= 2) a2 = *(const uint2*)(zp - 2 * XW);
            if (j >= 3) a3 = *(const uint2*)(zp - 3 * XW);
        }
        float v[4];
#pragma unroll
        for (int u = 0; u < 4; u++) {
            unsigned int w0 = (u < 2) ? a0.x : a0.y;
            unsigned int w1 = (u < 2) ? a1.x : a1.y;
            unsigned int w2 = (u < 2) ? a2.x : a2.y;
            unsigned int w3 = (u < 2) ? a3.x : a3.y;
            int sh = (u & 1) * 16;
            float r0 = bf2f((unsigned short)(w0 >> sh));
            float r1 = bf2f((unsigned short)(w1 >> sh));
            float r2 = bf2f((unsigned short)(w2 >> sh));
            float r3 = bf2f((unsigned short)(w3 >> sh));
            float4 wv = *(const float4*)(CW + (cc + u) * 4);
            float tt = CB[cc + u] + wv.w * r0 + wv.z * r1 + wv.y * r2 + wv.x * r3;
            v[u] = fsilu(tt);
        }
        if (cc < 128) {
#pragma unroll
            for (int u = 0; u < 4; u++) sXt[cc + u][j] = f2bf(v[u]);
        } else if (cc < 256) {
            int s = cc - 128;
            unsigned int p0 = pk2(v[0], v[1]);
            unsigned int p1 = pk2(v[2], v[3]);
            *(uint2*)&uBC[0][j][s] = make_uint2(p0, p1);
#pragma unroll
            for (int u = 0; u < 4; u++) sBt[s + u][j] = f2bf(v[u]);
        } else {
            int s = cc - 256;
            unsigned int p0 = pk2(v[0], v[1]);
            unsigned int p1 = pk2(v[2], v[3]);
            *(uint2*)&uBC[1][j][s] = make_uint2(p0, p1);
            *(uint2*)(CBuf + cbbase + (size_t)j * 128 + s) = make_uint2(p0, p1);
        }
    }
    __syncthreads();

    // Phase C: G = C.B^T (16 tiles / 16 waves), stage in regs, overlay sM
    f32x4 gacc;
    {
        int it = wid >> 2, jt = wid & 3;
        f32x4 acc = {0.f, 0.f, 0.f, 0.f};
        __builtin_amdgcn_s_setprio(1);
        for (int ks = 0; ks < 4; ks++) {
            bf16x8 a = fragld(&uBC[1][0][0], it * 16, ks * 32, 136);
            bf16x8 bb = fragld(&uBC[0][0][0], jt * 16, ks * 32, 136);
            acc = __builtin_amdgcn_mfma_f32_16x16x32_bf16(a, bb, acc, 0, 0, 0);
        }
        __builtin_amdgcn_s_setprio(0);
        gacc = acc;
    }
    __syncthreads();
    {
        int it = wid >> 2, jt = wid & 3;
        int j = jt * 16 + c16;
        for (int rr = 0; rr < 4; rr++) {
            int i = it * 16 + q4 * 4 + rr;
            float gv = gacc[rr];
            for (int h = 0; h < 2; h++) {
                float m = 0.f;
                if (j <= i) m = gv * __expf(s_cum[h][i] - s_cum[h][j]) * s_dt[h][j];
                sM[h][i][j] = f2bf(m);
            }
        }
    }
    __syncthreads();

    // Phase D1: Y_intra = M_h @ X_h + D*x (32 tiles / 16 waves) — tile-major store
    size_t ybase = ((size_t)(b * NC + c)) * 8192;   // 32 tiles * 256 elems per chunk
#pragma unroll
    for (int u = 0; u < 2; u++) {
        int idx = wid * 2 + u;
        int h = idx >> 4, tt = idx & 15;
        int it = tt >> 2, pt = tt & 3;
        float dco = Dv[h];
        int pg = h * 64 + pt * 16 + c16;
        f32x4 acc;
        for (int rr = 0; rr < 4; rr++) {
            int i = it * 16 + q4 * 4 + rr;
            acc[rr] = dco * bf2f(sXt[pg][i]);
        }
        __builtin_amdgcn_s_setprio(1);
        for (int ks = 0; ks < 2; ks++) {
            bf16x8 a = fragld(&sM[h][0][0], it * 16, ks * 32, 72);
            bf16x8 bb = fragld(&sXt[0][0], h * 64 + pt * 16, ks * 32, 72);
            acc = __builtin_amdgcn_mfma_f32_16x16x32_bf16(a, bb, acc, 0, 0, 0);
        }
        __builtin_amdgcn_s_setprio(0);
        uint2 pk;
        pk.x = pk2(acc[0], acc[1]);
        pk.y = pk2(acc[2], acc[3]);
        *(uint2*)(YBb + ybase + (size_t)idx * 256 + lane * 4) = pk;
    }
    // Pre-scale sXt in place by s_w so D2 needs no per-fragment rescale
    __syncthreads();
    {
        int row = tid >> 3, c0 = (tid & 7) * 8;
        uint4 xv = *(uint4*)&sXt[row][c0];
        const float* wp = s_w[row >> 6];
        unsigned int* px = &xv.x;
        uint4 ov;
        unsigned int* po = &ov.x;
#pragma unroll
        for (int t = 0; t < 4; t++) {
            float lo = bf2f((unsigned short)(px[t] & 0xffff)) * wp[c0 + 2 * t];
            float hi = bf2f((unsigned short)(px[t] >> 16)) * wp[c0 + 2 * t + 1];
            po[t] = pk2(lo, hi);
        }
        *(uint4*)&sXt[row][c0] = ov;
    }
    __syncthreads();
    // Phase D2: SL^T[p][s] (64 tiles / 16 waves)
    size_t slbase = ((size_t)(b * NC + c)) * 16384;
#pragma unroll
    for (int u = 0; u < 4; u++) {
        int idx = wid * 4 + u;
        int ptl = idx >> 3, st = idx & 7;
        f32x4 acc = {0.f, 0.f, 0.f, 0.f};
        __builtin_amdgcn_s_setprio(1);
        for (int ks = 0; ks < 2; ks++) {
            bf16x8 a = fragld(&sXt[0][0], ptl * 16, ks * 32, 72);
            bf16x8 bb = fragld(&sBt[0][0], st * 16, ks * 32, 72);
            acc = __builtin_amdgcn_mfma_f32_16x16x32_bf16(a, bb, acc, 0, 0, 0);
        }
        __builtin_amdgcn_s_setprio(0);
        int s = st * 16 + c16;
        for (int rr = 0; rr < 4; rr++) {
            int p = ptl * 16 + q4 * 4 + rr;
            float vv = acc[rr];
            float vn = __shfl_xor(vv, 1);
            if (!(lane & 1)) {
                unsigned int pk = pk2(vv, vn);
                *(unsigned int*)(SL + slbase + (size_t)p * 128 + s) = pk;
            }
        }
    }
}

// ---------------- cross-chunk state scan: segmented, 8-deep chain (512 blk x 1024 thr) ----------------
__global__ __launch_bounds__(1024) void k_scan(unsigned short* __restrict__ SL,
                                               const float* __restrict__ TB) {
    __shared__ float sT0[8][128], sT1[8][128], sP[8];
    int tid = threadIdx.x;
    int col = tid & 127, seg = tid >> 7;
    int colg = blockIdx.x * 128 + col;         // 65536 col-pairs total
    int b2 = colg >> 13;
    int pu = colg & 8191;
    int h2 = pu >> 12;
    const float* dAp = TB + (b2 * 2 + h2) * NC;
    size_t cbase = (size_t)(b2 * NC) * 16384 + (size_t)pu * 2;
    int cc0 = seg * 8;
    unsigned int sv[8];
    float dA[8];
    float hP = 1.f, t0 = 0.f, t1 = 0.f;
#pragma unroll
    for (int k = 0; k < 8; k++) {
        sv[k] = *(unsigned int*)(SL + cbase + (size_t)(cc0 + k) * 16384);
        dA[k] = dAp[cc0 + k];
        float sx0 = bf2f((unsigned short)(sv[k] & 0xffff));
        float sx1 = bf2f((unsigned short)(sv[k] >> 16));
        t0 = t0 * dA[k] + sx0;
        t1 = t1 * dA[k] + sx1;
        hP *= dA[k];
    }
    sT0[seg][col] = t0;
    sT1[seg][col] = t1;
    if (col == 0) sP[seg] = hP;
    __syncthreads();
    float h0 = 0.f, h1 = 0.f;
    for (int s2 = 0; s2 < seg; s2++) {
        float Ps = sP[s2];
        h0 = h0 * Ps + sT0[s2][col];
        h1 = h1 * Ps + sT1[s2][col];
    }
#pragma unroll
    for (int k = 0; k < 8; k++) {
        *(unsigned int*)(SL + cbase + (size_t)(cc0 + k) * 16384) = pk2(h0, h1);
        float sx0 = bf2f((unsigned short)(sv[k] & 0xffff));
        float sx1 = bf2f((unsigned short)(sv[k] >> 16));
        h0 = h0 * dA[k] + sx0;
        h1 = h1 * dA[k] + sx1;
    }
}

// ---------------- fused (1024 thr): z-GEMM + Y_inter + gate + RMSNorm + out_proj + residual
//                  + next-layer in_proj (row-local, from LDS) ----------------
__global__ __launch_bounds__(1024, 8) void k_fused(
        const unsigned short* __restrict__ SL, const unsigned short* __restrict__ CBuf,
        const float* __restrict__ EB,
        const unsigned short* __restrict__ YBb, const unsigned short* __restrict__ Wzb,
        const float* __restrict__ NW, const unsigned short* __restrict__ OWb,
        unsigned short* __restrict__ Xb, float* __restrict__ OutF,
        const unsigned short* __restrict__ WbN,      // next layer's in_proj weights (bf16)
        unsigned short* __restrict__ ZXbO,           // next layer's xBC buffer
        float* __restrict__ DTO,                     // next layer's dt buffer
        int last) {
    __shared__ __attribute__((aligned(16))) unsigned short sH[128][136];
    __shared__ __attribute__((aligned(16))) unsigned short sE[128][136];
    float* sGf = (float*)&sH[0][0];                                   // [64][132] overlay (dead after RMS)
    unsigned short (*sG)[136] = (unsigned short (*)[136])&sE[0][0];   // [64][136] overlay
    unsigned short (*sX2)[72] = (unsigned short (*)[72])&sH[0][0];    // [64][72] overlay (written in out_proj)

    int c = blockIdx.x, b = blockIdx.y;
    size_t rbase = (size_t)b * SEQ + c * QC;
    int tid = threadIdx.x;
    int wid = tid >> 6, lane = tid & 63;
    int q4 = lane >> 4, c16 = lane & 15;
    size_t base = ((size_t)(b * NC + c)) * 16384;
    size_t ybase = ((size_t)(b * NC + c)) * 8192;

    // ---- prefetch (issues before the first barrier; latency hides under sE fill) ----
    uint2 yi[2];
    bf16x8 xa[2][2];
#pragma unroll
    for (int u = 0; u < 2; u++) {
        int idx = wid * 2 + u;
        int it = (idx & 15) >> 2;
        yi[u] = *(const uint2*)(YBb + ybase + (size_t)idx * 256 + lane * 4);
#pragma unroll
        for (int ks = 0; ks < 2; ks++)
            xa[u][ks] = fragld(Xb, (int)rbase + it * 16, ks * 32, 64);
    }

    for (int u = 0; u < 2; u++) {
        int e = u * 1024 + tid;
        int row = e >> 4, cb8 = (e & 15) * 8;
        *(uint4*)&sH[row][cb8] = *(const uint4*)(SL + base + (size_t)row * 128 + cb8);
    }
    size_t cbbase = ((size_t)(b * NC + c)) * 8192;
    size_t ebase  = ((size_t)(b * NC + c)) * 128;
    {
        int i = tid >> 4, sc = (tid & 15) * 8;
        uint4 cv = *(const uint4*)(CBuf + cbbase + (size_t)i * 128 + sc);
        float e0 = EB[ebase + i], e1 = EB[ebase + 64 + i];
        unsigned int w[4] = {cv.x, cv.y, cv.z, cv.w};
        uint4 o0, o1;
        unsigned int* po0 = &o0.x;
        unsigned int* po1 = &o1.x;
#pragma unroll
        for (int t = 0; t < 4; t++) {
            float lo = bf2f((unsigned short)(w[t] & 0xffff));
            float hi = bf2f((unsigned short)(w[t] >> 16));
            po0[t] = pk2(lo * e0, hi * e0);
            po1[t] = pk2(lo * e1, hi * e1);
        }
        *(uint4*)&sE[i][sc] = o0;
        *(uint4*)&sE[64 + i][sc] = o1;
    }
    __syncthreads();

    float yv[2][4];
    int tit[2], tpg[2];
#pragma unroll
    for (int u = 0; u < 2; u++) {
        int idx = wid * 2 + u;                 // 32 tiles / 16 waves
        int h = idx >> 4, tt = idx & 15;
        int it = tt >> 2, pt = tt & 3;
        int pg = h * 64 + pt * 16 + c16;
        f32x4 zacc = {0.f, 0.f, 0.f, 0.f};
        f32x4 acc = {0.f, 0.f, 0.f, 0.f};
        __builtin_amdgcn_s_setprio(1);
#pragma unroll
        for (int ks = 0; ks < 2; ks++) {
            bf16x8 wz = fragld(Wzb, h * 64 + pt * 16, ks * 32, 64);
            zacc = __builtin_amdgcn_mfma_f32_16x16x32_bf16(xa[u][ks], wz, zacc, 0, 0, 0);
        }
        for (int ks = 0; ks < 4; ks++) {
            bf16x8 a = fragld(&sE[0][0], h * 64 + it * 16, ks * 32, 136);
            bf16x8 bb = fragld(&sH[0][0], h * 64 + pt * 16, ks * 32, 136);
            acc = __builtin_amdgcn_mfma_f32_16x16x32_bf16(a, bb, acc, 0, 0, 0);
        }
        __builtin_amdgcn_s_setprio(0);
        tit[u] = it; tpg[u] = pg;
        float yin[4] = {bf2f((unsigned short)(yi[u].x & 0xffff)), bf2f((unsigned short)(yi[u].x >> 16)),
                        bf2f((unsigned short)(yi[u].y & 0xffff)), bf2f((unsigned short)(yi[u].y >> 16))};
        for (int rr = 0; rr < 4; rr++) {
            float y = acc[rr] + yin[rr];
            yv[u][rr] = y * fsilu(zacc[rr]);
        }
    }
    __syncthreads();
#pragma unroll
    for (int u = 0; u < 2; u++)
        for (int rr = 0; rr < 4; rr++) {
            int i = tit[u] * 16 + q4 * 4 + rr;
            sGf[i * 132 + tpg[u]] = yv[u][rr];
        }
    __syncthreads();
    // prefetch residual (hides under RMS reduction)
    unsigned short xres[4];
    {
        int mt = wid >> 2, nt2 = wid & 3;
        int n = nt2 * 16 + c16;
#pragma unroll
        for (int rr = 0; rr < 4; rr++) {
            int m = mt * 16 + q4 * 4 + rr;
            xres[rr] = Xb[(rbase + m) * DM + n];
        }
    }
    {
        int row = tid >> 4, part = tid & 15;
        int d0 = part * 8;
        float g[8];
        float ss = 0.f;
        for (int t2 = 0; t2 < 8; t2++) { g[t2] = sGf[row * 132 + d0 + t2]; ss += g[t2] * g[t2]; }
        ss += __shfl_xor(ss, 1);
        ss += __shfl_xor(ss, 2);
        ss += __shfl_xor(ss, 4);
        ss += __shfl_xor(ss, 8);
        float rms = rsqrtf(ss * (1.f / 128.f) + 1e-5f);
        for (int t2 = 0; t2 < 8; t2 += 2) {
            unsigned int pk = pk2(g[t2] * rms * NW[d0 + t2], g[t2 + 1] * rms * NW[d0 + t2 + 1]);
            *(unsigned int*)&sG[row][d0 + t2] = pk;
        }
    }
    __syncthreads();
    {
        // out_proj: 16 tiles over 16 waves (mt 0..3 × nt 0..3); also stage new-x into sX2
        int mt = wid >> 2, nt = wid & 3;
        f32x4 acc = {0.f, 0.f, 0.f, 0.f};
        __builtin_amdgcn_s_setprio(1);
        for (int ks = 0; ks < 4; ks++) {
            bf16x8 a = fragld(&sG[0][0], mt * 16, ks * 32, 136);
            bf16x8 bb = *(const bf16x8*)(OWb + (size_t)(nt * 16 + c16) * 128 + ks * 32 + q4 * 8);
            acc = __builtin_amdgcn_mfma_f32_16x16x32_bf16(a, bb, acc, 0, 0, 0);
        }
        __builtin_amdgcn_s_setprio(0);
        for (int rr = 0; rr < 4; rr++) {
            int m = mt * 16 + q4 * 4 + rr;
            int n = nt * 16 + c16;
            size_t o = (rbase + m) * DM + n;
            float v = bf2f(xres[rr]) + acc[rr];
            if (last) {
                OutF[o] = v;
            } else {
                unsigned short vb = f2bf(v);
                sX2[m][n] = vb;
                float vn = __shfl_xor(v, 1);
                if (!(lane & 1)) {
                    unsigned int pk = (unsigned int)vb | ((unsigned int)f2bf(vn) << 16);
                    *(unsigned int*)(Xb + o) = pk;
                }
            }
        }
    }
    if (!last) {
        __syncthreads();
        // next-layer in_proj for rows rbase..rbase+63: 100 tile jobs over 16 waves
        for (int t = wid; t < 100; t += 16) {
            int mt2, n0;
            int isdt = (t >= 96);
            if (!isdt) { mt2 = t & 3; n0 = (t >> 2) * 16; }
            else       { mt2 = t - 96; n0 = 0; }
            bf16x8 a0 = fragld(&sX2[0][0], mt2 * 16, 0, 72);
            bf16x8 a1 = fragld(&sX2[0][0], mt2 * 16, 32, 72);
            const unsigned short* wrow = isdt ? (WbN + (size_t)(512 + c16) * 64)
                                              : (WbN + (size_t)(128 + n0 + c16) * 64);
            bf16x8 b0 = *(const bf16x8*)(wrow + q4 * 8);
            bf16x8 b1 = *(const bf16x8*)(wrow + 32 + q4 * 8);
            f32x4 acc = {0.f, 0.f, 0.f, 0.f};
            __builtin_amdgcn_s_setprio(1);
            acc = __builtin_amdgcn_mfma_f32_16x16x32_bf16(a0, b0, acc, 0, 0, 0);
            acc = __builtin_amdgcn_mfma_f32_16x16x32_bf16(a1, b1, acc, 0, 0, 0);
            __builtin_amdgcn_s_setprio(0);
            if (!isdt) {
#pragma unroll
                for (int rr = 0; rr < 4; rr++) {
                    float v = acc[rr];
                    float vn = __shfl_xor(v, 1);
                    if (!(lane & 1)) {
                        unsigned int pk = pk2(v, vn);
                        *(unsigned int*)(ZXbO + (rbase + mt2 * 16 + q4 * 4 + rr) * XW + n0 + c16) = pk;
                    }
                }
            } else {
                if (c16 < 2)
#pragma unroll
                    for (int rr = 0; rr < 4; rr++)
                        DTO[(rbase + mt2 * 16 + q4 * 4 + rr) * 2 + c16] = acc[rr];
            }
        }
    }
}

extern "C" void kernel_launch(void* const* d_in, const int* in_sizes, int n_in,
                              void* d_out, int out_size, void* d_ws, size_t ws_size,
                              hipStream_t stream) {
    const float* x       = (const float*)d_in[0];
    const float* in_w    = (const float*)d_in[1];
    const float* conv_w  = (const float*)d_in[2];
    const float* conv_b  = (const float*)d_in[3];
    const float* dt_bias = (const float*)d_in[4];
    const float* A_log   = (const float*)d_in[5];
    const float* Dp      = (const float*)d_in[6];
    const float* norm_w  = (const float*)d_in[7];
    const float* out_w   = (const float*)d_in[8];
    float* out = (float*)d_out;
    float* ws  = (float*)d_ws;

    float* dt = ws;                                        // NR*2 f32
    float* tb = dt + (size_t)NR * 2;                       // 1024 f32
    float* eb = tb + 1024;                                 // 8*64*128 f32
    unsigned short* zxb  = (unsigned short*)(eb + (size_t)B_SZ * NC * 128); // NR*384
    unsigned short* ybb  = zxb + (size_t)NR * XW;          // 8*64*8192 (tile-major)
    unsigned short* sl   = ybb + (size_t)B_SZ * NC * 8192; // 8*64*16384
    unsigned short* cbuf = sl + (size_t)B_SZ * NC * 16384; // 8*64*8192
    unsigned short* xb   = cbuf + (size_t)B_SZ * NC * 8192;// NR*64
    unsigned short* wb   = xb + (size_t)NR * DM;           // 4*576*64
    unsigned short* owb  = wb + (size_t)4 * WPAD * 64;     // 4*64*128

    k_pre<<<576 + NR * DM / 1024, 256, 0, stream>>>(in_w, out_w, x, wb, owb, xb);
    k_inproj<<<dim3(NR / 256, 7), 256, 0, stream>>>(xb, wb, zxb, dt);   // layer 0 only

    for (int layer = 0; layer < 4; layer++) {
        int nl = (layer < 3) ? layer + 1 : 3;
        k_chunk1<<<dim3(NC, B_SZ), 1024, 0, stream>>>(zxb, dt,
                conv_w + (size_t)layer * CD * 4, conv_b + (size_t)layer * CD,
                dt_bias + layer * NH, A_log + layer * NH, Dp + layer * NH,
                sl, cbuf, eb, tb, ybb);
        k_scan<<<512, 1024, 0, stream>>>(sl, tb);
        k_fused<<<dim3(NC, B_SZ), 1024, 0, stream>>>(sl, cbuf, eb, ybb,
                wb + (size_t)layer * WPAD * 64, norm_w + layer * DI,
                owb + (size_t)layer * 64 * 128, xb, out,
                wb + (size_t)nl * WPAD * 64, zxb, dt,
                (layer == 3) ? 1 : 0);
    }
}

// Round 12
// 330.182 us; speedup vs baseline: 1.0835x; 1.0170x over previous
//
#include <hip/hip_runtime.h>
#include <math.h>

#define B_SZ 8
#define SEQ  4096
#define DM   64
#define DI   128
#define NH   2
#define HD   64
#define DS   128
#define DIP  514
#define XW   384           // zxb width: xBC only (z computed in k_fused, dt in DT)
#define CD   384
#define QC   64
#define NC   64
#define NR   (B_SZ*SEQ)
#define WPAD 576

typedef __attribute__((ext_vector_type(8))) short bf16x8;
typedef __attribute__((ext_vector_type(4))) float f32x4;
typedef __attribute__((ext_vector_type(2))) __bf16 bf16x2;

__device__ __forceinline__ unsigned short f2bf(float f) {
    union { __bf16 h; unsigned short u; } x;
    x.h = (__bf16)f;
    return x.u;
}
__device__ __forceinline__ unsigned int pk2(float lo, float hi) {
    union { bf16x2 v; unsigned int u; } x;
    x.v[0] = (__bf16)lo;
    x.v[1] = (__bf16)hi;
    return x.u;
}
__device__ __forceinline__ float bf2f(unsigned short h) {
    union { unsigned int u; float f; } x; x.u = ((unsigned int)h) << 16;
    return x.f;
}
// fast SiLU: x * rcp(1+e^-x). v_rcp_f32 is 1ulp — invisible after bf16 rounding.
__device__ __forceinline__ float fsilu(float x) {
    return x * __builtin_amdgcn_rcpf(1.f + __expf(-x));
}
// A/B-operand frag: lane holds M[r0+(lane&15)][k0 + (lane>>4)*8 + j], row-major [m][k]
__device__ __forceinline__ bf16x8 fragld(const unsigned short* base, int r0, int k0, int ld) {
    int l = threadIdx.x & 63;
    return *(const bf16x8*)(base + (ptrdiff_t)(r0 + (l & 15)) * ld + k0 + (l >> 4) * 8);
}

// ---------------- setup: weight bf16 conversion + residual x conversion (merged) ----------------
__global__ __launch_bounds__(256) void k_pre(const float* __restrict__ in_w,
                                             const float* __restrict__ out_w,
                                             const float* __restrict__ X,
                                             unsigned short* __restrict__ Wb,
                                             unsigned short* __restrict__ OWb,
                                             unsigned short* __restrict__ Xb) {
    int bid = blockIdx.x;
    if (bid < 576) {
        int idx = bid * 256 + threadIdx.x;
        if (idx < 4 * WPAD * 64) {
            int l = idx / (WPAD * 64), r = idx % (WPAD * 64);
            int n = r >> 6, k = r & 63;
            float v = (n < DIP) ? in_w[(size_t)l * DIP * 64 + (size_t)n * 64 + k] : 0.f;
            Wb[idx] = f2bf(v);
        }
        if (idx < 4 * 64 * 128) OWb[idx] = f2bf(out_w[idx]);
    } else {
        int idx = ((bid - 576) * 256 + threadIdx.x) * 4;
        float4 v = *(const float4*)(X + idx);
        uint2 p;
        p.x = pk2(v.x, v.y);
        p.y = pk2(v.z, v.w);
        *(uint2*)(Xb + idx) = p;
    }
}

// ---------------- in_proj (layer 0 only): LDS-free MFMA ----------------
__global__ __launch_bounds__(256) void k_inproj(const unsigned short* __restrict__ Xb,
                                                const unsigned short* __restrict__ Wb,
                                                unsigned short* __restrict__ ZXb,
                                                float* __restrict__ DT) {
    int m0 = blockIdx.x * 256;
    int ny = blockIdx.y;               // 0..5: xBC cols; 6: dt
    int tid = threadIdx.x;
    int wid = tid >> 6, lane = tid & 63;
    int q4 = lane >> 4, c16 = lane & 15;
    int mb = m0 + wid * 64;
    bf16x8 af[4][2];
#pragma unroll
    for (int mt = 0; mt < 4; mt++)
#pragma unroll
        for (int ks = 0; ks < 2; ks++)
            af[mt][ks] = *(const bf16x8*)(Xb + (size_t)(mb + mt * 16 + c16) * 64 + ks * 32 + q4 * 8);
    if (ny < 6) {
#pragma unroll
        for (int nt = 0; nt < 4; nt++) {
            bf16x8 bf[2];
#pragma unroll
            for (int ks = 0; ks < 2; ks++)
                bf[ks] = *(const bf16x8*)(Wb + (size_t)(128 + ny * 64 + nt * 16 + c16) * 64 + ks * 32 + q4 * 8);
#pragma unroll
            for (int mt = 0; mt < 4; mt++) {
                f32x4 acc = {0.f, 0.f, 0.f, 0.f};
                acc = __builtin_amdgcn_mfma_f32_16x16x32_bf16(af[mt][0], bf[0], acc, 0, 0, 0);
                acc = __builtin_amdgcn_mfma_f32_16x16x32_bf16(af[mt][1], bf[1], acc, 0, 0, 0);
#pragma unroll
                for (int rr = 0; rr < 4; rr++) {
                    float v = acc[rr];
                    float vn = __shfl_xor(v, 1);
                    if (!(lane & 1)) {
                        unsigned int pk = pk2(v, vn);
                        *(unsigned int*)(ZXb + (size_t)(mb + mt * 16 + q4 * 4 + rr) * XW + ny * 64 + nt * 16 + c16) = pk;
                    }
                }
            }
        }
    } else {
        bf16x8 bf[2];
#pragma unroll
        for (int ks = 0; ks < 2; ks++)
            bf[ks] = *(const bf16x8*)(Wb + (size_t)(512 + c16) * 64 + ks * 32 + q4 * 8);
#pragma unroll
        for (int mt = 0; mt < 4; mt++) {
            f32x4 acc = {0.f, 0.f, 0.f, 0.f};
            acc = __builtin_amdgcn_mfma_f32_16x16x32_bf16(af[mt][0], bf[0], acc, 0, 0, 0);
            acc = __builtin_amdgcn_mfma_f32_16x16x32_bf16(af[mt][1], bf[1], acc, 0, 0, 0);
            if (c16 < 2)
#pragma unroll
                for (int rr = 0; rr < 4; rr++)
                    DT[(size_t)(mb + mt * 16 + q4 * 4 + rr) * 2 + c16] = acc[rr];
        }
    }
}

// ---------------- chunk1 (1024 thr): dt/cum, conv+SiLU, G, M, Y_intra(tile-major), SL^T ----------------
__global__ __launch_bounds__(1024, 8) void k_chunk1(
        const unsigned short* __restrict__ ZXb, const float* __restrict__ DT,
        const float* __restrict__ CW, const float* __restrict__ CB,
        const float* __restrict__ dtb, const float* __restrict__ Alog,
        const float* __restrict__ Dv,
        unsigned short* __restrict__ SL, unsigned short* __restrict__ CBuf,
        float* __restrict__ EB,
        float* __restrict__ TB, unsigned short* __restrict__ YBb) {
    __shared__ unsigned short sBt[128][72];
    __shared__ unsigned short sXt[128][72];
    __shared__ unsigned short uBC[2][64][136];
    __shared__ float s_cum[2][64], s_dt[2][64], s_w[2][64];
    unsigned short (*sM)[64][72] = (unsigned short (*)[64][72])&uBC[0][0][0];

    int c = blockIdx.x, b = blockIdx.y;
    size_t rbase = (size_t)b * SEQ + c * QC;
    int tid = threadIdx.x;
    int wid = tid >> 6, lane = tid & 63;
    int q4 = lane >> 4, c16 = lane & 15;

    // Phase A: dt/cumsum (waves 0,1) — ordered vs Phase C by the conv barrier
    if (wid < 2) {
        int h = wid, j = lane;
        float raw = DT[(rbase + j) * 2 + h] + dtb[h];
        float dt = (raw > 20.f) ? raw : log1pf(__expf(raw));
        float A = -__expf(Alog[h]);
        float x = dt * A;
        for (int off = 1; off < 64; off <<= 1) {
            float o = __shfl_up(x, off);
            if (lane >= off) x += o;
        }
        float T = __shfl(x, 63);
        s_dt[h][j] = dt;
        s_cum[h][j] = x;
        s_w[h][j] = __expf(T - x) * dt;
        EB[((size_t)(b * NC + c)) * 128 + h * 64 + j] = __expf(x);
        if (j == 0) TB[(b * 2 + h) * NC + c] = __expf(T);
    }

    // Phase B: conv(4)+bias+SiLU from global ZXb (width 384); scatter to MFMA layouts
    size_t cbbase = ((size_t)(b * NC + c)) * 8192;
    for (int e = tid; e < 64 * 96; e += 1024) {
        int j = e / 96;
        int q = e - j * 96;
        int cc = q * 4;
        const unsigned short* zp = ZXb + (rbase + j) * XW + cc;
        uint2 a0 = *(const uint2*)zp;
        uint2 a1, a2, a3;
        if (c != 0) {            // uniform (SGPR) branch: interior chunk, halo always valid
            a1 = *(const uint2*)(zp - XW);
            a2 = *(const uint2*)(zp - 2 * XW);
            a3 = *(const uint2*)(zp - 3 * XW);
        } else {
            a1 = make_uint2(0, 0); a2 = make_uint2(0, 0); a3 = make_uint2(0, 0);
            if (j >= 1) a1 = *(const uint2*)(zp - XW);
            if (j >= 2) a2 = *(const uint2*)(zp - 2 * XW);
            if (j >= 3) a3 = *(const uint2*)(zp - 3 * XW);
        }
        float v[4];
#pragma unroll
        for (int u = 0; u < 4; u++) {
            unsigned int w0 = (u < 2) ? a0.x : a0.y;
            unsigned int w1 = (u < 2) ? a1.x : a1.y;
            unsigned int w2 = (u < 2) ? a2.x : a2.y;
            unsigned int w3 = (u < 2) ? a3.x : a3.y;
            int sh = (u & 1) * 16;
            float r0 = bf2f((unsigned short)(w0 >> sh));
            float r1 = bf2f((unsigned short)(w1 >> sh));
            float r2 = bf2f((unsigned short)(w2 >> sh));
            float r3 = bf2f((unsigned short)(w3 >> sh));
            float4 wv = *(const float4*)(CW + (cc + u) * 4);
            float tt = CB[cc + u] + wv.w * r0 + wv.z * r1 + wv.y * r2 + wv.x * r3;
            v[u] = fsilu(tt);
        }
        if (cc < 128) {
#pragma unroll
            for (int u = 0; u < 4; u++) sXt[cc + u][j] = f2bf(v[u]);
        } else if (cc < 256) {
            int s = cc - 128;
            unsigned int p0 = pk2(v[0], v[1]);
            unsigned int p1 = pk2(v[2], v[3]);
            *(uint2*)&uBC[0][j][s] = make_uint2(p0, p1);
#pragma unroll
            for (int u = 0; u < 4; u++) sBt[s + u][j] = f2bf(v[u]);
        } else {
            int s = cc - 256;
            unsigned int p0 = pk2(v[0], v[1]);
            unsigned int p1 = pk2(v[2], v[3]);
            *(uint2*)&uBC[1][j][s] = make_uint2(p0, p1);
            *(uint2*)(CBuf + cbbase + (size_t)j * 128 + s) = make_uint2(p0, p1);
        }
    }
    __syncthreads();

    // Phase C: G = C.B^T (16 tiles / 16 waves), stage in regs, overlay sM
    f32x4 gacc;
    {
        int it = wid >> 2, jt = wid & 3;
        f32x4 acc = {0.f, 0.f, 0.f, 0.f};
        for (int ks = 0; ks < 4; ks++) {
            bf16x8 a = fragld(&uBC[1][0][0], it * 16, ks * 32, 136);
            bf16x8 bb = fragld(&uBC[0][0][0], jt * 16, ks * 32, 136);
            acc = __builtin_amdgcn_mfma_f32_16x16x32_bf16(a, bb, acc, 0, 0, 0);
        }
        gacc = acc;
    }
    __syncthreads();
    {
        int it = wid >> 2, jt = wid & 3;
        int j = jt * 16 + c16;
        for (int rr = 0; rr < 4; rr++) {
            int i = it * 16 + q4 * 4 + rr;
            float gv = gacc[rr];
            for (int h = 0; h < 2; h++) {
                float m = 0.f;
                if (j <= i) m = gv * __expf(s_cum[h][i] - s_cum[h][j]) * s_dt[h][j];
                sM[h][i][j] = f2bf(m);
            }
        }
    }
    __syncthreads();

    // Phase D1: Y_intra = M_h @ X_h + D*x (32 tiles / 16 waves) — tile-major store
    size_t ybase = ((size_t)(b * NC + c)) * 8192;   // 32 tiles * 256 elems per chunk
#pragma unroll
    for (int u = 0; u < 2; u++) {
        int idx = wid * 2 + u;
        int h = idx >> 4, tt = idx & 15;
        int it = tt >> 2, pt = tt & 3;
        float dco = Dv[h];
        int pg = h * 64 + pt * 16 + c16;
        f32x4 acc;
        for (int rr = 0; rr < 4; rr++) {
            int i = it * 16 + q4 * 4 + rr;
            acc[rr] = dco * bf2f(sXt[pg][i]);
        }
        for (int ks = 0; ks < 2; ks++) {
            bf16x8 a = fragld(&sM[h][0][0], it * 16, ks * 32, 72);
            bf16x8 bb = fragld(&sXt[0][0], h * 64 + pt * 16, ks * 32, 72);
            acc = __builtin_amdgcn_mfma_f32_16x16x32_bf16(a, bb, acc, 0, 0, 0);
        }
        uint2 pk;
        pk.x = pk2(acc[0], acc[1]);
        pk.y = pk2(acc[2], acc[3]);
        *(uint2*)(YBb + ybase + (size_t)idx * 256 + lane * 4) = pk;
    }
    // Pre-scale sXt in place by s_w so D2 needs no per-fragment rescale
    __syncthreads();
    {
        int row = tid >> 3, c0 = (tid & 7) * 8;
        uint4 xv = *(uint4*)&sXt[row][c0];
        const float* wp = s_w[row >> 6];
        unsigned int* px = &xv.x;
        uint4 ov;
        unsigned int* po = &ov.x;
#pragma unroll
        for (int t = 0; t < 4; t++) {
            float lo = bf2f((unsigned short)(px[t] & 0xffff)) * wp[c0 + 2 * t];
            float hi = bf2f((unsigned short)(px[t] >> 16)) * wp[c0 + 2 * t + 1];
            po[t] = pk2(lo, hi);
        }
        *(uint4*)&sXt[row][c0] = ov;
    }
    __syncthreads();
    // Phase D2: SL^T[p][s] (64 tiles / 16 waves)
    size_t slbase = ((size_t)(b * NC + c)) * 16384;
#pragma unroll
    for (int u = 0; u < 4; u++) {
        int idx = wid * 4 + u;
        int ptl = idx >> 3, st = idx & 7;
        f32x4 acc = {0.f, 0.f, 0.f, 0.f};
        for (int ks = 0; ks < 2; ks++) {
            bf16x8 a = fragld(&sXt[0][0], ptl * 16, ks * 32, 72);
            bf16x8 bb = fragld(&sBt[0][0], st * 16, ks * 32, 72);
            acc = __builtin_amdgcn_mfma_f32_16x16x32_bf16(a, bb, acc, 0, 0, 0);
        }
        int s = st * 16 + c16;
        for (int rr = 0; rr < 4; rr++) {
            int p = ptl * 16 + q4 * 4 + rr;
            float vv = acc[rr];
            float vn = __shfl_xor(vv, 1);
            if (!(lane & 1)) {
                unsigned int pk = pk2(vv, vn);
                *(unsigned int*)(SL + slbase + (size_t)p * 128 + s) = pk;
            }
        }
    }
}

// ---------------- cross-chunk state scan: segmented, 8-deep chain (512 blk x 1024 thr) ----------------
__global__ __launch_bounds__(1024) void k_scan(unsigned short* __restrict__ SL,
                                               const float* __restrict__ TB) {
    __shared__ float sT0[8][128], sT1[8][128], sP[8];
    int tid = threadIdx.x;
    int col = tid & 127, seg = tid >> 7;
    int colg = blockIdx.x * 128 + col;         // 65536 col-pairs total
    int b2 = colg >> 13;
    int pu = colg & 8191;
    int h2 = pu >> 12;
    const float* dAp = TB + (b2 * 2 + h2) * NC;
    size_t cbase = (size_t)(b2 * NC) * 16384 + (size_t)pu * 2;
    int cc0 = seg * 8;
    unsigned int sv[8];
    float dA[8];
    float hP = 1.f, t0 = 0.f, t1 = 0.f;
#pragma unroll
    for (int k = 0; k < 8; k++) {
        sv[k] = *(unsigned int*)(SL + cbase + (size_t)(cc0 + k) * 16384);
        dA[k] = dAp[cc0 + k];
        float sx0 = bf2f((unsigned short)(sv[k] & 0xffff));
        float sx1 = bf2f((unsigned short)(sv[k] >> 16));
        t0 = t0 * dA[k] + sx0;
        t1 = t1 * dA[k] + sx1;
        hP *= dA[k];
    }
    sT0[seg][col] = t0;
    sT1[seg][col] = t1;
    if (col == 0) sP[seg] = hP;
    __syncthreads();
    float h0 = 0.f, h1 = 0.f;
    for (int s2 = 0; s2 < seg; s2++) {
        float Ps = sP[s2];
        h0 = h0 * Ps + sT0[s2][col];
        h1 = h1 * Ps + sT1[s2][col];
    }
#pragma unroll
    for (int k = 0; k < 8; k++) {
        *(unsigned int*)(SL + cbase + (size_t)(cc0 + k) * 16384) = pk2(h0, h1);
        float sx0 = bf2f((unsigned short)(sv[k] & 0xffff));
        float sx1 = bf2f((unsigned short)(sv[k] >> 16));
        h0 = h0 * dA[k] + sx0;
        h1 = h1 * dA[k] + sx1;
    }
}

// ---------------- fused (1024 thr): z-GEMM + Y_inter + gate + RMSNorm + out_proj + residual
//                  + next-layer in_proj (row-local, from LDS) ----------------
__global__ __launch_bounds__(1024, 8) void k_fused(
        const unsigned short* __restrict__ SL, const unsigned short* __restrict__ CBuf,
        const float* __restrict__ EB,
        const unsigned short* __restrict__ YBb, const unsigned short* __restrict__ Wzb,
        const float* __restrict__ NW, const unsigned short* __restrict__ OWb,
        unsigned short* __restrict__ Xb, float* __restrict__ OutF,
        const unsigned short* __restrict__ WbN,      // next layer's in_proj weights (bf16)
        unsigned short* __restrict__ ZXbO,           // next layer's xBC buffer
        float* __restrict__ DTO,                     // next layer's dt buffer
        int last) {
    __shared__ __attribute__((aligned(16))) unsigned short sH[128][136];
    __shared__ __attribute__((aligned(16))) unsigned short sE[128][136];
    float* sGf = (float*)&sH[0][0];                                   // [64][132] overlay (dead after RMS)
    unsigned short (*sG)[136] = (unsigned short (*)[136])&sE[0][0];   // [64][136] overlay
    unsigned short (*sX2)[72] = (unsigned short (*)[72])&sH[0][0];    // [64][72] overlay (written in out_proj)

    int c = blockIdx.x, b = blockIdx.y;
    size_t rbase = (size_t)b * SEQ + c * QC;
    int tid = threadIdx.x;
    int wid = tid >> 6, lane = tid & 63;
    int q4 = lane >> 4, c16 = lane & 15;
    size_t base = ((size_t)(b * NC + c)) * 16384;
    size_t ybase = ((size_t)(b * NC + c)) * 8192;

    // ---- prefetch (issues before the first barrier; latency hides under sE fill) ----
    uint2 yi[2];
    bf16x8 xa[2][2];
#pragma unroll
    for (int u = 0; u < 2; u++) {
        int idx = wid * 2 + u;
        int it = (idx & 15) >> 2;
        yi[u] = *(const uint2*)(YBb + ybase + (size_t)idx * 256 + lane * 4);
#pragma unroll
        for (int ks = 0; ks < 2; ks++)
            xa[u][ks] = fragld(Xb, (int)rbase + it * 16, ks * 32, 64);
    }

    for (int u = 0; u < 2; u++) {
        int e = u * 1024 + tid;
        int row = e >> 4, cb8 = (e & 15) * 8;
        *(uint4*)&sH[row][cb8] = *(const uint4*)(SL + base + (size_t)row * 128 + cb8);
    }
    size_t cbbase = ((size_t)(b * NC + c)) * 8192;
    size_t ebase  = ((size_t)(b * NC + c)) * 128;
    {
        int i = tid >> 4, sc = (tid & 15) * 8;
        uint4 cv = *(const uint4*)(CBuf + cbbase + (size_t)i * 128 + sc);
        float e0 = EB[ebase + i], e1 = EB[ebase + 64 + i];
        unsigned int w[4] = {cv.x, cv.y, cv.z, cv.w};
        uint4 o0, o1;
        unsigned int* po0 = &o0.x;
        unsigned int* po1 = &o1.x;
#pragma unroll
        for (int t = 0; t < 4; t++) {
            float lo = bf2f((unsigned short)(w[t] & 0xffff));
            float hi = bf2f((unsigned short)(w[t] >> 16));
            po0[t] = pk2(lo * e0, hi * e0);
            po1[t] = pk2(lo * e1, hi * e1);
        }
        *(uint4*)&sE[i][sc] = o0;
        *(uint4*)&sE[64 + i][sc] = o1;
    }
    __syncthreads();

    float yv[2][4];
    int tit[2], tpg[2];
#pragma unroll
    for (int u = 0; u < 2; u++) {
        int idx = wid * 2 + u;                 // 32 tiles / 16 waves
        int h = idx >> 4, tt = idx & 15;
        int it = tt >> 2, pt = tt & 3;
        int pg = h * 64 + pt * 16 + c16;
        f32x4 zacc = {0.f, 0.f, 0.f, 0.f};
        f32x4 acc = {0.f, 0.f, 0.f, 0.f};
#pragma unroll
        for (int ks = 0; ks < 2; ks++) {
            bf16x8 wz = fragld(Wzb, h * 64 + pt * 16, ks * 32, 64);
            zacc = __builtin_amdgcn_mfma_f32_16x16x32_bf16(xa[u][ks], wz, zacc, 0, 0, 0);
        }
        for (int ks = 0; ks < 4; ks++) {
            bf16x8 a = fragld(&sE[0][0], h * 64 + it * 16, ks * 32, 136);
            bf16x8 bb = fragld(&sH[0][0], h * 64 + pt * 16, ks * 32, 136);
            acc = __builtin_amdgcn_mfma_f32_16x16x32_bf16(a, bb, acc, 0, 0, 0);
        }
        tit[u] = it; tpg[u] = pg;
        float yin[4] = {bf2f((unsigned short)(yi[u].x & 0xffff)), bf2f((unsigned short)(yi[u].x >> 16)),
                        bf2f((unsigned short)(yi[u].y & 0xffff)), bf2f((unsigned short)(yi[u].y >> 16))};
        for (int rr = 0; rr < 4; rr++) {
            float y = acc[rr] + yin[rr];
            yv[u][rr] = y * fsilu(zacc[rr]);
        }
    }
    __syncthreads();
#pragma unroll
    for (int u = 0; u < 2; u++)
        for (int rr = 0; rr < 4; rr++) {
            int i = tit[u] * 16 + q4 * 4 + rr;
            sGf[i * 132 + tpg[u]] = yv[u][rr];
        }
    __syncthreads();
    // prefetch residual (hides under RMS reduction)
    unsigned short xres[4];
    {
        int mt = wid >> 2, nt2 = wid & 3;
        int n = nt2 * 16 + c16;
#pragma unroll
        for (int rr = 0; rr < 4; rr++) {
            int m = mt * 16 + q4 * 4 + rr;
            xres[rr] = Xb[(rbase + m) * DM + n];
        }
    }
    {
        int row = tid >> 4, part = tid & 15;
        int d0 = part * 8;
        float g[8];
        float ss = 0.f;
        for (int t2 = 0; t2 < 8; t2++) { g[t2] = sGf[row * 132 + d0 + t2]; ss += g[t2] * g[t2]; }
        ss += __shfl_xor(ss, 1);
        ss += __shfl_xor(ss, 2);
        ss += __shfl_xor(ss, 4);
        ss += __shfl_xor(ss, 8);
        float rms = rsqrtf(ss * (1.f / 128.f) + 1e-5f);
        for (int t2 = 0; t2 < 8; t2 += 2) {
            unsigned int pk = pk2(g[t2] * rms * NW[d0 + t2], g[t2 + 1] * rms * NW[d0 + t2 + 1]);
            *(unsigned int*)&sG[row][d0 + t2] = pk;
        }
    }
    __syncthreads();
    {
        // out_proj: 16 tiles over 16 waves (mt 0..3 × nt 0..3); also stage new-x into sX2
        int mt = wid >> 2, nt = wid & 3;
        f32x4 acc = {0.f, 0.f, 0.f, 0.f};
        for (int ks = 0; ks < 4; ks++) {
            bf16x8 a = fragld(&sG[0][0], mt * 16, ks * 32, 136);
            bf16x8 bb = *(const bf16x8*)(OWb + (size_t)(nt * 16 + c16) * 128 + ks * 32 + q4 * 8);
            acc = __builtin_amdgcn_mfma_f32_16x16x32_bf16(a, bb, acc, 0, 0, 0);
        }
        for (int rr = 0; rr < 4; rr++) {
            int m = mt * 16 + q4 * 4 + rr;
            int n = nt * 16 + c16;
            size_t o = (rbase + m) * DM + n;
            float v = bf2f(xres[rr]) + acc[rr];
            if (last) {
                OutF[o] = v;
            } else {
                unsigned short vb = f2bf(v);
                sX2[m][n] = vb;
                float vn = __shfl_xor(v, 1);
                if (!(lane & 1)) {
                    unsigned int pk = (unsigned int)vb | ((unsigned int)f2bf(vn) << 16);
                    *(unsigned int*)(Xb + o) = pk;
                }
            }
        }
    }
    if (!last) {
        __syncthreads();
        // next-layer in_proj for rows rbase..rbase+63: 100 tile jobs over 16 waves
        for (int t = wid; t < 100; t += 16) {
            int mt2, n0;
            int isdt = (t >= 96);
            if (!isdt) { mt2 = t & 3; n0 = (t >> 2) * 16; }
            else       { mt2 = t - 96; n0 = 0; }
            bf16x8 a0 = fragld(&sX2[0][0], mt2 * 16, 0, 72);
            bf16x8 a1 = fragld(&sX2[0][0], mt2 * 16, 32, 72);
            const unsigned short* wrow = isdt ? (WbN + (size_t)(512 + c16) * 64)
                                              : (WbN + (size_t)(128 + n0 + c16) * 64);
            bf16x8 b0 = *(const bf16x8*)(wrow + q4 * 8);
            bf16x8 b1 = *(const bf16x8*)(wrow + 32 + q4 * 8);
            f32x4 acc = {0.f, 0.f, 0.f, 0.f};
            acc = __builtin_amdgcn_mfma_f32_16x16x32_bf16(a0, b0, acc, 0, 0, 0);
            acc = __builtin_amdgcn_mfma_f32_16x16x32_bf16(a1, b1, acc, 0, 0, 0);
            if (!isdt) {
#pragma unroll
                for (int rr = 0; rr < 4; rr++) {
                    float v = acc[rr];
                    float vn = __shfl_xor(v, 1);
                    if (!(lane & 1)) {
                        unsigned int pk = pk2(v, vn);
                        *(unsigned int*)(ZXbO + (rbase + mt2 * 16 + q4 * 4 + rr) * XW + n0 + c16) = pk;
                    }
                }
            } else {
                if (c16 < 2)
#pragma unroll
                    for (int rr = 0; rr < 4; rr++)
                        DTO[(rbase + mt2 * 16 + q4 * 4 + rr) * 2 + c16] = acc[rr];
            }
        }
    }
}

extern "C" void kernel_launch(void* const* d_in, const int* in_sizes, int n_in,
                              void* d_out, int out_size, void* d_ws, size_t ws_size,
                              hipStream_t stream) {
    const float* x       = (const float*)d_in[0];
    const float* in_w    = (const float*)d_in[1];
    const float* conv_w  = (const float*)d_in[2];
    const float* conv_b  = (const float*)d_in[3];
    const float* dt_bias = (const float*)d_in[4];
    const float* A_log   = (const float*)d_in[5];
    const float* Dp      = (const float*)d_in[6];
    const float* norm_w  = (const float*)d_in[7];
    const float* out_w   = (const float*)d_in[8];
    float* out = (float*)d_out;
    float* ws  = (float*)d_ws;

    float* dt = ws;                                        // NR*2 f32
    float* tb = dt + (size_t)NR * 2;                       // 1024 f32
    float* eb = tb + 1024;                                 // 8*64*128 f32
    unsigned short* zxb  = (unsigned short*)(eb + (size_t)B_SZ * NC * 128); // NR*384
    unsigned short* ybb  = zxb + (size_t)NR * XW;          // 8*64*8192 (tile-major)
    unsigned short* sl   = ybb + (size_t)B_SZ * NC * 8192; // 8*64*16384
    unsigned short* cbuf = sl + (size_t)B_SZ * NC * 16384; // 8*64*8192
    unsigned short* xb   = cbuf + (size_t)B_SZ * NC * 8192;// NR*64
    unsigned short* wb   = xb + (size_t)NR * DM;           // 4*576*64
    unsigned short* owb  = wb + (size_t)4 * WPAD * 64;     // 4*64*128

    k_pre<<<576 + NR * DM / 1024, 256, 0, stream>>>(in_w, out_w, x, wb, owb, xb);
    k_inproj<<<dim3(NR / 256, 7), 256, 0, stream>>>(xb, wb, zxb, dt);   // layer 0 only

    for (int layer = 0; layer < 4; layer++) {
        int nl = (layer < 3) ? layer + 1 : 3;
        k_chunk1<<<dim3(NC, B_SZ), 1024, 0, stream>>>(zxb, dt,
                conv_w + (size_t)layer * CD * 4, conv_b + (size_t)layer * CD,
                dt_bias + layer * NH, A_log + layer * NH, Dp + layer * NH,
                sl, cbuf, eb, tb, ybb);
        k_scan<<<512, 1024, 0, stream>>>(sl, tb);
        k_fused<<<dim3(NC, B_SZ), 1024, 0, stream>>>(sl, cbuf, eb, ybb,
                wb + (size_t)layer * WPAD * 64, norm_w + layer * DI,
                owb + (size_t)layer * 64 * 128, xb, out,
                wb + (size_t)nl * WPAD * 64, zxb, dt,
                (layer == 3) ? 1 : 0);
    }
}

// Round 13
// 329.739 us; speedup vs baseline: 1.0850x; 1.0013x over previous
//
#include <hip/hip_runtime.h>
#include <math.h>

#define B_SZ 8
#define SEQ  4096
#define DM   64
#define DI   128
#define NH   2
#define HD   64
#define DS   128
#define DIP  514
#define XW   384           // zxb width: xBC only (z computed in k_fused, dt in DT)
#define CD   384
#define QC   64
#define NC   64
#define NR   (B_SZ*SEQ)
#define WPAD 576

typedef __attribute__((ext_vector_type(8))) short bf16x8;
typedef __attribute__((ext_vector_type(4))) float f32x4;
typedef __attribute__((ext_vector_type(2))) __bf16 bf16x2;

__device__ __forceinline__ unsigned short f2bf(float f) {
    union { __bf16 h; unsigned short u; } x;
    x.h = (__bf16)f;
    return x.u;
}
__device__ __forceinline__ unsigned int pk2(float lo, float hi) {
    union { bf16x2 v; unsigned int u; } x;
    x.v[0] = (__bf16)lo;
    x.v[1] = (__bf16)hi;
    return x.u;
}
__device__ __forceinline__ float bf2f(unsigned short h) {
    union { unsigned int u; float f; } x; x.u = ((unsigned int)h) << 16;
    return x.f;
}
// fast SiLU: x * rcp(1+e^-x). v_rcp_f32 is 1ulp — invisible after bf16 rounding.
__device__ __forceinline__ float fsilu(float x) {
    return x * __builtin_amdgcn_rcpf(1.f + __expf(-x));
}
// A/B-operand frag: lane holds M[r0+(lane&15)][k0 + (lane>>4)*8 + j], row-major [m][k]
__device__ __forceinline__ bf16x8 fragld(const unsigned short* base, int r0, int k0, int ld) {
    int l = threadIdx.x & 63;
    return *(const bf16x8*)(base + (ptrdiff_t)(r0 + (l & 15)) * ld + k0 + (l >> 4) * 8);
}

// ---------------- setup: weight bf16 conversion + residual x conversion (merged) ----------------
__global__ __launch_bounds__(256) void k_pre(const float* __restrict__ in_w,
                                             const float* __restrict__ out_w,
                                             const float* __restrict__ X,
                                             unsigned short* __restrict__ Wb,
                                             unsigned short* __restrict__ OWb,
                                             unsigned short* __restrict__ Xb) {
    int bid = blockIdx.x;
    if (bid < 576) {
        int idx = bid * 256 + threadIdx.x;
        if (idx < 4 * WPAD * 64) {
            int l = idx / (WPAD * 64), r = idx % (WPAD * 64);
            int n = r >> 6, k = r & 63;
            float v = (n < DIP) ? in_w[(size_t)l * DIP * 64 + (size_t)n * 64 + k] : 0.f;
            Wb[idx] = f2bf(v);
        }
        if (idx < 4 * 64 * 128) OWb[idx] = f2bf(out_w[idx]);
    } else {
        int idx = ((bid - 576) * 256 + threadIdx.x) * 4;
        float4 v = *(const float4*)(X + idx);
        uint2 p;
        p.x = pk2(v.x, v.y);
        p.y = pk2(v.z, v.w);
        *(uint2*)(Xb + idx) = p;
    }
}

// ---------------- in_proj (layer 0 only): LDS-free MFMA ----------------
__global__ __launch_bounds__(256) void k_inproj(const unsigned short* __restrict__ Xb,
                                                const unsigned short* __restrict__ Wb,
                                                unsigned short* __restrict__ ZXb,
                                                float* __restrict__ DT) {
    int m0 = blockIdx.x * 256;
    int ny = blockIdx.y;               // 0..5: xBC cols; 6: dt
    int tid = threadIdx.x;
    int wid = tid >> 6, lane = tid & 63;
    int q4 = lane >> 4, c16 = lane & 15;
    int mb = m0 + wid * 64;
    bf16x8 af[4][2];
#pragma unroll
    for (int mt = 0; mt < 4; mt++)
#pragma unroll
        for (int ks = 0; ks < 2; ks++)
            af[mt][ks] = *(const bf16x8*)(Xb + (size_t)(mb + mt * 16 + c16) * 64 + ks * 32 + q4 * 8);
    if (ny < 6) {
#pragma unroll
        for (int nt = 0; nt < 4; nt++) {
            bf16x8 bf[2];
#pragma unroll
            for (int ks = 0; ks < 2; ks++)
                bf[ks] = *(const bf16x8*)(Wb + (size_t)(128 + ny * 64 + nt * 16 + c16) * 64 + ks * 32 + q4 * 8);
#pragma unroll
            for (int mt = 0; mt < 4; mt++) {
                f32x4 acc = {0.f, 0.f, 0.f, 0.f};
                acc = __builtin_amdgcn_mfma_f32_16x16x32_bf16(af[mt][0], bf[0], acc, 0, 0, 0);
                acc = __builtin_amdgcn_mfma_f32_16x16x32_bf16(af[mt][1], bf[1], acc, 0, 0, 0);
#pragma unroll
                for (int rr = 0; rr < 4; rr++) {
                    float v = acc[rr];
                    float vn = __shfl_xor(v, 1);
                    if (!(lane & 1)) {
                        unsigned int pk = pk2(v, vn);
                        *(unsigned int*)(ZXb + (size_t)(mb + mt * 16 + q4 * 4 + rr) * XW + ny * 64 + nt * 16 + c16) = pk;
                    }
                }
            }
        }
    } else {
        bf16x8 bf[2];
#pragma unroll
        for (int ks = 0; ks < 2; ks++)
            bf[ks] = *(const bf16x8*)(Wb + (size_t)(512 + c16) * 64 + ks * 32 + q4 * 8);
#pragma unroll
        for (int mt = 0; mt < 4; mt++) {
            f32x4 acc = {0.f, 0.f, 0.f, 0.f};
            acc = __builtin_amdgcn_mfma_f32_16x16x32_bf16(af[mt][0], bf[0], acc, 0, 0, 0);
            acc = __builtin_amdgcn_mfma_f32_16x16x32_bf16(af[mt][1], bf[1], acc, 0, 0, 0);
            if (c16 < 2)
#pragma unroll
                for (int rr = 0; rr < 4; rr++)
                    DT[(size_t)(mb + mt * 16 + q4 * 4 + rr) * 2 + c16] = acc[rr];
        }
    }
}

// ---------------- chunk1 (1024 thr): dt/cum, conv+SiLU, G, M, Y_intra(tile-major), SL^T ----------------
__global__ __launch_bounds__(1024, 8) void k_chunk1(
        const unsigned short* __restrict__ ZXb, const float* __restrict__ DT,
        const float* __restrict__ CW, const float* __restrict__ CB,
        const float* __restrict__ dtb, const float* __restrict__ Alog,
        const float* __restrict__ Dv,
        unsigned short* __restrict__ SL, unsigned short* __restrict__ CBuf,
        float* __restrict__ EB,
        float* __restrict__ TB, unsigned short* __restrict__ YBb) {
    __shared__ unsigned short sBt[128][72];
    __shared__ unsigned short sXt[128][72];
    __shared__ unsigned short uBC[2][64][136];
    __shared__ float s_cum[2][64], s_dt[2][64], s_w[2][64];
    unsigned short (*sM)[64][72] = (unsigned short (*)[64][72])&uBC[0][0][0];

    int c = blockIdx.x, b = blockIdx.y;
    size_t rbase = (size_t)b * SEQ + c * QC;
    int tid = threadIdx.x;
    int wid = tid >> 6, lane = tid & 63;
    int q4 = lane >> 4, c16 = lane & 15;

    // Phase A: dt/cumsum (waves 0,1) — ordered vs Phase C by the conv barrier
    if (wid < 2) {
        int h = wid, j = lane;
        float raw = DT[(rbase + j) * 2 + h] + dtb[h];
        float dt = (raw > 20.f) ? raw : log1pf(__expf(raw));
        float A = -__expf(Alog[h]);
        float x = dt * A;
        for (int off = 1; off < 64; off <<= 1) {
            float o = __shfl_up(x, off);
            if (lane >= off) x += o;
        }
        float T = __shfl(x, 63);
        s_dt[h][j] = dt;
        s_cum[h][j] = x;
        s_w[h][j] = __expf(T - x) * dt;
        EB[((size_t)(b * NC + c)) * 128 + h * 64 + j] = __expf(x);
        if (j == 0) TB[(b * 2 + h) * NC + c] = __expf(T);
    }

    // Phase B: conv(4)+bias+SiLU from global ZXb (width 384); scatter to MFMA layouts
    size_t cbbase = ((size_t)(b * NC + c)) * 8192;
    for (int e = tid; e < 64 * 96; e += 1024) {
        int j = e / 96;
        int q = e - j * 96;
        int cc = q * 4;
        const unsigned short* zp = ZXb + (rbase + j) * XW + cc;
        uint2 a0 = *(const uint2*)zp;
        uint2 a1, a2, a3;
        if (c != 0) {            // uniform (SGPR) branch: interior chunk, halo always valid
            a1 = *(const uint2*)(zp - XW);
            a2 = *(const uint2*)(zp - 2 * XW);
            a3 = *(const uint2*)(zp - 3 * XW);
        } else {
            a1 = make_uint2(0, 0); a2 = make_uint2(0, 0); a3 = make_uint2(0, 0);
            if (j >= 1) a1 = *(const uint2*)(zp - XW);
            if (j >= 2) a2 = *(const uint2*)(zp - 2 * XW);
            if (j >= 3) a3 = *(const uint2*)(zp - 3 * XW);
        }
        float v[4];
#pragma unroll
        for (int u = 0; u < 4; u++) {
            unsigned int w0 = (u < 2) ? a0.x : a0.y;
            unsigned int w1 = (u < 2) ? a1.x : a1.y;
            unsigned int w2 = (u < 2) ? a2.x : a2.y;
            unsigned int w3 = (u < 2) ? a3.x : a3.y;
            int sh = (u & 1) * 16;
            float r0 = bf2f((unsigned short)(w0 >> sh));
            float r1 = bf2f((unsigned short)(w1 >> sh));
            float r2 = bf2f((unsigned short)(w2 >> sh));
            float r3 = bf2f((unsigned short)(w3 >> sh));
            float4 wv = *(const float4*)(CW + (cc + u) * 4);
            float tt = CB[cc + u] + wv.w * r0 + wv.z * r1 + wv.y * r2 + wv.x * r3;
            v[u] = fsilu(tt);
        }
        if (cc < 128) {
#pragma unroll
            for (int u = 0; u < 4; u++) sXt[cc + u][j] = f2bf(v[u]);
        } else if (cc < 256) {
            int s = cc - 128;
            unsigned int p0 = pk2(v[0], v[1]);
            unsigned int p1 = pk2(v[2], v[3]);
            *(uint2*)&uBC[0][j][s] = make_uint2(p0, p1);
#pragma unroll
            for (int u = 0; u < 4; u++) sBt[s + u][j] = f2bf(v[u]);
        } else {
            int s = cc - 256;
            unsigned int p0 = pk2(v[0], v[1]);
            unsigned int p1 = pk2(v[2], v[3]);
            *(uint2*)&uBC[1][j][s] = make_uint2(p0, p1);
            *(uint2*)(CBuf + cbbase + (size_t)j * 128 + s) = make_uint2(p0, p1);
        }
    }
    __syncthreads();

    // Phase C: G = C.B^T (16 tiles / 16 waves), stage in regs, overlay sM
    f32x4 gacc;
    {
        int it = wid >> 2, jt = wid & 3;
        f32x4 acc = {0.f, 0.f, 0.f, 0.f};
        for (int ks = 0; ks < 4; ks++) {
            bf16x8 a = fragld(&uBC[1][0][0], it * 16, ks * 32, 136);
            bf16x8 bb = fragld(&uBC[0][0][0], jt * 16, ks * 32, 136);
            acc = __builtin_amdgcn_mfma_f32_16x16x32_bf16(a, bb, acc, 0, 0, 0);
        }
        gacc = acc;
    }
    __syncthreads();
    {
        int it = wid >> 2, jt = wid & 3;
        int j = jt * 16 + c16;
        for (int rr = 0; rr < 4; rr++) {
            int i = it * 16 + q4 * 4 + rr;
            float gv = gacc[rr];
            for (int h = 0; h < 2; h++) {
                float m = 0.f;
                if (j <= i) m = gv * __expf(s_cum[h][i] - s_cum[h][j]) * s_dt[h][j];
                sM[h][i][j] = f2bf(m);
            }
        }
    }
    __syncthreads();

    // Phase D1: Y_intra = M_h @ X_h + D*x (32 tiles / 16 waves) — tile-major store
    size_t ybase = ((size_t)(b * NC + c)) * 8192;   // 32 tiles * 256 elems per chunk
#pragma unroll
    for (int u = 0; u < 2; u++) {
        int idx = wid * 2 + u;
        int h = idx >> 4, tt = idx & 15;
        int it = tt >> 2, pt = tt & 3;
        float dco = Dv[h];
        int pg = h * 64 + pt * 16 + c16;
        f32x4 acc;
        for (int rr = 0; rr < 4; rr++) {
            int i = it * 16 + q4 * 4 + rr;
            acc[rr] = dco * bf2f(sXt[pg][i]);
        }
        for (int ks = 0; ks < 2; ks++) {
            bf16x8 a = fragld(&sM[h][0][0], it * 16, ks * 32, 72);
            bf16x8 bb = fragld(&sXt[0][0], h * 64 + pt * 16, ks * 32, 72);
            acc = __builtin_amdgcn_mfma_f32_16x16x32_bf16(a, bb, acc, 0, 0, 0);
        }
        uint2 pk;
        pk.x = pk2(acc[0], acc[1]);
        pk.y = pk2(acc[2], acc[3]);
        *(uint2*)(YBb + ybase + (size_t)idx * 256 + lane * 4) = pk;
    }
    // Pre-scale sXt in place by s_w so D2 needs no per-fragment rescale
    __syncthreads();
    {
        int row = tid >> 3, c0 = (tid & 7) * 8;
        uint4 xv = *(uint4*)&sXt[row][c0];
        const float* wp = s_w[row >> 6];
        unsigned int* px = &xv.x;
        uint4 ov;
        unsigned int* po = &ov.x;
#pragma unroll
        for (int t = 0; t < 4; t++) {
            float lo = bf2f((unsigned short)(px[t] & 0xffff)) * wp[c0 + 2 * t];
            float hi = bf2f((unsigned short)(px[t] >> 16)) * wp[c0 + 2 * t + 1];
            po[t] = pk2(lo, hi);
        }
        *(uint4*)&sXt[row][c0] = ov;
    }
    __syncthreads();
    // Phase D2: SL^T[p][s] (64 tiles / 16 waves)
    size_t slbase = ((size_t)(b * NC + c)) * 16384;
#pragma unroll
    for (int u = 0; u < 4; u++) {
        int idx = wid * 4 + u;
        int ptl = idx >> 3, st = idx & 7;
        f32x4 acc = {0.f, 0.f, 0.f, 0.f};
        for (int ks = 0; ks < 2; ks++) {
            bf16x8 a = fragld(&sXt[0][0], ptl * 16, ks * 32, 72);
            bf16x8 bb = fragld(&sBt[0][0], st * 16, ks * 32, 72);
            acc = __builtin_amdgcn_mfma_f32_16x16x32_bf16(a, bb, acc, 0, 0, 0);
        }
        int s = st * 16 + c16;
        for (int rr = 0; rr < 4; rr++) {
            int p = ptl * 16 + q4 * 4 + rr;
            float vv = acc[rr];
            float vn = __shfl_xor(vv, 1);
            if (!(lane & 1)) {
                unsigned int pk = pk2(vv, vn);
                *(unsigned int*)(SL + slbase + (size_t)p * 128 + s) = pk;
            }
        }
    }
}

// ---------------- cross-chunk state scan: segmented, 8-deep chain (512 blk x 1024 thr) ----------------
__global__ __launch_bounds__(1024) void k_scan(unsigned short* __restrict__ SL,
                                               const float* __restrict__ TB) {
    __shared__ float sT0[8][128], sT1[8][128], sP[8];
    int tid = threadIdx.x;
    int col = tid & 127, seg = tid >> 7;
    int colg = blockIdx.x * 128 + col;         // 65536 col-pairs total
    int b2 = colg >> 13;
    int pu = colg & 8191;
    int h2 = pu >> 12;
    const float* dAp = TB + (b2 * 2 + h2) * NC;
    size_t cbase = (size_t)(b2 * NC) * 16384 + (size_t)pu * 2;
    int cc0 = seg * 8;
    unsigned int sv[8];
    float dA[8];
    float hP = 1.f, t0 = 0.f, t1 = 0.f;
#pragma unroll
    for (int k = 0; k < 8; k++) {
        sv[k] = *(unsigned int*)(SL + cbase + (size_t)(cc0 + k) * 16384);
        dA[k] = dAp[cc0 + k];
        float sx0 = bf2f((unsigned short)(sv[k] & 0xffff));
        float sx1 = bf2f((unsigned short)(sv[k] >> 16));
        t0 = t0 * dA[k] + sx0;
        t1 = t1 * dA[k] + sx1;
        hP *= dA[k];
    }
    sT0[seg][col] = t0;
    sT1[seg][col] = t1;
    if (col == 0) sP[seg] = hP;
    __syncthreads();
    float h0 = 0.f, h1 = 0.f;
    for (int s2 = 0; s2 < seg; s2++) {
        float Ps = sP[s2];
        h0 = h0 * Ps + sT0[s2][col];
        h1 = h1 * Ps + sT1[s2][col];
    }
#pragma unroll
    for (int k = 0; k < 8; k++) {
        *(unsigned int*)(SL + cbase + (size_t)(cc0 + k) * 16384) = pk2(h0, h1);
        float sx0 = bf2f((unsigned short)(sv[k] & 0xffff));
        float sx1 = bf2f((unsigned short)(sv[k] >> 16));
        h0 = h0 * dA[k] + sx0;
        h1 = h1 * dA[k] + sx1;
    }
}

// ---------------- fused (1024 thr): z-GEMM + Y_inter + gate + RMSNorm + out_proj + residual
//                  + next-layer in_proj (row-local, from LDS) ----------------
__global__ __launch_bounds__(1024, 8) void k_fused(
        const unsigned short* __restrict__ SL, const unsigned short* __restrict__ CBuf,
        const float* __restrict__ EB,
        const unsigned short* __restrict__ YBb, const unsigned short* __restrict__ Wzb,
        const float* __restrict__ NW, const unsigned short* __restrict__ OWb,
        unsigned short* __restrict__ Xb, float* __restrict__ OutF,
        const unsigned short* __restrict__ WbN,      // next layer's in_proj weights (bf16)
        unsigned short* __restrict__ ZXbO,           // next layer's xBC buffer
        float* __restrict__ DTO,                     // next layer's dt buffer
        int last) {
    __shared__ __attribute__((aligned(16))) unsigned short sH[128][136];
    __shared__ __attribute__((aligned(16))) unsigned short sE[128][136];
    float* sGf = (float*)&sH[0][0];                                   // [64][132] overlay (dead after RMS)
    unsigned short (*sG)[136] = (unsigned short (*)[136])&sE[0][0];   // [64][136] overlay
    unsigned short (*sX2)[72] = (unsigned short (*)[72])&sH[0][0];    // [64][72] overlay (written in out_proj)

    int c = blockIdx.x, b = blockIdx.y;
    size_t rbase = (size_t)b * SEQ + c * QC;
    int tid = threadIdx.x;
    int wid = tid >> 6, lane = tid & 63;
    int q4 = lane >> 4, c16 = lane & 15;
    size_t base = ((size_t)(b * NC + c)) * 16384;
    size_t ybase = ((size_t)(b * NC + c)) * 8192;

    // ---- prefetch (issues before the first barrier; latency hides under sH/sE fill):
    //      YBb tile, Xb fragments, AND Wzb z-weight fragments (L2-hot broadcast) ----
    uint2 yi[2];
    bf16x8 xa[2][2], wz[2][2];
#pragma unroll
    for (int u = 0; u < 2; u++) {
        int idx = wid * 2 + u;
        int h = idx >> 4, tt = idx & 15;
        int it = tt >> 2, pt = tt & 3;
        yi[u] = *(const uint2*)(YBb + ybase + (size_t)idx * 256 + lane * 4);
#pragma unroll
        for (int ks = 0; ks < 2; ks++) {
            xa[u][ks] = fragld(Xb, (int)rbase + it * 16, ks * 32, 64);
            wz[u][ks] = fragld(Wzb, h * 64 + pt * 16, ks * 32, 64);
        }
    }

    for (int u = 0; u < 2; u++) {
        int e = u * 1024 + tid;
        int row = e >> 4, cb8 = (e & 15) * 8;
        *(uint4*)&sH[row][cb8] = *(const uint4*)(SL + base + (size_t)row * 128 + cb8);
    }
    size_t cbbase = ((size_t)(b * NC + c)) * 8192;
    size_t ebase  = ((size_t)(b * NC + c)) * 128;
    {
        int i = tid >> 4, sc = (tid & 15) * 8;
        uint4 cv = *(const uint4*)(CBuf + cbbase + (size_t)i * 128 + sc);
        float e0 = EB[ebase + i], e1 = EB[ebase + 64 + i];
        unsigned int w[4] = {cv.x, cv.y, cv.z, cv.w};
        uint4 o0, o1;
        unsigned int* po0 = &o0.x;
        unsigned int* po1 = &o1.x;
#pragma unroll
        for (int t = 0; t < 4; t++) {
            float lo = bf2f((unsigned short)(w[t] & 0xffff));
            float hi = bf2f((unsigned short)(w[t] >> 16));
            po0[t] = pk2(lo * e0, hi * e0);
            po1[t] = pk2(lo * e1, hi * e1);
        }
        *(uint4*)&sE[i][sc] = o0;
        *(uint4*)&sE[64 + i][sc] = o1;
    }
    __syncthreads();

    float yv[2][4];
    int tit[2], tpg[2];
#pragma unroll
    for (int u = 0; u < 2; u++) {
        int idx = wid * 2 + u;                 // 32 tiles / 16 waves
        int h = idx >> 4, tt = idx & 15;
        int it = tt >> 2, pt = tt & 3;
        int pg = h * 64 + pt * 16 + c16;
        f32x4 zacc = {0.f, 0.f, 0.f, 0.f};
        f32x4 acc = {0.f, 0.f, 0.f, 0.f};
#pragma unroll
        for (int ks = 0; ks < 2; ks++)
            zacc = __builtin_amdgcn_mfma_f32_16x16x32_bf16(xa[u][ks], wz[u][ks], zacc, 0, 0, 0);
        for (int ks = 0; ks < 4; ks++) {
            bf16x8 a = fragld(&sE[0][0], h * 64 + it * 16, ks * 32, 136);
            bf16x8 bb = fragld(&sH[0][0], h * 64 + pt * 16, ks * 32, 136);
            acc = __builtin_amdgcn_mfma_f32_16x16x32_bf16(a, bb, acc, 0, 0, 0);
        }
        tit[u] = it; tpg[u] = pg;
        float yin[4] = {bf2f((unsigned short)(yi[u].x & 0xffff)), bf2f((unsigned short)(yi[u].x >> 16)),
                        bf2f((unsigned short)(yi[u].y & 0xffff)), bf2f((unsigned short)(yi[u].y >> 16))};
        for (int rr = 0; rr < 4; rr++) {
            float y = acc[rr] + yin[rr];
            yv[u][rr] = y * fsilu(zacc[rr]);
        }
    }
    __syncthreads();
#pragma unroll
    for (int u = 0; u < 2; u++)
        for (int rr = 0; rr < 4; rr++) {
            int i = tit[u] * 16 + q4 * 4 + rr;
            sGf[i * 132 + tpg[u]] = yv[u][rr];
        }
    __syncthreads();
    // prefetch residual + out_proj weights (both hide under RMS reduction;
    // yi/xa/wz registers are dead here so VGPR peak is unchanged)
    unsigned short xres[4];
    bf16x8 owf[4];
    {
        int mt = wid >> 2, nt2 = wid & 3;
        int n = nt2 * 16 + c16;
#pragma unroll
        for (int rr = 0; rr < 4; rr++) {
            int m = mt * 16 + q4 * 4 + rr;
            xres[rr] = Xb[(rbase + m) * DM + n];
        }
#pragma unroll
        for (int ks = 0; ks < 4; ks++)
            owf[ks] = *(const bf16x8*)(OWb + (size_t)(nt2 * 16 + c16) * 128 + ks * 32 + q4 * 8);
    }
    {
        int row = tid >> 4, part = tid & 15;
        int d0 = part * 8;
        float g[8];
        float ss = 0.f;
        for (int t2 = 0; t2 < 8; t2++) { g[t2] = sGf[row * 132 + d0 + t2]; ss += g[t2] * g[t2]; }
        ss += __shfl_xor(ss, 1);
        ss += __shfl_xor(ss, 2);
        ss += __shfl_xor(ss, 4);
        ss += __shfl_xor(ss, 8);
        float rms = rsqrtf(ss * (1.f / 128.f) + 1e-5f);
        for (int t2 = 0; t2 < 8; t2 += 2) {
            unsigned int pk = pk2(g[t2] * rms * NW[d0 + t2], g[t2 + 1] * rms * NW[d0 + t2 + 1]);
            *(unsigned int*)&sG[row][d0 + t2] = pk;
        }
    }
    __syncthreads();
    {
        // out_proj: 16 tiles over 16 waves (mt 0..3 × nt 0..3); also stage new-x into sX2
        int mt = wid >> 2, nt = wid & 3;
        f32x4 acc = {0.f, 0.f, 0.f, 0.f};
        for (int ks = 0; ks < 4; ks++) {
            bf16x8 a = fragld(&sG[0][0], mt * 16, ks * 32, 136);
            acc = __builtin_amdgcn_mfma_f32_16x16x32_bf16(a, owf[ks], acc, 0, 0, 0);
        }
        for (int rr = 0; rr < 4; rr++) {
            int m = mt * 16 + q4 * 4 + rr;
            int n = nt * 16 + c16;
            size_t o = (rbase + m) * DM + n;
            float v = bf2f(xres[rr]) + acc[rr];
            if (last) {
                OutF[o] = v;
            } else {
                unsigned short vb = f2bf(v);
                sX2[m][n] = vb;
                float vn = __shfl_xor(v, 1);
                if (!(lane & 1)) {
                    unsigned int pk = (unsigned int)vb | ((unsigned int)f2bf(vn) << 16);
                    *(unsigned int*)(Xb + o) = pk;
                }
            }
        }
    }
    if (!last) {
        __syncthreads();
        // next-layer in_proj for rows rbase..rbase+63: 100 tile jobs over 16 waves
        for (int t = wid; t < 100; t += 16) {
            int mt2, n0;
            int isdt = (t >= 96);
            if (!isdt) { mt2 = t & 3; n0 = (t >> 2) * 16; }
            else       { mt2 = t - 96; n0 = 0; }
            bf16x8 a0 = fragld(&sX2[0][0], mt2 * 16, 0, 72);
            bf16x8 a1 = fragld(&sX2[0][0], mt2 * 16, 32, 72);
            const unsigned short* wrow = isdt ? (WbN + (size_t)(512 + c16) * 64)
                                              : (WbN + (size_t)(128 + n0 + c16) * 64);
            bf16x8 b0 = *(const bf16x8*)(wrow + q4 * 8);
            bf16x8 b1 = *(const bf16x8*)(wrow + 32 + q4 * 8);
            f32x4 acc = {0.f, 0.f, 0.f, 0.f};
            acc = __builtin_amdgcn_mfma_f32_16x16x32_bf16(a0, b0, acc, 0, 0, 0);
            acc = __builtin_amdgcn_mfma_f32_16x16x32_bf16(a1, b1, acc, 0, 0, 0);
            if (!isdt) {
#pragma unroll
                for (int rr = 0; rr < 4; rr++) {
                    float v = acc[rr];
                    float vn = __shfl_xor(v, 1);
                    if (!(lane & 1)) {
                        unsigned int pk = pk2(v, vn);
                        *(unsigned int*)(ZXbO + (rbase + mt2 * 16 + q4 * 4 + rr) * XW + n0 + c16) = pk;
                    }
                }
            } else {
                if (c16 < 2)
#pragma unroll
                    for (int rr = 0; rr < 4; rr++)
                        DTO[(rbase + mt2 * 16 + q4 * 4 + rr) * 2 + c16] = acc[rr];
            }
        }
    }
}

extern "C" void kernel_launch(void* const* d_in, const int* in_sizes, int n_in,
                              void* d_out, int out_size, void* d_ws, size_t ws_size,
                              hipStream_t stream) {
    const float* x       = (const float*)d_in[0];
    const float* in_w    = (const float*)d_in[1];
    const float* conv_w  = (const float*)d_in[2];
    const float* conv_b  = (const float*)d_in[3];
    const float* dt_bias = (const float*)d_in[4];
    const float* A_log   = (const float*)d_in[5];
    const float* Dp      = (const float*)d_in[6];
    const float* norm_w  = (const float*)d_in[7];
    const float* out_w   = (const float*)d_in[8];
    float* out = (float*)d_out;
    float* ws  = (float*)d_ws;

    float* dt = ws;                                        // NR*2 f32
    float* tb = dt + (size_t)NR * 2;                       // 1024 f32
    float* eb = tb + 1024;                                 // 8*64*128 f32
    unsigned short* zxb  = (unsigned short*)(eb + (size_t)B_SZ * NC * 128); // NR*384
    unsigned short* ybb  = zxb + (size_t)NR * XW;          // 8*64*8192 (tile-major)
    unsigned short* sl   = ybb + (size_t)B_SZ * NC * 8192; // 8*64*16384
    unsigned short* cbuf = sl + (size_t)B_SZ * NC * 16384; // 8*64*8192
    unsigned short* xb   = cbuf + (size_t)B_SZ * NC * 8192;// NR*64
    unsigned short* wb   = xb + (size_t)NR * DM;           // 4*576*64
    unsigned short* owb  = wb + (size_t)4 * WPAD * 64;     // 4*64*128

    k_pre<<<576 + NR * DM / 1024, 256, 0, stream>>>(in_w, out_w, x, wb, owb, xb);
    k_inproj<<<dim3(NR / 256, 7), 256, 0, stream>>>(xb, wb, zxb, dt);   // layer 0 only

    for (int layer = 0; layer < 4; layer++) {
        int nl = (layer < 3) ? layer + 1 : 3;
        k_chunk1<<<dim3(NC, B_SZ), 1024, 0, stream>>>(zxb, dt,
                conv_w + (size_t)layer * CD * 4, conv_b + (size_t)layer * CD,
                dt_bias + layer * NH, A_log + layer * NH, Dp + layer * NH,
                sl, cbuf, eb, tb, ybb);
        k_scan<<<512, 1024, 0, stream>>>(sl, tb);
        k_fused<<<dim3(NC, B_SZ), 1024, 0, stream>>>(sl, cbuf, eb, ybb,
                wb + (size_t)layer * WPAD * 64, norm_w + layer * DI,
                owb + (size_t)layer * 64 * 128, xb, out,
                wb + (size_t)nl * WPAD * 64, zxb, dt,
                (layer == 3) ? 1 : 0);
    }
}

// Round 14
// 325.303 us; speedup vs baseline: 1.0998x; 1.0136x over previous
//
#include <hip/hip_runtime.h>
#include <math.h>

#define B_SZ 8
#define SEQ  4096
#define DM   64
#define DI   128
#define NH   2
#define HD   64
#define DS   128
#define DIP  514
#define XW   384           // zxb width: xBC only (z computed in k_fused, dt in DT)
#define CD   384
#define QC   64
#define NC   64
#define NR   (B_SZ*SEQ)
#define WPAD 576

typedef __attribute__((ext_vector_type(8))) short bf16x8;
typedef __attribute__((ext_vector_type(4))) float f32x4;
typedef __attribute__((ext_vector_type(2))) __bf16 bf16x2;

__device__ __forceinline__ unsigned short f2bf(float f) {
    union { __bf16 h; unsigned short u; } x;
    x.h = (__bf16)f;
    return x.u;
}
__device__ __forceinline__ unsigned int pk2(float lo, float hi) {
    union { bf16x2 v; unsigned int u; } x;
    x.v[0] = (__bf16)lo;
    x.v[1] = (__bf16)hi;
    return x.u;
}
__device__ __forceinline__ float bf2f(unsigned short h) {
    union { unsigned int u; float f; } x; x.u = ((unsigned int)h) << 16;
    return x.f;
}
// fast SiLU: x * rcp(1+e^-x). v_rcp_f32 is 1ulp — invisible after bf16 rounding.
__device__ __forceinline__ float fsilu(float x) {
    return x * __builtin_amdgcn_rcpf(1.f + __expf(-x));
}
// A/B-operand frag: lane holds M[r0+(lane&15)][k0 + (lane>>4)*8 + j], row-major [m][k]
__device__ __forceinline__ bf16x8 fragld(const unsigned short* base, int r0, int k0, int ld) {
    int l = threadIdx.x & 63;
    return *(const bf16x8*)(base + (ptrdiff_t)(r0 + (l & 15)) * ld + k0 + (l >> 4) * 8);
}

// ---------------- setup: weight bf16 conversion + residual x conversion (merged) ----------------
__global__ __launch_bounds__(256) void k_pre(const float* __restrict__ in_w,
                                             const float* __restrict__ out_w,
                                             const float* __restrict__ X,
                                             unsigned short* __restrict__ Wb,
                                             unsigned short* __restrict__ OWb,
                                             unsigned short* __restrict__ Xb) {
    int bid = blockIdx.x;
    if (bid < 576) {
        int idx = bid * 256 + threadIdx.x;
        if (idx < 4 * WPAD * 64) {
            int l = idx / (WPAD * 64), r = idx % (WPAD * 64);
            int n = r >> 6, k = r & 63;
            float v = (n < DIP) ? in_w[(size_t)l * DIP * 64 + (size_t)n * 64 + k] : 0.f;
            Wb[idx] = f2bf(v);
        }
        if (idx < 4 * 64 * 128) OWb[idx] = f2bf(out_w[idx]);
    } else {
        int idx = ((bid - 576) * 256 + threadIdx.x) * 4;
        float4 v = *(const float4*)(X + idx);
        uint2 p;
        p.x = pk2(v.x, v.y);
        p.y = pk2(v.z, v.w);
        *(uint2*)(Xb + idx) = p;
    }
}

// ---------------- in_proj (layer 0 only): LDS-free MFMA ----------------
__global__ __launch_bounds__(256) void k_inproj(const unsigned short* __restrict__ Xb,
                                                const unsigned short* __restrict__ Wb,
                                                unsigned short* __restrict__ ZXb,
                                                float* __restrict__ DT) {
    int m0 = blockIdx.x * 256;
    int ny = blockIdx.y;               // 0..5: xBC cols; 6: dt
    int tid = threadIdx.x;
    int wid = tid >> 6, lane = tid & 63;
    int q4 = lane >> 4, c16 = lane & 15;
    int mb = m0 + wid * 64;
    bf16x8 af[4][2];
#pragma unroll
    for (int mt = 0; mt < 4; mt++)
#pragma unroll
        for (int ks = 0; ks < 2; ks++)
            af[mt][ks] = *(const bf16x8*)(Xb + (size_t)(mb + mt * 16 + c16) * 64 + ks * 32 + q4 * 8);
    if (ny < 6) {
#pragma unroll
        for (int nt = 0; nt < 4; nt++) {
            bf16x8 bf[2];
#pragma unroll
            for (int ks = 0; ks < 2; ks++)
                bf[ks] = *(const bf16x8*)(Wb + (size_t)(128 + ny * 64 + nt * 16 + c16) * 64 + ks * 32 + q4 * 8);
#pragma unroll
            for (int mt = 0; mt < 4; mt++) {
                f32x4 acc = {0.f, 0.f, 0.f, 0.f};
                acc = __builtin_amdgcn_mfma_f32_16x16x32_bf16(af[mt][0], bf[0], acc, 0, 0, 0);
                acc = __builtin_amdgcn_mfma_f32_16x16x32_bf16(af[mt][1], bf[1], acc, 0, 0, 0);
#pragma unroll
                for (int rr = 0; rr < 4; rr++) {
                    float v = acc[rr];
                    float vn = __shfl_xor(v, 1);
                    if (!(lane & 1)) {
                        unsigned int pk = pk2(v, vn);
                        *(unsigned int*)(ZXb + (size_t)(mb + mt * 16 + q4 * 4 + rr) * XW + ny * 64 + nt * 16 + c16) = pk;
                    }
                }
            }
        }
    } else {
        bf16x8 bf[2];
#pragma unroll
        for (int ks = 0; ks < 2; ks++)
            bf[ks] = *(const bf16x8*)(Wb + (size_t)(512 + c16) * 64 + ks * 32 + q4 * 8);
#pragma unroll
        for (int mt = 0; mt < 4; mt++) {
            f32x4 acc = {0.f, 0.f, 0.f, 0.f};
            acc = __builtin_amdgcn_mfma_f32_16x16x32_bf16(af[mt][0], bf[0], acc, 0, 0, 0);
            acc = __builtin_amdgcn_mfma_f32_16x16x32_bf16(af[mt][1], bf[1], acc, 0, 0, 0);
            if (c16 < 2)
#pragma unroll
                for (int rr = 0; rr < 4; rr++)
                    DT[(size_t)(mb + mt * 16 + q4 * 4 + rr) * 2 + c16] = acc[rr];
        }
    }
}

// ---------------- chunk1 (1024 thr): dt/cum, conv+SiLU, G, M, Y_intra(tile-major), SL^T ----------------
__global__ __launch_bounds__(1024, 8) void k_chunk1(
        const unsigned short* __restrict__ ZXb, const float* __restrict__ DT,
        const float* __restrict__ CW, const float* __restrict__ CB,
        const float* __restrict__ dtb, const float* __restrict__ Alog,
        const float* __restrict__ Dv,
        unsigned short* __restrict__ SL, unsigned short* __restrict__ CBuf,
        float* __restrict__ EB,
        float* __restrict__ TB, unsigned short* __restrict__ YBb) {
    __shared__ unsigned short sBt[128][72];
    __shared__ unsigned short sXt[128][72];
    __shared__ unsigned short uBC[2][64][136];
    __shared__ float s_cum[2][64], s_dt[2][64], s_w[2][64];
    unsigned short (*sM)[64][72] = (unsigned short (*)[64][72])&uBC[0][0][0];

    int c = blockIdx.x, b = blockIdx.y;
    size_t rbase = (size_t)b * SEQ + c * QC;
    int tid = threadIdx.x;
    int wid = tid >> 6, lane = tid & 63;
    int q4 = lane >> 4, c16 = lane & 15;

    // Phase A: dt/cumsum (waves 0,1) — ordered vs Phase C by the conv barrier
    if (wid < 2) {
        int h = wid, j = lane;
        float raw = DT[(rbase + j) * 2 + h] + dtb[h];
        float dt = (raw > 20.f) ? raw : log1pf(__expf(raw));
        float A = -__expf(Alog[h]);
        float x = dt * A;
        for (int off = 1; off < 64; off <<= 1) {
            float o = __shfl_up(x, off);
            if (lane >= off) x += o;
        }
        float T = __shfl(x, 63);
        s_dt[h][j] = dt;
        s_cum[h][j] = x;
        s_w[h][j] = __expf(T - x) * dt;
        EB[((size_t)(b * NC + c)) * 128 + h * 64 + j] = __expf(x);
        if (j == 0) TB[(b * 2 + h) * NC + c] = __expf(T);
    }

    // Phase B: conv(4)+bias+SiLU from global ZXb (width 384); software-pipelined depth 2.
    // 6 jobs/thread (e = tid + r*1024); job r+1's halo loads issue before job r's compute.
    size_t cbbase = ((size_t)(b * NC + c)) * 8192;
    {
        uint2 A0[2], A1[2], A2[2], A3[2];
        int JJ[2], CC[2];
        // prologue: issue loads for job 0 into slot 0
        {
            int e = tid;
            int j = e / 96, q = e - j * 96, cc = q * 4;
            const unsigned short* zp = ZXb + (rbase + j) * XW + cc;
            JJ[0] = j; CC[0] = cc;
            A0[0] = *(const uint2*)zp;
            if (c != 0) {
                A1[0] = *(const uint2*)(zp - XW);
                A2[0] = *(const uint2*)(zp - 2 * XW);
                A3[0] = *(const uint2*)(zp - 3 * XW);
            } else {
                A1[0] = make_uint2(0, 0); A2[0] = make_uint2(0, 0); A3[0] = make_uint2(0, 0);
                if (j >= 1) A1[0] = *(const uint2*)(zp - XW);
                if (j >= 2) A2[0] = *(const uint2*)(zp - 2 * XW);
                if (j >= 3) A3[0] = *(const uint2*)(zp - 3 * XW);
            }
        }
#pragma unroll
        for (int r = 0; r < 6; r++) {
            int sl = r & 1, sn = sl ^ 1;
            if (r < 5) {
                // issue next job's loads (overlap with this job's compute)
                int e = tid + (r + 1) * 1024;
                int j = e / 96, q = e - j * 96, cc = q * 4;
                const unsigned short* zp = ZXb + (rbase + j) * XW + cc;
                JJ[sn] = j; CC[sn] = cc;
                A0[sn] = *(const uint2*)zp;
                if (c != 0) {
                    A1[sn] = *(const uint2*)(zp - XW);
                    A2[sn] = *(const uint2*)(zp - 2 * XW);
                    A3[sn] = *(const uint2*)(zp - 3 * XW);
                } else {
                    A1[sn] = make_uint2(0, 0); A2[sn] = make_uint2(0, 0); A3[sn] = make_uint2(0, 0);
                    if (j >= 1) A1[sn] = *(const uint2*)(zp - XW);
                    if (j >= 2) A2[sn] = *(const uint2*)(zp - 2 * XW);
                    if (j >= 3) A3[sn] = *(const uint2*)(zp - 3 * XW);
                }
            }
            int j = JJ[sl], cc = CC[sl];
            uint2 a0 = A0[sl], a1 = A1[sl], a2 = A2[sl], a3 = A3[sl];
            float v[4];
#pragma unroll
            for (int u = 0; u < 4; u++) {
                unsigned int w0 = (u < 2) ? a0.x : a0.y;
                unsigned int w1 = (u < 2) ? a1.x : a1.y;
                unsigned int w2 = (u < 2) ? a2.x : a2.y;
                unsigned int w3 = (u < 2) ? a3.x : a3.y;
                int sh = (u & 1) * 16;
                float r0 = bf2f((unsigned short)(w0 >> sh));
                float r1 = bf2f((unsigned short)(w1 >> sh));
                float r2 = bf2f((unsigned short)(w2 >> sh));
                float r3 = bf2f((unsigned short)(w3 >> sh));
                float4 wv = *(const float4*)(CW + (cc + u) * 4);
                float tt = CB[cc + u] + wv.w * r0 + wv.z * r1 + wv.y * r2 + wv.x * r3;
                v[u] = fsilu(tt);
            }
            if (cc < 128) {
#pragma unroll
                for (int u = 0; u < 4; u++) sXt[cc + u][j] = f2bf(v[u]);
            } else if (cc < 256) {
                int s = cc - 128;
                unsigned int p0 = pk2(v[0], v[1]);
                unsigned int p1 = pk2(v[2], v[3]);
                *(uint2*)&uBC[0][j][s] = make_uint2(p0, p1);
#pragma unroll
                for (int u = 0; u < 4; u++) sBt[s + u][j] = f2bf(v[u]);
            } else {
                int s = cc - 256;
                unsigned int p0 = pk2(v[0], v[1]);
                unsigned int p1 = pk2(v[2], v[3]);
                *(uint2*)&uBC[1][j][s] = make_uint2(p0, p1);
                *(uint2*)(CBuf + cbbase + (size_t)j * 128 + s) = make_uint2(p0, p1);
            }
        }
    }
    __syncthreads();

    // Phase C: G = C.B^T (16 tiles / 16 waves), stage in regs, overlay sM
    f32x4 gacc;
    {
        int it = wid >> 2, jt = wid & 3;
        f32x4 acc = {0.f, 0.f, 0.f, 0.f};
        for (int ks = 0; ks < 4; ks++) {
            bf16x8 a = fragld(&uBC[1][0][0], it * 16, ks * 32, 136);
            bf16x8 bb = fragld(&uBC[0][0][0], jt * 16, ks * 32, 136);
            acc = __builtin_amdgcn_mfma_f32_16x16x32_bf16(a, bb, acc, 0, 0, 0);
        }
        gacc = acc;
    }
    __syncthreads();
    {
        int it = wid >> 2, jt = wid & 3;
        int j = jt * 16 + c16;
        for (int rr = 0; rr < 4; rr++) {
            int i = it * 16 + q4 * 4 + rr;
            float gv = gacc[rr];
            for (int h = 0; h < 2; h++) {
                float m = 0.f;
                if (j <= i) m = gv * __expf(s_cum[h][i] - s_cum[h][j]) * s_dt[h][j];
                sM[h][i][j] = f2bf(m);
            }
        }
    }
    __syncthreads();

    // Phase D1: Y_intra = M_h @ X_h + D*x (32 tiles / 16 waves) — tile-major store
    size_t ybase = ((size_t)(b * NC + c)) * 8192;   // 32 tiles * 256 elems per chunk
#pragma unroll
    for (int u = 0; u < 2; u++) {
        int idx = wid * 2 + u;
        int h = idx >> 4, tt = idx & 15;
        int it = tt >> 2, pt = tt & 3;
        float dco = Dv[h];
        int pg = h * 64 + pt * 16 + c16;
        f32x4 acc;
        for (int rr = 0; rr < 4; rr++) {
            int i = it * 16 + q4 * 4 + rr;
            acc[rr] = dco * bf2f(sXt[pg][i]);
        }
        for (int ks = 0; ks < 2; ks++) {
            bf16x8 a = fragld(&sM[h][0][0], it * 16, ks * 32, 72);
            bf16x8 bb = fragld(&sXt[0][0], h * 64 + pt * 16, ks * 32, 72);
            acc = __builtin_amdgcn_mfma_f32_16x16x32_bf16(a, bb, acc, 0, 0, 0);
        }
        uint2 pk;
        pk.x = pk2(acc[0], acc[1]);
        pk.y = pk2(acc[2], acc[3]);
        *(uint2*)(YBb + ybase + (size_t)idx * 256 + lane * 4) = pk;
    }
    // Pre-scale sXt in place by s_w so D2 needs no per-fragment rescale
    __syncthreads();
    {
        int row = tid >> 3, c0 = (tid & 7) * 8;
        uint4 xv = *(uint4*)&sXt[row][c0];
        const float* wp = s_w[row >> 6];
        unsigned int* px = &xv.x;
        uint4 ov;
        unsigned int* po = &ov.x;
#pragma unroll
        for (int t = 0; t < 4; t++) {
            float lo = bf2f((unsigned short)(px[t] & 0xffff)) * wp[c0 + 2 * t];
            float hi = bf2f((unsigned short)(px[t] >> 16)) * wp[c0 + 2 * t + 1];
            po[t] = pk2(lo, hi);
        }
        *(uint4*)&sXt[row][c0] = ov;
    }
    __syncthreads();
    // Phase D2: SL^T[p][s] (64 tiles / 16 waves)
    size_t slbase = ((size_t)(b * NC + c)) * 16384;
#pragma unroll
    for (int u = 0; u < 4; u++) {
        int idx = wid * 4 + u;
        int ptl = idx >> 3, st = idx & 7;
        f32x4 acc = {0.f, 0.f, 0.f, 0.f};
        for (int ks = 0; ks < 2; ks++) {
            bf16x8 a = fragld(&sXt[0][0], ptl * 16, ks * 32, 72);
            bf16x8 bb = fragld(&sBt[0][0], st * 16, ks * 32, 72);
            acc = __builtin_amdgcn_mfma_f32_16x16x32_bf16(a, bb, acc, 0, 0, 0);
        }
        int s = st * 16 + c16;
        for (int rr = 0; rr < 4; rr++) {
            int p = ptl * 16 + q4 * 4 + rr;
            float vv = acc[rr];
            float vn = __shfl_xor(vv, 1);
            if (!(lane & 1)) {
                unsigned int pk = pk2(vv, vn);
                *(unsigned int*)(SL + slbase + (size_t)p * 128 + s) = pk;
            }
        }
    }
}

// ---------------- cross-chunk state scan: segmented, 8-deep chain (512 blk x 1024 thr) ----------------
__global__ __launch_bounds__(1024) void k_scan(unsigned short* __restrict__ SL,
                                               const float* __restrict__ TB) {
    __shared__ float sT0[8][128], sT1[8][128], sP[8];
    int tid = threadIdx.x;
    int col = tid & 127, seg = tid >> 7;
    int colg = blockIdx.x * 128 + col;         // 65536 col-pairs total
    int b2 = colg >> 13;
    int pu = colg & 8191;
    int h2 = pu >> 12;
    const float* dAp = TB + (b2 * 2 + h2) * NC;
    size_t cbase = (size_t)(b2 * NC) * 16384 + (size_t)pu * 2;
    int cc0 = seg * 8;
    unsigned int sv[8];
    float dA[8];
    float hP = 1.f, t0 = 0.f, t1 = 0.f;
#pragma unroll
    for (int k = 0; k < 8; k++) {
        sv[k] = *(unsigned int*)(SL + cbase + (size_t)(cc0 + k) * 16384);
        dA[k] = dAp[cc0 + k];
        float sx0 = bf2f((unsigned short)(sv[k] & 0xffff));
        float sx1 = bf2f((unsigned short)(sv[k] >> 16));
        t0 = t0 * dA[k] + sx0;
        t1 = t1 * dA[k] + sx1;
        hP *= dA[k];
    }
    sT0[seg][col] = t0;
    sT1[seg][col] = t1;
    if (col == 0) sP[seg] = hP;
    __syncthreads();
    float h0 = 0.f, h1 = 0.f;
    for (int s2 = 0; s2 < seg; s2++) {
        float Ps = sP[s2];
        h0 = h0 * Ps + sT0[s2][col];
        h1 = h1 * Ps + sT1[s2][col];
    }
#pragma unroll
    for (int k = 0; k < 8; k++) {
        *(unsigned int*)(SL + cbase + (size_t)(cc0 + k) * 16384) = pk2(h0, h1);
        float sx0 = bf2f((unsigned short)(sv[k] & 0xffff));
        float sx1 = bf2f((unsigned short)(sv[k] >> 16));
        h0 = h0 * dA[k] + sx0;
        h1 = h1 * dA[k] + sx1;
    }
}

// ---------------- fused (1024 thr): z-GEMM + Y_inter + gate + RMSNorm + out_proj + residual
//                  + next-layer in_proj (row-local, from LDS) ----------------
__global__ __launch_bounds__(1024, 8) void k_fused(
        const unsigned short* __restrict__ SL, const unsigned short* __restrict__ CBuf,
        const float* __restrict__ EB,
        const unsigned short* __restrict__ YBb, const unsigned short* __restrict__ Wzb,
        const float* __restrict__ NW, const unsigned short* __restrict__ OWb,
        unsigned short* __restrict__ Xb, float* __restrict__ OutF,
        const unsigned short* __restrict__ WbN,      // next layer's in_proj weights (bf16)
        unsigned short* __restrict__ ZXbO,           // next layer's xBC buffer
        float* __restrict__ DTO,                     // next layer's dt buffer
        int last) {
    __shared__ __attribute__((aligned(16))) unsigned short sH[128][136];
    __shared__ __attribute__((aligned(16))) unsigned short sE[128][136];
    float* sGf = (float*)&sH[0][0];                                   // [64][132] overlay (dead after RMS)
    unsigned short (*sG)[136] = (unsigned short (*)[136])&sE[0][0];   // [64][136] overlay
    unsigned short (*sX2)[72] = (unsigned short (*)[72])&sH[0][0];    // [64][72] overlay (written in out_proj)

    int c = blockIdx.x, b = blockIdx.y;
    size_t rbase = (size_t)b * SEQ + c * QC;
    int tid = threadIdx.x;
    int wid = tid >> 6, lane = tid & 63;
    int q4 = lane >> 4, c16 = lane & 15;
    size_t base = ((size_t)(b * NC + c)) * 16384;
    size_t ybase = ((size_t)(b * NC + c)) * 8192;

    // ---- prefetch (issues before the first barrier; latency hides under sH/sE fill):
    //      YBb tile, Xb fragments, AND Wzb z-weight fragments (L2-hot broadcast) ----
    uint2 yi[2];
    bf16x8 xa[2][2], wz[2][2];
#pragma unroll
    for (int u = 0; u < 2; u++) {
        int idx = wid * 2 + u;
        int h = idx >> 4, tt = idx & 15;
        int it = tt >> 2, pt = tt & 3;
        yi[u] = *(const uint2*)(YBb + ybase + (size_t)idx * 256 + lane * 4);
#pragma unroll
        for (int ks = 0; ks < 2; ks++) {
            xa[u][ks] = fragld(Xb, (int)rbase + it * 16, ks * 32, 64);
            wz[u][ks] = fragld(Wzb, h * 64 + pt * 16, ks * 32, 64);
        }
    }

    for (int u = 0; u < 2; u++) {
        int e = u * 1024 + tid;
        int row = e >> 4, cb8 = (e & 15) * 8;
        *(uint4*)&sH[row][cb8] = *(const uint4*)(SL + base + (size_t)row * 128 + cb8);
    }
    size_t cbbase = ((size_t)(b * NC + c)) * 8192;
    size_t ebase  = ((size_t)(b * NC + c)) * 128;
    {
        int i = tid >> 4, sc = (tid & 15) * 8;
        uint4 cv = *(const uint4*)(CBuf + cbbase + (size_t)i * 128 + sc);
        float e0 = EB[ebase + i], e1 = EB[ebase + 64 + i];
        unsigned int w[4] = {cv.x, cv.y, cv.z, cv.w};
        uint4 o0, o1;
        unsigned int* po0 = &o0.x;
        unsigned int* po1 = &o1.x;
#pragma unroll
        for (int t = 0; t < 4; t++) {
            float lo = bf2f((unsigned short)(w[t] & 0xffff));
            float hi = bf2f((unsigned short)(w[t] >> 16));
            po0[t] = pk2(lo * e0, hi * e0);
            po1[t] = pk2(lo * e1, hi * e1);
        }
        *(uint4*)&sE[i][sc] = o0;
        *(uint4*)&sE[64 + i][sc] = o1;
    }
    __syncthreads();

    float yv[2][4];
    int tit[2], tpg[2];
#pragma unroll
    for (int u = 0; u < 2; u++) {
        int idx = wid * 2 + u;                 // 32 tiles / 16 waves
        int h = idx >> 4, tt = idx & 15;
        int it = tt >> 2, pt = tt & 3;
        int pg = h * 64 + pt * 16 + c16;
        f32x4 zacc = {0.f, 0.f, 0.f, 0.f};
        f32x4 acc = {0.f, 0.f, 0.f, 0.f};
#pragma unroll
        for (int ks = 0; ks < 2; ks++)
            zacc = __builtin_amdgcn_mfma_f32_16x16x32_bf16(xa[u][ks], wz[u][ks], zacc, 0, 0, 0);
        for (int ks = 0; ks < 4; ks++) {
            bf16x8 a = fragld(&sE[0][0], h * 64 + it * 16, ks * 32, 136);
            bf16x8 bb = fragld(&sH[0][0], h * 64 + pt * 16, ks * 32, 136);
            acc = __builtin_amdgcn_mfma_f32_16x16x32_bf16(a, bb, acc, 0, 0, 0);
        }
        tit[u] = it; tpg[u] = pg;
        float yin[4] = {bf2f((unsigned short)(yi[u].x & 0xffff)), bf2f((unsigned short)(yi[u].x >> 16)),
                        bf2f((unsigned short)(yi[u].y & 0xffff)), bf2f((unsigned short)(yi[u].y >> 16))};
        for (int rr = 0; rr < 4; rr++) {
            float y = acc[rr] + yin[rr];
            yv[u][rr] = y * fsilu(zacc[rr]);
        }
    }
    __syncthreads();
#pragma unroll
    for (int u = 0; u < 2; u++)
        for (int rr = 0; rr < 4; rr++) {
            int i = tit[u] * 16 + q4 * 4 + rr;
            sGf[i * 132 + tpg[u]] = yv[u][rr];
        }
    __syncthreads();
    // prefetch residual + out_proj weights (both hide under RMS reduction;
    // yi/xa/wz registers are dead here so VGPR peak is unchanged)
    unsigned short xres[4];
    bf16x8 owf[4];
    {
        int mt = wid >> 2, nt2 = wid & 3;
        int n = nt2 * 16 + c16;
#pragma unroll
        for (int rr = 0; rr < 4; rr++) {
            int m = mt * 16 + q4 * 4 + rr;
            xres[rr] = Xb[(rbase + m) * DM + n];
        }
#pragma unroll
        for (int ks = 0; ks < 4; ks++)
            owf[ks] = *(const bf16x8*)(OWb + (size_t)(nt2 * 16 + c16) * 128 + ks * 32 + q4 * 8);
    }
    {
        int row = tid >> 4, part = tid & 15;
        int d0 = part * 8;
        float g[8];
        float ss = 0.f;
        for (int t2 = 0; t2 < 8; t2++) { g[t2] = sGf[row * 132 + d0 + t2]; ss += g[t2] * g[t2]; }
        ss += __shfl_xor(ss, 1);
        ss += __shfl_xor(ss, 2);
        ss += __shfl_xor(ss, 4);
        ss += __shfl_xor(ss, 8);
        float rms = rsqrtf(ss * (1.f / 128.f) + 1e-5f);
        for (int t2 = 0; t2 < 8; t2 += 2) {
            unsigned int pk = pk2(g[t2] * rms * NW[d0 + t2], g[t2 + 1] * rms * NW[d0 + t2 + 1]);
            *(unsigned int*)&sG[row][d0 + t2] = pk;
        }
    }
    __syncthreads();
    {
        // out_proj: 16 tiles over 16 waves (mt 0..3 × nt 0..3); also stage new-x into sX2
        int mt = wid >> 2, nt = wid & 3;
        f32x4 acc = {0.f, 0.f, 0.f, 0.f};
        for (int ks = 0; ks < 4; ks++) {
            bf16x8 a = fragld(&sG[0][0], mt * 16, ks * 32, 136);
            acc = __builtin_amdgcn_mfma_f32_16x16x32_bf16(a, owf[ks], acc, 0, 0, 0);
        }
        for (int rr = 0; rr < 4; rr++) {
            int m = mt * 16 + q4 * 4 + rr;
            int n = nt * 16 + c16;
            size_t o = (rbase + m) * DM + n;
            float v = bf2f(xres[rr]) + acc[rr];
            if (last) {
                OutF[o] = v;
            } else {
                unsigned short vb = f2bf(v);
                sX2[m][n] = vb;
                float vn = __shfl_xor(v, 1);
                if (!(lane & 1)) {
                    unsigned int pk = (unsigned int)vb | ((unsigned int)f2bf(vn) << 16);
                    *(unsigned int*)(Xb + o) = pk;
                }
            }
        }
    }
    if (!last) {
        __syncthreads();
        // next-layer in_proj for rows rbase..rbase+63: 100 tile jobs over 16 waves
        for (int t = wid; t < 100; t += 16) {
            int mt2, n0;
            int isdt = (t >= 96);
            if (!isdt) { mt2 = t & 3; n0 = (t >> 2) * 16; }
            else       { mt2 = t - 96; n0 = 0; }
            bf16x8 a0 = fragld(&sX2[0][0], mt2 * 16, 0, 72);
            bf16x8 a1 = fragld(&sX2[0][0], mt2 * 16, 32, 72);
            const unsigned short* wrow = isdt ? (WbN + (size_t)(512 + c16) * 64)
                                              : (WbN + (size_t)(128 + n0 + c16) * 64);
            bf16x8 b0 = *(const bf16x8*)(wrow + q4 * 8);
            bf16x8 b1 = *(const bf16x8*)(wrow + 32 + q4 * 8);
            f32x4 acc = {0.f, 0.f, 0.f, 0.f};
            acc = __builtin_amdgcn_mfma_f32_16x16x32_bf16(a0, b0, acc, 0, 0, 0);
            acc = __builtin_amdgcn_mfma_f32_16x16x32_bf16(a1, b1, acc, 0, 0, 0);
            if (!isdt) {
#pragma unroll
                for (int rr = 0; rr < 4; rr++) {
                    float v = acc[rr];
                    float vn = __shfl_xor(v, 1);
                    if (!(lane & 1)) {
                        unsigned int pk = pk2(v, vn);
                        *(unsigned int*)(ZXbO + (rbase + mt2 * 16 + q4 * 4 + rr) * XW + n0 + c16) = pk;
                    }
                }
            } else {
                if (c16 < 2)
#pragma unroll
                    for (int rr = 0; rr < 4; rr++)
                        DTO[(rbase + mt2 * 16 + q4 * 4 + rr) * 2 + c16] = acc[rr];
            }
        }
    }
}

extern "C" void kernel_launch(void* const* d_in, const int* in_sizes, int n_in,
                              void* d_out, int out_size, void* d_ws, size_t ws_size,
                              hipStream_t stream) {
    const float* x       = (const float*)d_in[0];
    const float* in_w    = (const float*)d_in[1];
    const float* conv_w  = (const float*)d_in[2];
    const float* conv_b  = (const float*)d_in[3];
    const float* dt_bias = (const float*)d_in[4];
    const float* A_log   = (const float*)d_in[5];
    const float* Dp      = (const float*)d_in[6];
    const float* norm_w  = (const float*)d_in[7];
    const float* out_w   = (const float*)d_in[8];
    float* out = (float*)d_out;
    float* ws  = (float*)d_ws;

    float* dt = ws;                                        // NR*2 f32
    float* tb = dt + (size_t)NR * 2;                       // 1024 f32
    float* eb = tb + 1024;                                 // 8*64*128 f32
    unsigned short* zxb  = (unsigned short*)(eb + (size_t)B_SZ * NC * 128); // NR*384
    unsigned short* ybb  = zxb + (size_t)NR * XW;          // 8*64*8192 (tile-major)
    unsigned short* sl   = ybb + (size_t)B_SZ * NC * 8192; // 8*64*16384
    unsigned short* cbuf = sl + (size_t)B_SZ * NC * 16384; // 8*64*8192
    unsigned short* xb   = cbuf + (size_t)B_SZ * NC * 8192;// NR*64
    unsigned short* wb   = xb + (size_t)NR * DM;           // 4*576*64
    unsigned short* owb  = wb + (size_t)4 * WPAD * 64;     // 4*64*128

    k_pre<<<576 + NR * DM / 1024, 256, 0, stream>>>(in_w, out_w, x, wb, owb, xb);
    k_inproj<<<dim3(NR / 256, 7), 256, 0, stream>>>(xb, wb, zxb, dt);   // layer 0 only

    for (int layer = 0; layer < 4; layer++) {
        int nl = (layer < 3) ? layer + 1 : 3;
        k_chunk1<<<dim3(NC, B_SZ), 1024, 0, stream>>>(zxb, dt,
                conv_w + (size_t)layer * CD * 4, conv_b + (size_t)layer * CD,
                dt_bias + layer * NH, A_log + layer * NH, Dp + layer * NH,
                sl, cbuf, eb, tb, ybb);
        k_scan<<<512, 1024, 0, stream>>>(sl, tb);
        k_fused<<<dim3(NC, B_SZ), 1024, 0, stream>>>(sl, cbuf, eb, ybb,
                wb + (size_t)layer * WPAD * 64, norm_w + layer * DI,
                owb + (size_t)layer * 64 * 128, xb, out,
                wb + (size_t)nl * WPAD * 64, zxb, dt,
                (layer == 3) ? 1 : 0);
    }
}